// Round 1
// baseline (750.952 us; speedup 1.0000x reference)
//
#include <hip/hip_runtime.h>
#include <hip/hip_bf16.h>

// DA-RNN persistent kernel, round 7: occupancy doubling (2 blocks/CU).
// R6 counters: MfmaUtil 8.4%, VALUBusy 43%, HBM 0.8%, Occupancy 23% -> ~50%
// of cycles are chain/barrier stalls with 1 block/CU (LDS 137 KB).
// R7: BB 4->2 (512 blocks x 512 threads) halves row-indexed LDS; enc-only
// constants (s_se/s_encb) are overwritten with dec scales/bias after the
// encoder (saves 4 KB). LDS ~77.6 KB -> 2 independent barrier domains per CU
// hide each other's serial-chain stalls. Math is bit-identical per row.

#define B_    1024
#define T_    64
#define D_    128
#define H_    128
#define HOR_  24
#define ATT_  64
#define BB    2
#define LOG2E 1.4426950408889634f
#define C127  (1.f/127.f)

typedef float f32x4  __attribute__((ext_vector_type(4)));
typedef short bf16x8 __attribute__((ext_vector_type(8)));
typedef int   i32x4  __attribute__((ext_vector_type(4)));

#define MFMA16(a,b,c) __builtin_amdgcn_mfma_f32_16x16x32_bf16((a),(b),(c),0,0,0)
#define MFMAI8(a,b,c) __builtin_amdgcn_mfma_i32_16x16x64_i8((a),(b),(c),0,0,0)

// ---- workspace layout (same packing as R5/R6) ----
#define WHS_E    0        // base GEMM  B bf16: kt0..7, nt0..3  (16384 el)
#define WDDC_E   16384    // dc GEMM    B bf16: kt0..7, nt0..3  (16384 el)
#define WDENC_E  32768    // proj GEMM  B bf16: kt0..3, nt0..3  ( 8192 el)
#define WENC8_B  81920    // i8 enc gates B: [kt4][nt32][lane64][16] (131072 B)
#define WDEC8_B  212992   // i8 dec gates B: [kt2][nt32][lane64][16] ( 65536 B)
#define SENC_B   278528   // 512 f32 per-col scales (enc)
#define SDEC_B   280576   // 512 f32 per-col scales (dec)

__device__ __forceinline__ short f2b(float f) {        // fp32 -> bf16 RNE
  union { float f; unsigned u; } c; c.f = f;
  unsigned r = c.u + 0x7fffu + ((c.u >> 16) & 1u);
  return (short)(r >> 16);
}
__device__ __forceinline__ float b2f(short s) {
  union { unsigned u; float f; } c; c.u = ((unsigned)(unsigned short)s) << 16;
  return c.f;
}
__device__ __forceinline__ float fexp2(float x) { return __builtin_amdgcn_exp2f(x); }
__device__ __forceinline__ float frcp (float x) { return __builtin_amdgcn_rcpf(x); }
__device__ __forceinline__ float tanh_acc(float x) {   // 1 - 2/(1+e^{2x})
  float e = fexp2(x * 2.885390081777927f);
  return 1.f - 2.f * frcp(1.f + e);
}
__device__ __forceinline__ float sigm(float x) {
  return frcp(1.f + fexp2(-LOG2E * x));
}
__device__ __forceinline__ float wsum64(float v) {
#pragma unroll
  for (int o = 32; o > 0; o >>= 1) v += __shfl_xor(v, o, 64);
  return v;
}
__device__ __forceinline__ float wmax64(float v) {
#pragma unroll
  for (int o = 32; o > 0; o >>= 1) v = fmaxf(v, __shfl_xor(v, o, 64));
  return v;
}

// ---- prep1: bf16 B-frags (base / dc / proj), one element per thread ----
__global__ void prep_bf(const float* __restrict__ We_w,
                        const float* __restrict__ Wd_w,
                        char* __restrict__ ws8) {
  int e = blockIdx.x * 256 + threadIdx.x;
  if (e >= 40960) return;
  short* f16 = (short*)ws8;
  int region = e >> 14;                  // 0=WHS 1=WDDC 2=WDENC
  int er = e & 16383;
  int fi = er >> 9, li = (er >> 3) & 63, jq = er & 7;
  int kt = fi >> 2, nt = fi & 3;
  int k = kt * 32 + ((li >> 4) << 3) + jq, n = nt * 16 + (li & 15);
  float v;
  if (region == 0)      v = We_w[n * 257 + k];
  else if (region == 1) v = (k < 128) ? Wd_w[n * 384 + 128 + k]
                                      : Wd_w[n * 384 + 256 + (k - 128)];
  else                  v = Wd_w[n * 384 + k];
  f16[e] = f2b(v);
}

// ---- prep2: i8 quantized gates weights, one wave per column ----
__global__ void prep_q(const float* __restrict__ enc_Wih,
                       const float* __restrict__ enc_Whh,
                       const float* __restrict__ dec_Whh,
                       char* __restrict__ ws8) {
  int gw = (blockIdx.x * 256 + threadIdx.x) >> 6;
  int lane = threadIdx.x & 63;
  if (gw < 512) {                        // encoder col, K=256
    int n = gw;
    float v[4]; float m = 0.f;
#pragma unroll
    for (int q = 0; q < 4; ++q) {
      int k = lane * 4 + q;
      v[q] = (k < 128) ? enc_Wih[n * 128 + k] : enc_Whh[n * 128 + (k - 128)];
      m = fmaxf(m, fabsf(v[q]));
    }
    m = wmax64(m);
    if (lane == 0) ((float*)(ws8 + SENC_B))[n] = m * C127;
    float inv = m > 0.f ? 127.f / m : 0.f;
    char* dst = ws8 + WENC8_B;
#pragma unroll
    for (int q = 0; q < 4; ++q) {
      int k = lane * 4 + q;
      int kt = k >> 6, grp = (k >> 4) & 3, b = k & 15, l16 = (n & 15) | (grp << 4);
      dst[((kt * 32 + (n >> 4)) * 64 + l16) * 16 + b] = (char)(int)rintf(v[q] * inv);
    }
  } else if (gw < 1024) {                // decoder col, K=128
    int n = gw - 512;
    float v[2]; float m = 0.f;
#pragma unroll
    for (int q = 0; q < 2; ++q) {
      int k = lane * 2 + q;
      v[q] = dec_Whh[n * 128 + k];
      m = fmaxf(m, fabsf(v[q]));
    }
    m = wmax64(m);
    if (lane == 0) ((float*)(ws8 + SDEC_B))[n] = m * C127;
    float inv = m > 0.f ? 127.f / m : 0.f;
    char* dst = ws8 + WDEC8_B;
#pragma unroll
    for (int q = 0; q < 2; ++q) {
      int k = lane * 2 + q;
      int kt = k >> 6, grp = (k >> 4) & 3, b = k & 15, l16 = (n & 15) | (grp << 4);
      dst[((kt * 32 + (n >> 4)) * 64 + l16) * 16 + b] = (char)(int)rintf(v[q] * inv);
    }
  }
}

__global__ __launch_bounds__(512, 4)
void da_rnn(const float* __restrict__ X, const float* __restrict__ y_hist,
            const float* __restrict__ We_w, const float* __restrict__ We_b,
            const float* __restrict__ ve_w,
            const float* __restrict__ enc_bih, const float* __restrict__ enc_bhh,
            const float* __restrict__ dec_Wih,
            const float* __restrict__ dec_bih, const float* __restrict__ dec_bhh,
            const float* __restrict__ Wd_b, const float* __restrict__ vd_w,
            const float* __restrict__ fc_w, const float* __restrict__ fc_b,
            const char* __restrict__ ws8, float* __restrict__ out) {
  const short* f16  = (const short*)ws8;
  const i32x4* enc8 = (const i32x4*)(ws8 + WENC8_B);
  const i32x4* dec8 = (const i32x4*)(ws8 + WDEC8_B);
  const float* senc = (const float*)(ws8 + SENC_B);
  const float* sdec = (const float*)(ws8 + SDEC_B);

  // strides: s_A8 272B=68w (68%32=4 -> 2-way, free); s_Ahc 264sh=132w (4 mod 32)
  __shared__ __align__(16) char  s_A8[16][272];   // gates A i8
  __shared__ __align__(16) short s_Ahc[16][264];  // base/dc/proj A bf16 [h;c]
  __shared__ short s_projT[BB][64][65];           // enc_proj^T
  __shared__ short s_encht[BB][128][66];          // enc_hiddens [r][j][t] bf16
  __shared__ float s_gates[BB][512];
  __shared__ float s_base[BB][64];                // enc: base ; dec: dc
  __shared__ float s_beta[BB][64];
  __shared__ float s_xr[BB];
  __shared__ float2 s_wv[64];                     // (w_feat[k], ve_w[k])
  __shared__ float s_web[64], s_vd[64], s_wdb[64];
  __shared__ float s_se[512];                     // enc scales -> dec scales
  __shared__ float s_encb[512];                   // enc bias   -> dec bias
  __shared__ float s_dwih[512];
  __shared__ float s_fcw[320];

  const int tid  = threadIdx.x;
  const int lane = tid & 63;
  const int w    = tid >> 6;        // wave 0..7 ; waves 0-1 own row w
  const int b0   = blockIdx.x * BB;

  // ---- init ----
  if (tid < 64) {
    s_wv[tid]  = make_float2(We_w[tid * 257 + 256], ve_w[tid]);
    s_web[tid] = We_b[tid];
    s_vd[tid]  = vd_w[tid];
    s_wdb[tid] = Wd_b[tid];
  }
  if (tid < 320) s_fcw[tid] = fc_w[tid];
  s_se[tid]   = senc[tid];
  s_encb[tid] = enc_bih[tid] + enc_bhh[tid];
  s_dwih[tid] = dec_Wih[tid];
  for (int i = tid; i < (16 * 272) / 4; i += 512) ((int*)s_A8)[i] = 0;
  for (int i = tid; i < (16 * 264) / 2; i += 512) ((int*)s_Ahc)[i] = 0;
  if (tid < 64 * BB) s_base[tid >> 6][tid & 63] = We_b[tid & 63];  // base_0

  // ---- register-resident weights (loaded once, L2) ----
  i32x4 wg[4][4];                       // enc gates i8, nt = w + 8i
#pragma unroll
  for (int kt = 0; kt < 4; ++kt)
#pragma unroll
    for (int i = 0; i < 4; ++i)
      wg[kt][i] = enc8[(kt * 32 + (w + 8 * i)) * 64 + lane];
  bf16x8 wb[8], wp[4];
  if (w < 4) {
#pragma unroll
    for (int kt = 0; kt < 8; ++kt)
      wb[kt] = *(const bf16x8*)(f16 + WHS_E + ((kt * 4 + w) * 64 + lane) * 8);
  } else {
#pragma unroll
    for (int kt = 0; kt < 4; ++kt)
      wp[kt] = *(const bf16x8*)(f16 + WDENC_E + ((kt * 4 + (w - 4)) * 64 + lane) * 8);
  }

  // per-row state (waves 0-1): features j0=lane, j1=lane+64
  float h0 = 0.f, c0 = 0.f, h1 = 0.f, c1 = 0.f;
  float x0 = 0.f, x1 = 0.f, xi = 0.f;
  const float* Xr = X + (size_t)(b0 + (w & (BB - 1))) * T_ * D_;
  if (w < BB) {
    x0 = Xr[lane]; x1 = Xr[64 + lane];
    xi = 6.f * cosf((2 * (lane >> 3) + 1) * 0.19634954084936207f);  // node
  }
  __syncthreads();

  // ====================== encoder ======================
  for (int t = 0; t < T_; ++t) {
    // ---- P_A: input attention, in-wave, waves 0-1 (row = w) ----
    if (w < BB) {
      float x0n = 0.f, x1n = 0.f;
      if (t < T_ - 1) { x0n = Xr[(t + 1) * D_ + lane]; x1n = Xr[(t + 1) * D_ + 64 + lane]; }
      // node eval: lane = (ni = lane>>3, kc = lane&7); 8 k-terms each
      const int kc = lane & 7;
      float p = 0.f;
      const float4* wvp = (const float4*)&s_wv[kc * 8];
      const float4* bp  = (const float4*)&s_base[w][kc * 8];
      float4 bA = bp[0], bB = bp[1];
#pragma unroll
      for (int q = 0; q < 4; ++q) {
        float4 wv = wvp[q];                       // (w_k, ve_k, w_{k+1}, ve_{k+1})
        float bb0 = (q < 2) ? ((q & 1) ? bA.z : bA.x) : ((q & 1) ? bB.z : bB.x);
        float bb1 = (q < 2) ? ((q & 1) ? bA.w : bA.y) : ((q & 1) ? bB.w : bB.y);
        p += wv.y * tanh_acc(fmaf(xi, wv.x, bb0));
        p += wv.w * tanh_acc(fmaf(xi, wv.z, bb1));
      }
      p += __shfl_xor(p, 1, 64); p += __shfl_xor(p, 2, 64); p += __shfl_xor(p, 4, 64);
      float f0 = __shfl(p,  0, 64), f1 = __shfl(p,  8, 64);
      float f2 = __shfl(p, 16, 64), f3 = __shfl(p, 24, 64);
      float f4 = __shfl(p, 32, 64), f5 = __shfl(p, 40, 64);
      float f6 = __shfl(p, 48, 64), f7 = __shfl(p, 56, 64);
      // barycentric interpolation at u = clamp(x, +-6), Cheb-1 nodes
      float sc0, sc1;
      {
        const float xb[8] = { 5.884711682f, 4.988817674f, 3.333421398f, 1.170541932f,
                             -1.170541932f, -3.333421398f, -4.988817674f, -5.884711682f};
        const float wbar[8] = { 0.1950903220f, -0.5555702330f, 0.8314696123f, -0.9807852804f,
                                0.9807852804f, -0.8314696123f, 0.5555702330f, -0.1950903220f};
        float u0 = fminf(fmaxf(x0, -6.f), 6.f), u1 = fminf(fmaxf(x1, -6.f), 6.f);
        float n0 = 0.f, d0 = 0.f, n1 = 0.f, d1 = 0.f;
        float fv[8] = {f0, f1, f2, f3, f4, f5, f6, f7};
#pragma unroll
        for (int i = 0; i < 8; ++i) {
          float dd0 = u0 - xb[i]; dd0 = copysignf(fmaxf(fabsf(dd0), 1e-5f), dd0);
          float dd1 = u1 - xb[i]; dd1 = copysignf(fmaxf(fabsf(dd1), 1e-5f), dd1);
          float t0 = wbar[i] * frcp(dd0), t1 = wbar[i] * frcp(dd1);
          n0 = fmaf(t0, fv[i], n0); d0 += t0;
          n1 = fmaf(t1, fv[i], n1); d1 += t1;
        }
        sc0 = n0 * frcp(d0); sc1 = n1 * frcp(d1);
      }
      float e0 = fexp2(sc0 * LOG2E), e1 = fexp2(sc1 * LOG2E);  // |sc|<=sum|ve|~2.6
      float sum = wsum64(e0 + e1);
      float mx  = wmax64(fmaxf(e0 * fabsf(x0), e1 * fabsf(x1)));
      float inv = mx > 0.f ? 127.f * frcp(mx) : 0.f;
      s_A8[w][lane]      = (char)(int)rintf(x0 * e0 * inv);
      s_A8[w][64 + lane] = (char)(int)rintf(x1 * e1 * inv);
      if (lane == 0) s_xr[w] = mx * frcp(127.f * sum);
      x0 = x0n; x1 = x1n;
    }
    __syncthreads();                                            // B1
    // ---- P_G: gates i8 GEMM, all 8 waves, weights in registers ----
    {
      i32x4 a0 = *(const i32x4*)&s_A8[lane & 15][  0 + ((lane >> 4) << 4)];
      i32x4 a1 = *(const i32x4*)&s_A8[lane & 15][ 64 + ((lane >> 4) << 4)];
      i32x4 a2 = *(const i32x4*)&s_A8[lane & 15][128 + ((lane >> 4) << 4)];
      i32x4 a3 = *(const i32x4*)&s_A8[lane & 15][192 + ((lane >> 4) << 4)];
      i32x4 ax[4], ah[4];
#pragma unroll
      for (int i = 0; i < 4; ++i) {
        i32x4 z = {0, 0, 0, 0};
        ax[i] = MFMAI8(a1, wg[1][i], MFMAI8(a0, wg[0][i], z));
        ah[i] = MFMAI8(a3, wg[3][i], MFMAI8(a2, wg[2][i], z));
      }
      if (lane < 16) {
        float sx0 = s_xr[0], sx1 = s_xr[1];
#pragma unroll
        for (int i = 0; i < 4; ++i) {
          int col = (w + 8 * i) * 16 + lane;
          float se = s_se[col];
          s_gates[0][col] = se * fmaf(sx0, (float)ax[i][0], C127 * (float)ah[i][0]);
          s_gates[1][col] = se * fmaf(sx1, (float)ax[i][1], C127 * (float)ah[i][1]);
        }
      }
    }
    __syncthreads();                                            // B2
    // ---- P_E: LSTM epilogue, in-wave, waves 0-1 (2 features/lane) ----
    if (w < BB) {
      float gi0 = s_gates[w][lane]       + s_encb[lane];
      float gf0 = s_gates[w][lane + 128] + s_encb[lane + 128];
      float gg0 = s_gates[w][lane + 256] + s_encb[lane + 256];
      float go0 = s_gates[w][lane + 384] + s_encb[lane + 384];
      float gi1 = s_gates[w][lane + 64]  + s_encb[lane + 64];
      float gf1 = s_gates[w][lane + 192] + s_encb[lane + 192];
      float gg1 = s_gates[w][lane + 320] + s_encb[lane + 320];
      float go1 = s_gates[w][lane + 448] + s_encb[lane + 448];
      c0 = sigm(gf0) * c0 + sigm(gi0) * tanh_acc(gg0);
      h0 = sigm(go0) * tanh_acc(c0);
      c1 = sigm(gf1) * c1 + sigm(gi1) * tanh_acc(gg1);
      h1 = sigm(go1) * tanh_acc(c1);
      s_Ahc[w][lane]        = f2b(h0);
      s_Ahc[w][lane + 64]   = f2b(h1);
      s_Ahc[w][lane + 128]  = f2b(c0);
      s_Ahc[w][lane + 192]  = f2b(c1);
      s_A8[w][128 + lane]      = (char)(int)rintf(h0 * 127.f);
      s_A8[w][128 + lane + 64] = (char)(int)rintf(h1 * 127.f);
      s_encht[w][lane][t]      = f2b(h0);
      s_encht[w][lane + 64][t] = f2b(h1);
    }
    __syncthreads();                                            // B3
    // ---- P_B: base_{t+1} (waves 0-3) | proj_t (waves 4-7), B in regs ----
    if (w < 4) {
      f32x4 acc = {0.f, 0.f, 0.f, 0.f};
#pragma unroll
      for (int kt = 0; kt < 8; ++kt) {
        bf16x8 a = *(const bf16x8*)&s_Ahc[lane & 15][kt * 32 + ((lane >> 4) << 3)];
        acc = MFMA16(a, wb[kt], acc);
      }
      if (lane < 16) {
        int col = w * 16 + lane; float bias = s_web[col];
#pragma unroll
        for (int r = 0; r < BB; ++r) s_base[r][col] = acc[r] + bias;
      }
    } else {
      f32x4 acc = {0.f, 0.f, 0.f, 0.f};
#pragma unroll
      for (int kt = 0; kt < 4; ++kt) {
        bf16x8 a = *(const bf16x8*)&s_Ahc[lane & 15][kt * 32 + ((lane >> 4) << 3)];
        acc = MFMA16(a, wp[kt], acc);
      }
      if (lane < 16) {
        int katt = (w - 4) * 16 + lane;
#pragma unroll
        for (int r = 0; r < BB; ++r) s_projT[r][katt][t] = f2b(acc[r]);
      }
    }
    __syncthreads();                                            // B4
  }

  // ====================== decoder ======================
  {
    int r = tid >> 8, j = tid & 255;                // rows 0..1
    s_Ahc[r][j] = 0;
    if (j < 128) s_A8[r][j] = 0;
    // enc-only LDS constants -> decoder versions (all enc reads happened
    // before the barrier below; saves 4 KB of LDS vs separate arrays)
    s_se[tid]   = sdec[tid];
    s_encb[tid] = dec_bih[tid] + dec_bhh[tid];
  }
  i32x4 wdg[2][8];                      // dec gates i8 (waves 4-7), nt=(w-4)*8+i
  bf16x8 wdc[8];                        // dc bf16 (waves 0-3)
  float yp = 0.f, yhd = 0.f;
  if (w >= 4) {
#pragma unroll
    for (int kt = 0; kt < 2; ++kt)
#pragma unroll
      for (int i = 0; i < 8; ++i)
        wdg[kt][i] = dec8[(kt * 32 + ((w - 4) * 8 + i)) * 64 + lane];
  } else {
#pragma unroll
    for (int kt = 0; kt < 8; ++kt)
      wdc[kt] = *(const bf16x8*)(f16 + WDDC_E + ((kt * 4 + w) * 64 + lane) * 8);
    if (w < BB) {
      yp = y_hist[(b0 + w) * T_ + (T_ - 1)];
      float pp = s_fcw[256 + lane] * y_hist[(b0 + w) * T_ + lane];
      yhd = wsum64(pp) + fc_b[0];
    }
  }
  float dd0 = 0.f, dc0 = 0.f, dd1 = 0.f, dc1 = 0.f;   // d, cc (2 feats/lane)
  __syncthreads();

  for (int hs = 0; hs < HOR_; ++hs) {
    // ---- P_dG: dec gates i8 (waves 4-7) | dc bf16 (waves 0-3) ----
    if (w >= 4) {
      i32x4 a0 = *(const i32x4*)&s_A8[lane & 15][ 0 + ((lane >> 4) << 4)];
      i32x4 a1 = *(const i32x4*)&s_A8[lane & 15][64 + ((lane >> 4) << 4)];
#pragma unroll
      for (int i = 0; i < 8; ++i) {
        i32x4 z = {0, 0, 0, 0};
        i32x4 ac = MFMAI8(a1, wdg[1][i], MFMAI8(a0, wdg[0][i], z));
        if (lane < 16) {
          int col = ((w - 4) * 8 + i) * 16 + lane;
          float sd = s_se[col] * C127;             // dec scales (reloaded)
#pragma unroll
          for (int r = 0; r < BB; ++r) s_gates[r][col] = sd * (float)ac[r];
        }
      }
    } else {
      f32x4 acc = {0.f, 0.f, 0.f, 0.f};
#pragma unroll
      for (int kt = 0; kt < 8; ++kt) {
        bf16x8 a = *(const bf16x8*)&s_Ahc[lane & 15][kt * 32 + ((lane >> 4) << 3)];
        acc = MFMA16(a, wdc[kt], acc);
      }
      if (lane < 16) {
        int col = w * 16 + lane; float bias = s_wdb[col];
#pragma unroll
        for (int r = 0; r < BB; ++r) s_base[r][col] = acc[r] + bias;
      }
    }
    __syncthreads();                                            // B1
    // ---- P_dA: attention + context + epilogue + fc, in-wave (waves 0-1) ----
    if (w < BB) {
      // scores: lane = t'
      float s = 0.f;
#pragma unroll 8
      for (int k = 0; k < 64; ++k)
        s += s_vd[k] * tanh_acc(b2f(s_projT[w][k][lane]) + s_base[w][k]);
      float e = fexp2(s * LOG2E);
      float ssum = wsum64(e);
      s_beta[w][lane] = e * frcp(ssum);
      // context: per lane features j0=lane, j1=lane+64 (same-wave LDS RAW ok)
      float cx0 = 0.f, cx1 = 0.f;
      const short* e0p = &s_encht[w][lane][0];
      const short* e1p = &s_encht[w][lane + 64][0];
#pragma unroll 8
      for (int tp = 0; tp < 64; ++tp) {
        float bta = s_beta[w][tp];
        cx0 = fmaf(bta, b2f(e0p[tp]), cx0);
        cx1 = fmaf(bta, b2f(e1p[tp]), cx1);
      }
      // LSTM epilogue (gates use OLD d via GEMM; +y_prev*dec_Wih)
      float gi0 = s_gates[w][lane]       + s_encb[lane]       + yp * s_dwih[lane];
      float gf0 = s_gates[w][lane + 128] + s_encb[lane + 128] + yp * s_dwih[lane + 128];
      float gg0 = s_gates[w][lane + 256] + s_encb[lane + 256] + yp * s_dwih[lane + 256];
      float go0 = s_gates[w][lane + 384] + s_encb[lane + 384] + yp * s_dwih[lane + 384];
      float gi1 = s_gates[w][lane + 64]  + s_encb[lane + 64]  + yp * s_dwih[lane + 64];
      float gf1 = s_gates[w][lane + 192] + s_encb[lane + 192] + yp * s_dwih[lane + 192];
      float gg1 = s_gates[w][lane + 320] + s_encb[lane + 320] + yp * s_dwih[lane + 320];
      float go1 = s_gates[w][lane + 448] + s_encb[lane + 448] + yp * s_dwih[lane + 448];
      dc0 = sigm(gf0) * dc0 + sigm(gi0) * tanh_acc(gg0);
      dd0 = sigm(go0) * tanh_acc(dc0);
      dc1 = sigm(gf1) * dc1 + sigm(gi1) * tanh_acc(gg1);
      dd1 = sigm(go1) * tanh_acc(dc1);
      // fc
      float pf = s_fcw[lane] * dd0 + s_fcw[64 + lane] * dd1
               + s_fcw[128 + lane] * cx0 + s_fcw[192 + lane] * cx1;
      pf = wsum64(pf);
      float o = pf + yhd;
      if (lane == 0) out[(b0 + w) * HOR_ + hs] = o;
      yp = o;
      // state for next P_dG
      s_Ahc[w][lane]       = f2b(dd0);
      s_Ahc[w][lane + 64]  = f2b(dd1);
      s_Ahc[w][lane + 128] = f2b(dc0);
      s_Ahc[w][lane + 192] = f2b(dc1);
      s_A8[w][lane]      = (char)(int)rintf(dd0 * 127.f);
      s_A8[w][lane + 64] = (char)(int)rintf(dd1 * 127.f);
    }
    __syncthreads();                                            // B2
  }
}

extern "C" void kernel_launch(void* const* d_in, const int* in_sizes, int n_in,
                              void* d_out, int out_size, void* d_ws, size_t ws_size,
                              hipStream_t stream) {
  (void)in_sizes; (void)n_in; (void)out_size; (void)ws_size;
  const float* X       = (const float*)d_in[0];
  const float* y_hist  = (const float*)d_in[1];
  const float* We_w    = (const float*)d_in[2];
  const float* We_b    = (const float*)d_in[3];
  const float* ve_w    = (const float*)d_in[4];
  // d_in[5] = ve_b : softmax-invariant, unused
  const float* enc_Wih = (const float*)d_in[6];
  const float* enc_Whh = (const float*)d_in[7];
  const float* enc_bih = (const float*)d_in[8];
  const float* enc_bhh = (const float*)d_in[9];
  const float* dec_Wih = (const float*)d_in[10];
  const float* dec_Whh = (const float*)d_in[11];
  const float* dec_bih = (const float*)d_in[12];
  const float* dec_bhh = (const float*)d_in[13];
  const float* Wd_w    = (const float*)d_in[14];
  const float* Wd_b    = (const float*)d_in[15];
  const float* vd_w    = (const float*)d_in[16];
  // d_in[17] = vd_b : softmax-invariant, unused
  const float* fc_w    = (const float*)d_in[18];
  const float* fc_b    = (const float*)d_in[19];

  char* ws8  = (char*)d_ws;
  float* out = (float*)d_out;

  prep_bf<<<160, 256, 0, stream>>>(We_w, Wd_w, ws8);
  prep_q <<<256, 256, 0, stream>>>(enc_Wih, enc_Whh, dec_Whh, ws8);
  da_rnn <<<B_ / BB, 512, 0, stream>>>(X, y_hist, We_w, We_b, ve_w,
                                       enc_bih, enc_bhh, dec_Wih, dec_bih, dec_bhh,
                                       Wd_b, vd_w, fc_w, fc_b, ws8, out);
}

// Round 2
// 577.474 us; speedup vs baseline: 1.3004x; 1.3004x over previous
//
#include <hip/hip_runtime.h>
#include <hip/hip_bf16.h>

// DA-RNN persistent kernel, round 8: R7 LDS layout + R6 register budget.
// R7 post-mortem: __launch_bounds__(512,4) halved the arch-VGPR budget to 64
// -> register-resident weights spilled to scratch (FETCH 193MB, WRITE 126MB,
// dur 680us). The LDS shrink (137->77KB) was the real lever: occupancy did
// hit 44% (2 blocks/CU). R8 reverts to __launch_bounds__(512,2) (R6's
// known-good codegen: 100 VGPR, zero spill; 100<=128 still allows 4
// waves/SIMD). 2 chains/CU hide each other's barrier+latency stalls.

#define B_    1024
#define T_    64
#define D_    128
#define H_    128
#define HOR_  24
#define ATT_  64
#define BB    2
#define LOG2E 1.4426950408889634f
#define C127  (1.f/127.f)

typedef float f32x4  __attribute__((ext_vector_type(4)));
typedef short bf16x8 __attribute__((ext_vector_type(8)));
typedef int   i32x4  __attribute__((ext_vector_type(4)));

#define MFMA16(a,b,c) __builtin_amdgcn_mfma_f32_16x16x32_bf16((a),(b),(c),0,0,0)
#define MFMAI8(a,b,c) __builtin_amdgcn_mfma_i32_16x16x64_i8((a),(b),(c),0,0,0)

// ---- workspace layout (same packing as R5/R6) ----
#define WHS_E    0        // base GEMM  B bf16: kt0..7, nt0..3  (16384 el)
#define WDDC_E   16384    // dc GEMM    B bf16: kt0..7, nt0..3  (16384 el)
#define WDENC_E  32768    // proj GEMM  B bf16: kt0..3, nt0..3  ( 8192 el)
#define WENC8_B  81920    // i8 enc gates B: [kt4][nt32][lane64][16] (131072 B)
#define WDEC8_B  212992   // i8 dec gates B: [kt2][nt32][lane64][16] ( 65536 B)
#define SENC_B   278528   // 512 f32 per-col scales (enc)
#define SDEC_B   280576   // 512 f32 per-col scales (dec)

__device__ __forceinline__ short f2b(float f) {        // fp32 -> bf16 RNE
  union { float f; unsigned u; } c; c.f = f;
  unsigned r = c.u + 0x7fffu + ((c.u >> 16) & 1u);
  return (short)(r >> 16);
}
__device__ __forceinline__ float b2f(short s) {
  union { unsigned u; float f; } c; c.u = ((unsigned)(unsigned short)s) << 16;
  return c.f;
}
__device__ __forceinline__ float fexp2(float x) { return __builtin_amdgcn_exp2f(x); }
__device__ __forceinline__ float frcp (float x) { return __builtin_amdgcn_rcpf(x); }
__device__ __forceinline__ float tanh_acc(float x) {   // 1 - 2/(1+e^{2x})
  float e = fexp2(x * 2.885390081777927f);
  return 1.f - 2.f * frcp(1.f + e);
}
__device__ __forceinline__ float sigm(float x) {
  return frcp(1.f + fexp2(-LOG2E * x));
}
__device__ __forceinline__ float wsum64(float v) {
#pragma unroll
  for (int o = 32; o > 0; o >>= 1) v += __shfl_xor(v, o, 64);
  return v;
}
__device__ __forceinline__ float wmax64(float v) {
#pragma unroll
  for (int o = 32; o > 0; o >>= 1) v = fmaxf(v, __shfl_xor(v, o, 64));
  return v;
}

// ---- prep1: bf16 B-frags (base / dc / proj), one element per thread ----
__global__ void prep_bf(const float* __restrict__ We_w,
                        const float* __restrict__ Wd_w,
                        char* __restrict__ ws8) {
  int e = blockIdx.x * 256 + threadIdx.x;
  if (e >= 40960) return;
  short* f16 = (short*)ws8;
  int region = e >> 14;                  // 0=WHS 1=WDDC 2=WDENC
  int er = e & 16383;
  int fi = er >> 9, li = (er >> 3) & 63, jq = er & 7;
  int kt = fi >> 2, nt = fi & 3;
  int k = kt * 32 + ((li >> 4) << 3) + jq, n = nt * 16 + (li & 15);
  float v;
  if (region == 0)      v = We_w[n * 257 + k];
  else if (region == 1) v = (k < 128) ? Wd_w[n * 384 + 128 + k]
                                      : Wd_w[n * 384 + 256 + (k - 128)];
  else                  v = Wd_w[n * 384 + k];
  f16[e] = f2b(v);
}

// ---- prep2: i8 quantized gates weights, one wave per column ----
__global__ void prep_q(const float* __restrict__ enc_Wih,
                       const float* __restrict__ enc_Whh,
                       const float* __restrict__ dec_Whh,
                       char* __restrict__ ws8) {
  int gw = (blockIdx.x * 256 + threadIdx.x) >> 6;
  int lane = threadIdx.x & 63;
  if (gw < 512) {                        // encoder col, K=256
    int n = gw;
    float v[4]; float m = 0.f;
#pragma unroll
    for (int q = 0; q < 4; ++q) {
      int k = lane * 4 + q;
      v[q] = (k < 128) ? enc_Wih[n * 128 + k] : enc_Whh[n * 128 + (k - 128)];
      m = fmaxf(m, fabsf(v[q]));
    }
    m = wmax64(m);
    if (lane == 0) ((float*)(ws8 + SENC_B))[n] = m * C127;
    float inv = m > 0.f ? 127.f / m : 0.f;
    char* dst = ws8 + WENC8_B;
#pragma unroll
    for (int q = 0; q < 4; ++q) {
      int k = lane * 4 + q;
      int kt = k >> 6, grp = (k >> 4) & 3, b = k & 15, l16 = (n & 15) | (grp << 4);
      dst[((kt * 32 + (n >> 4)) * 64 + l16) * 16 + b] = (char)(int)rintf(v[q] * inv);
    }
  } else if (gw < 1024) {                // decoder col, K=128
    int n = gw - 512;
    float v[2]; float m = 0.f;
#pragma unroll
    for (int q = 0; q < 2; ++q) {
      int k = lane * 2 + q;
      v[q] = dec_Whh[n * 128 + k];
      m = fmaxf(m, fabsf(v[q]));
    }
    m = wmax64(m);
    if (lane == 0) ((float*)(ws8 + SDEC_B))[n] = m * C127;
    float inv = m > 0.f ? 127.f / m : 0.f;
    char* dst = ws8 + WDEC8_B;
#pragma unroll
    for (int q = 0; q < 2; ++q) {
      int k = lane * 2 + q;
      int kt = k >> 6, grp = (k >> 4) & 3, b = k & 15, l16 = (n & 15) | (grp << 4);
      dst[((kt * 32 + (n >> 4)) * 64 + l16) * 16 + b] = (char)(int)rintf(v[q] * inv);
    }
  }
}

__global__ __launch_bounds__(512, 2)
void da_rnn(const float* __restrict__ X, const float* __restrict__ y_hist,
            const float* __restrict__ We_w, const float* __restrict__ We_b,
            const float* __restrict__ ve_w,
            const float* __restrict__ enc_bih, const float* __restrict__ enc_bhh,
            const float* __restrict__ dec_Wih,
            const float* __restrict__ dec_bih, const float* __restrict__ dec_bhh,
            const float* __restrict__ Wd_b, const float* __restrict__ vd_w,
            const float* __restrict__ fc_w, const float* __restrict__ fc_b,
            const char* __restrict__ ws8, float* __restrict__ out) {
  const short* f16  = (const short*)ws8;
  const i32x4* enc8 = (const i32x4*)(ws8 + WENC8_B);
  const i32x4* dec8 = (const i32x4*)(ws8 + WDEC8_B);
  const float* senc = (const float*)(ws8 + SENC_B);
  const float* sdec = (const float*)(ws8 + SDEC_B);

  // strides: s_A8 272B=68w (68%32=4 -> 2-way, free); s_Ahc 264sh=132w (4 mod 32)
  __shared__ __align__(16) char  s_A8[16][272];   // gates A i8
  __shared__ __align__(16) short s_Ahc[16][264];  // base/dc/proj A bf16 [h;c]
  __shared__ short s_projT[BB][64][65];           // enc_proj^T
  __shared__ short s_encht[BB][128][66];          // enc_hiddens [r][j][t] bf16
  __shared__ float s_gates[BB][512];
  __shared__ float s_base[BB][64];                // enc: base ; dec: dc
  __shared__ float s_beta[BB][64];
  __shared__ float s_xr[BB];
  __shared__ float2 s_wv[64];                     // (w_feat[k], ve_w[k])
  __shared__ float s_web[64], s_vd[64], s_wdb[64];
  __shared__ float s_se[512];                     // enc scales -> dec scales
  __shared__ float s_encb[512];                   // enc bias   -> dec bias
  __shared__ float s_dwih[512];
  __shared__ float s_fcw[320];

  const int tid  = threadIdx.x;
  const int lane = tid & 63;
  const int w    = tid >> 6;        // wave 0..7 ; waves 0-1 own row w
  const int b0   = blockIdx.x * BB;

  // ---- init ----
  if (tid < 64) {
    s_wv[tid]  = make_float2(We_w[tid * 257 + 256], ve_w[tid]);
    s_web[tid] = We_b[tid];
    s_vd[tid]  = vd_w[tid];
    s_wdb[tid] = Wd_b[tid];
  }
  if (tid < 320) s_fcw[tid] = fc_w[tid];
  s_se[tid]   = senc[tid];
  s_encb[tid] = enc_bih[tid] + enc_bhh[tid];
  s_dwih[tid] = dec_Wih[tid];
  for (int i = tid; i < (16 * 272) / 4; i += 512) ((int*)s_A8)[i] = 0;
  for (int i = tid; i < (16 * 264) / 2; i += 512) ((int*)s_Ahc)[i] = 0;
  if (tid < 64 * BB) s_base[tid >> 6][tid & 63] = We_b[tid & 63];  // base_0

  // ---- register-resident weights (loaded once, L2) ----
  i32x4 wg[4][4];                       // enc gates i8, nt = w + 8i
#pragma unroll
  for (int kt = 0; kt < 4; ++kt)
#pragma unroll
    for (int i = 0; i < 4; ++i)
      wg[kt][i] = enc8[(kt * 32 + (w + 8 * i)) * 64 + lane];
  bf16x8 wb[8], wp[4];
  if (w < 4) {
#pragma unroll
    for (int kt = 0; kt < 8; ++kt)
      wb[kt] = *(const bf16x8*)(f16 + WHS_E + ((kt * 4 + w) * 64 + lane) * 8);
  } else {
#pragma unroll
    for (int kt = 0; kt < 4; ++kt)
      wp[kt] = *(const bf16x8*)(f16 + WDENC_E + ((kt * 4 + (w - 4)) * 64 + lane) * 8);
  }

  // per-row state (waves 0-1): features j0=lane, j1=lane+64
  float h0 = 0.f, c0 = 0.f, h1 = 0.f, c1 = 0.f;
  float x0 = 0.f, x1 = 0.f, xi = 0.f;
  const float* Xr = X + (size_t)(b0 + (w & (BB - 1))) * T_ * D_;
  if (w < BB) {
    x0 = Xr[lane]; x1 = Xr[64 + lane];
    xi = 6.f * cosf((2 * (lane >> 3) + 1) * 0.19634954084936207f);  // node
  }
  __syncthreads();

  // ====================== encoder ======================
  for (int t = 0; t < T_; ++t) {
    // ---- P_A: input attention, in-wave, waves 0-1 (row = w) ----
    if (w < BB) {
      float x0n = 0.f, x1n = 0.f;
      if (t < T_ - 1) { x0n = Xr[(t + 1) * D_ + lane]; x1n = Xr[(t + 1) * D_ + 64 + lane]; }
      // node eval: lane = (ni = lane>>3, kc = lane&7); 8 k-terms each
      const int kc = lane & 7;
      float p = 0.f;
      const float4* wvp = (const float4*)&s_wv[kc * 8];
      const float4* bp  = (const float4*)&s_base[w][kc * 8];
      float4 bA = bp[0], bB = bp[1];
#pragma unroll
      for (int q = 0; q < 4; ++q) {
        float4 wv = wvp[q];                       // (w_k, ve_k, w_{k+1}, ve_{k+1})
        float bb0 = (q < 2) ? ((q & 1) ? bA.z : bA.x) : ((q & 1) ? bB.z : bB.x);
        float bb1 = (q < 2) ? ((q & 1) ? bA.w : bA.y) : ((q & 1) ? bB.w : bB.y);
        p += wv.y * tanh_acc(fmaf(xi, wv.x, bb0));
        p += wv.w * tanh_acc(fmaf(xi, wv.z, bb1));
      }
      p += __shfl_xor(p, 1, 64); p += __shfl_xor(p, 2, 64); p += __shfl_xor(p, 4, 64);
      float f0 = __shfl(p,  0, 64), f1 = __shfl(p,  8, 64);
      float f2 = __shfl(p, 16, 64), f3 = __shfl(p, 24, 64);
      float f4 = __shfl(p, 32, 64), f5 = __shfl(p, 40, 64);
      float f6 = __shfl(p, 48, 64), f7 = __shfl(p, 56, 64);
      // barycentric interpolation at u = clamp(x, +-6), Cheb-1 nodes
      float sc0, sc1;
      {
        const float xb[8] = { 5.884711682f, 4.988817674f, 3.333421398f, 1.170541932f,
                             -1.170541932f, -3.333421398f, -4.988817674f, -5.884711682f};
        const float wbar[8] = { 0.1950903220f, -0.5555702330f, 0.8314696123f, -0.9807852804f,
                                0.9807852804f, -0.8314696123f, 0.5555702330f, -0.1950903220f};
        float u0 = fminf(fmaxf(x0, -6.f), 6.f), u1 = fminf(fmaxf(x1, -6.f), 6.f);
        float n0 = 0.f, d0 = 0.f, n1 = 0.f, d1 = 0.f;
        float fv[8] = {f0, f1, f2, f3, f4, f5, f6, f7};
#pragma unroll
        for (int i = 0; i < 8; ++i) {
          float dd0 = u0 - xb[i]; dd0 = copysignf(fmaxf(fabsf(dd0), 1e-5f), dd0);
          float dd1 = u1 - xb[i]; dd1 = copysignf(fmaxf(fabsf(dd1), 1e-5f), dd1);
          float t0 = wbar[i] * frcp(dd0), t1 = wbar[i] * frcp(dd1);
          n0 = fmaf(t0, fv[i], n0); d0 += t0;
          n1 = fmaf(t1, fv[i], n1); d1 += t1;
        }
        sc0 = n0 * frcp(d0); sc1 = n1 * frcp(d1);
      }
      float e0 = fexp2(sc0 * LOG2E), e1 = fexp2(sc1 * LOG2E);  // |sc|<=sum|ve|~2.6
      float sum = wsum64(e0 + e1);
      float mx  = wmax64(fmaxf(e0 * fabsf(x0), e1 * fabsf(x1)));
      float inv = mx > 0.f ? 127.f * frcp(mx) : 0.f;
      s_A8[w][lane]      = (char)(int)rintf(x0 * e0 * inv);
      s_A8[w][64 + lane] = (char)(int)rintf(x1 * e1 * inv);
      if (lane == 0) s_xr[w] = mx * frcp(127.f * sum);
      x0 = x0n; x1 = x1n;
    }
    __syncthreads();                                            // B1
    // ---- P_G: gates i8 GEMM, all 8 waves, weights in registers ----
    {
      i32x4 a0 = *(const i32x4*)&s_A8[lane & 15][  0 + ((lane >> 4) << 4)];
      i32x4 a1 = *(const i32x4*)&s_A8[lane & 15][ 64 + ((lane >> 4) << 4)];
      i32x4 a2 = *(const i32x4*)&s_A8[lane & 15][128 + ((lane >> 4) << 4)];
      i32x4 a3 = *(const i32x4*)&s_A8[lane & 15][192 + ((lane >> 4) << 4)];
      i32x4 ax[4], ah[4];
#pragma unroll
      for (int i = 0; i < 4; ++i) {
        i32x4 z = {0, 0, 0, 0};
        ax[i] = MFMAI8(a1, wg[1][i], MFMAI8(a0, wg[0][i], z));
        ah[i] = MFMAI8(a3, wg[3][i], MFMAI8(a2, wg[2][i], z));
      }
      if (lane < 16) {
        float sx0 = s_xr[0], sx1 = s_xr[1];
#pragma unroll
        for (int i = 0; i < 4; ++i) {
          int col = (w + 8 * i) * 16 + lane;
          float se = s_se[col];
          s_gates[0][col] = se * fmaf(sx0, (float)ax[i][0], C127 * (float)ah[i][0]);
          s_gates[1][col] = se * fmaf(sx1, (float)ax[i][1], C127 * (float)ah[i][1]);
        }
      }
    }
    __syncthreads();                                            // B2
    // ---- P_E: LSTM epilogue, in-wave, waves 0-1 (2 features/lane) ----
    if (w < BB) {
      float gi0 = s_gates[w][lane]       + s_encb[lane];
      float gf0 = s_gates[w][lane + 128] + s_encb[lane + 128];
      float gg0 = s_gates[w][lane + 256] + s_encb[lane + 256];
      float go0 = s_gates[w][lane + 384] + s_encb[lane + 384];
      float gi1 = s_gates[w][lane + 64]  + s_encb[lane + 64];
      float gf1 = s_gates[w][lane + 192] + s_encb[lane + 192];
      float gg1 = s_gates[w][lane + 320] + s_encb[lane + 320];
      float go1 = s_gates[w][lane + 448] + s_encb[lane + 448];
      c0 = sigm(gf0) * c0 + sigm(gi0) * tanh_acc(gg0);
      h0 = sigm(go0) * tanh_acc(c0);
      c1 = sigm(gf1) * c1 + sigm(gi1) * tanh_acc(gg1);
      h1 = sigm(go1) * tanh_acc(c1);
      s_Ahc[w][lane]        = f2b(h0);
      s_Ahc[w][lane + 64]   = f2b(h1);
      s_Ahc[w][lane + 128]  = f2b(c0);
      s_Ahc[w][lane + 192]  = f2b(c1);
      s_A8[w][128 + lane]      = (char)(int)rintf(h0 * 127.f);
      s_A8[w][128 + lane + 64] = (char)(int)rintf(h1 * 127.f);
      s_encht[w][lane][t]      = f2b(h0);
      s_encht[w][lane + 64][t] = f2b(h1);
    }
    __syncthreads();                                            // B3
    // ---- P_B: base_{t+1} (waves 0-3) | proj_t (waves 4-7), B in regs ----
    if (w < 4) {
      f32x4 acc = {0.f, 0.f, 0.f, 0.f};
#pragma unroll
      for (int kt = 0; kt < 8; ++kt) {
        bf16x8 a = *(const bf16x8*)&s_Ahc[lane & 15][kt * 32 + ((lane >> 4) << 3)];
        acc = MFMA16(a, wb[kt], acc);
      }
      if (lane < 16) {
        int col = w * 16 + lane; float bias = s_web[col];
#pragma unroll
        for (int r = 0; r < BB; ++r) s_base[r][col] = acc[r] + bias;
      }
    } else {
      f32x4 acc = {0.f, 0.f, 0.f, 0.f};
#pragma unroll
      for (int kt = 0; kt < 4; ++kt) {
        bf16x8 a = *(const bf16x8*)&s_Ahc[lane & 15][kt * 32 + ((lane >> 4) << 3)];
        acc = MFMA16(a, wp[kt], acc);
      }
      if (lane < 16) {
        int katt = (w - 4) * 16 + lane;
#pragma unroll
        for (int r = 0; r < BB; ++r) s_projT[r][katt][t] = f2b(acc[r]);
      }
    }
    __syncthreads();                                            // B4
  }

  // ====================== decoder ======================
  {
    int r = tid >> 8, j = tid & 255;                // rows 0..1
    s_Ahc[r][j] = 0;
    if (j < 128) s_A8[r][j] = 0;
    // enc-only LDS constants -> decoder versions (all enc reads happened
    // before the barrier below; saves 4 KB of LDS vs separate arrays)
    s_se[tid]   = sdec[tid];
    s_encb[tid] = dec_bih[tid] + dec_bhh[tid];
  }
  i32x4 wdg[2][8];                      // dec gates i8 (waves 4-7), nt=(w-4)*8+i
  bf16x8 wdc[8];                        // dc bf16 (waves 0-3)
  float yp = 0.f, yhd = 0.f;
  if (w >= 4) {
#pragma unroll
    for (int kt = 0; kt < 2; ++kt)
#pragma unroll
      for (int i = 0; i < 8; ++i)
        wdg[kt][i] = dec8[(kt * 32 + ((w - 4) * 8 + i)) * 64 + lane];
  } else {
#pragma unroll
    for (int kt = 0; kt < 8; ++kt)
      wdc[kt] = *(const bf16x8*)(f16 + WDDC_E + ((kt * 4 + w) * 64 + lane) * 8);
    if (w < BB) {
      yp = y_hist[(b0 + w) * T_ + (T_ - 1)];
      float pp = s_fcw[256 + lane] * y_hist[(b0 + w) * T_ + lane];
      yhd = wsum64(pp) + fc_b[0];
    }
  }
  float dd0 = 0.f, dc0 = 0.f, dd1 = 0.f, dc1 = 0.f;   // d, cc (2 feats/lane)
  __syncthreads();

  for (int hs = 0; hs < HOR_; ++hs) {
    // ---- P_dG: dec gates i8 (waves 4-7) | dc bf16 (waves 0-3) ----
    if (w >= 4) {
      i32x4 a0 = *(const i32x4*)&s_A8[lane & 15][ 0 + ((lane >> 4) << 4)];
      i32x4 a1 = *(const i32x4*)&s_A8[lane & 15][64 + ((lane >> 4) << 4)];
#pragma unroll
      for (int i = 0; i < 8; ++i) {
        i32x4 z = {0, 0, 0, 0};
        i32x4 ac = MFMAI8(a1, wdg[1][i], MFMAI8(a0, wdg[0][i], z));
        if (lane < 16) {
          int col = ((w - 4) * 8 + i) * 16 + lane;
          float sd = s_se[col] * C127;             // dec scales (reloaded)
#pragma unroll
          for (int r = 0; r < BB; ++r) s_gates[r][col] = sd * (float)ac[r];
        }
      }
    } else {
      f32x4 acc = {0.f, 0.f, 0.f, 0.f};
#pragma unroll
      for (int kt = 0; kt < 8; ++kt) {
        bf16x8 a = *(const bf16x8*)&s_Ahc[lane & 15][kt * 32 + ((lane >> 4) << 3)];
        acc = MFMA16(a, wdc[kt], acc);
      }
      if (lane < 16) {
        int col = w * 16 + lane; float bias = s_wdb[col];
#pragma unroll
        for (int r = 0; r < BB; ++r) s_base[r][col] = acc[r] + bias;
      }
    }
    __syncthreads();                                            // B1
    // ---- P_dA: attention + context + epilogue + fc, in-wave (waves 0-1) ----
    if (w < BB) {
      // scores: lane = t'
      float s = 0.f;
#pragma unroll 8
      for (int k = 0; k < 64; ++k)
        s += s_vd[k] * tanh_acc(b2f(s_projT[w][k][lane]) + s_base[w][k]);
      float e = fexp2(s * LOG2E);
      float ssum = wsum64(e);
      s_beta[w][lane] = e * frcp(ssum);
      // context: per lane features j0=lane, j1=lane+64 (same-wave LDS RAW ok)
      float cx0 = 0.f, cx1 = 0.f;
      const short* e0p = &s_encht[w][lane][0];
      const short* e1p = &s_encht[w][lane + 64][0];
#pragma unroll 8
      for (int tp = 0; tp < 64; ++tp) {
        float bta = s_beta[w][tp];
        cx0 = fmaf(bta, b2f(e0p[tp]), cx0);
        cx1 = fmaf(bta, b2f(e1p[tp]), cx1);
      }
      // LSTM epilogue (gates use OLD d via GEMM; +y_prev*dec_Wih)
      float gi0 = s_gates[w][lane]       + s_encb[lane]       + yp * s_dwih[lane];
      float gf0 = s_gates[w][lane + 128] + s_encb[lane + 128] + yp * s_dwih[lane + 128];
      float gg0 = s_gates[w][lane + 256] + s_encb[lane + 256] + yp * s_dwih[lane + 256];
      float go0 = s_gates[w][lane + 384] + s_encb[lane + 384] + yp * s_dwih[lane + 384];
      float gi1 = s_gates[w][lane + 64]  + s_encb[lane + 64]  + yp * s_dwih[lane + 64];
      float gf1 = s_gates[w][lane + 192] + s_encb[lane + 192] + yp * s_dwih[lane + 192];
      float gg1 = s_gates[w][lane + 320] + s_encb[lane + 320] + yp * s_dwih[lane + 320];
      float go1 = s_gates[w][lane + 448] + s_encb[lane + 448] + yp * s_dwih[lane + 448];
      dc0 = sigm(gf0) * dc0 + sigm(gi0) * tanh_acc(gg0);
      dd0 = sigm(go0) * tanh_acc(dc0);
      dc1 = sigm(gf1) * dc1 + sigm(gi1) * tanh_acc(gg1);
      dd1 = sigm(go1) * tanh_acc(dc1);
      // fc
      float pf = s_fcw[lane] * dd0 + s_fcw[64 + lane] * dd1
               + s_fcw[128 + lane] * cx0 + s_fcw[192 + lane] * cx1;
      pf = wsum64(pf);
      float o = pf + yhd;
      if (lane == 0) out[(b0 + w) * HOR_ + hs] = o;
      yp = o;
      // state for next P_dG
      s_Ahc[w][lane]       = f2b(dd0);
      s_Ahc[w][lane + 64]  = f2b(dd1);
      s_Ahc[w][lane + 128] = f2b(dc0);
      s_Ahc[w][lane + 192] = f2b(dc1);
      s_A8[w][lane]      = (char)(int)rintf(dd0 * 127.f);
      s_A8[w][lane + 64] = (char)(int)rintf(dd1 * 127.f);
    }
    __syncthreads();                                            // B2
  }
}

extern "C" void kernel_launch(void* const* d_in, const int* in_sizes, int n_in,
                              void* d_out, int out_size, void* d_ws, size_t ws_size,
                              hipStream_t stream) {
  (void)in_sizes; (void)n_in; (void)out_size; (void)ws_size;
  const float* X       = (const float*)d_in[0];
  const float* y_hist  = (const float*)d_in[1];
  const float* We_w    = (const float*)d_in[2];
  const float* We_b    = (const float*)d_in[3];
  const float* ve_w    = (const float*)d_in[4];
  // d_in[5] = ve_b : softmax-invariant, unused
  const float* enc_Wih = (const float*)d_in[6];
  const float* enc_Whh = (const float*)d_in[7];
  const float* enc_bih = (const float*)d_in[8];
  const float* enc_bhh = (const float*)d_in[9];
  const float* dec_Wih = (const float*)d_in[10];
  const float* dec_Whh = (const float*)d_in[11];
  const float* dec_bih = (const float*)d_in[12];
  const float* dec_bhh = (const float*)d_in[13];
  const float* Wd_w    = (const float*)d_in[14];
  const float* Wd_b    = (const float*)d_in[15];
  const float* vd_w    = (const float*)d_in[16];
  // d_in[17] = vd_b : softmax-invariant, unused
  const float* fc_w    = (const float*)d_in[18];
  const float* fc_b    = (const float*)d_in[19];

  char* ws8  = (char*)d_ws;
  float* out = (float*)d_out;

  prep_bf<<<160, 256, 0, stream>>>(We_w, Wd_w, ws8);
  prep_q <<<256, 256, 0, stream>>>(enc_Wih, enc_Whh, dec_Whh, ws8);
  da_rnn <<<B_ / BB, 512, 0, stream>>>(X, y_hist, We_w, We_b, ve_w,
                                       enc_bih, enc_bhh, dec_Wih, dec_bih, dec_bhh,
                                       Wd_b, vd_w, fc_w, fc_b, ws8, out);
}

// Round 3
// 381.271 us; speedup vs baseline: 1.9696x; 1.5146x over previous
//
#include <hip/hip_runtime.h>
#include <hip/hip_bf16.h>

// DA-RNN persistent kernel, round 9: chain-shortening via fused gates+epilogue.
// R8 post-mortem: 2-blocks/CU is a dead end — the chain is LATENCY-bound
// (BB=2 chain ~255us ~= BB=4 chain 275us; R8's 510 = 2 serialized rounds).
// Only lever: shorten the serial chain. Key fact: wave w's 4 gate tiles
// (nt=w+8i) are exactly gates i,f,g,o of features 16w..16w+15 -> LSTM
// epilogue runs IN-WAVE after the MFMA, c-state register-resident.
//  - encoder: 4 -> 3 barriers, s_gates LDS round-trip removed
//  - decoder: feature-aligned tile remap (tile=8q+2j+s); epilogue moves to
//    waves 4-7 phase 1 (parallel with dc GEMM), d2 via f32 LDS, yp via s_yp
//  - 8-deep chained MFMA accs split into 4+4 (less dependent latency)
// BB=4, 256 blocks, __launch_bounds__(512,2): proven no-spill regime.

#define B_    1024
#define T_    64
#define D_    128
#define H_    128
#define HOR_  24
#define ATT_  64
#define BB    4
#define LOG2E 1.4426950408889634f
#define C127  (1.f/127.f)

typedef float f32x4  __attribute__((ext_vector_type(4)));
typedef short bf16x8 __attribute__((ext_vector_type(8)));
typedef int   i32x4  __attribute__((ext_vector_type(4)));

#define MFMA16(a,b,c) __builtin_amdgcn_mfma_f32_16x16x32_bf16((a),(b),(c),0,0,0)
#define MFMAI8(a,b,c) __builtin_amdgcn_mfma_i32_16x16x64_i8((a),(b),(c),0,0,0)

// ---- workspace layout (same packing as R5..R8) ----
#define WHS_E    0        // base GEMM  B bf16: kt0..7, nt0..3  (16384 el)
#define WDDC_E   16384    // dc GEMM    B bf16: kt0..7, nt0..3  (16384 el)
#define WDENC_E  32768    // proj GEMM  B bf16: kt0..3, nt0..3  ( 8192 el)
#define WENC8_B  81920    // i8 enc gates B: [kt4][nt32][lane64][16] (131072 B)
#define WDEC8_B  212992   // i8 dec gates B: [kt2][nt32][lane64][16] ( 65536 B)
#define SENC_B   278528   // 512 f32 per-col scales (enc)
#define SDEC_B   280576   // 512 f32 per-col scales (dec)

__device__ __forceinline__ short f2b(float f) {        // fp32 -> bf16 RNE
  union { float f; unsigned u; } c; c.f = f;
  unsigned r = c.u + 0x7fffu + ((c.u >> 16) & 1u);
  return (short)(r >> 16);
}
__device__ __forceinline__ float b2f(short s) {
  union { unsigned u; float f; } c; c.u = ((unsigned)(unsigned short)s) << 16;
  return c.f;
}
__device__ __forceinline__ float fexp2(float x) { return __builtin_amdgcn_exp2f(x); }
__device__ __forceinline__ float frcp (float x) { return __builtin_amdgcn_rcpf(x); }
__device__ __forceinline__ float tanh_acc(float x) {   // 1 - 2/(1+e^{2x})
  float e = fexp2(x * 2.885390081777927f);
  return 1.f - 2.f * frcp(1.f + e);
}
__device__ __forceinline__ float sigm(float x) {
  return frcp(1.f + fexp2(-LOG2E * x));
}
__device__ __forceinline__ float wsum64(float v) {
#pragma unroll
  for (int o = 32; o > 0; o >>= 1) v += __shfl_xor(v, o, 64);
  return v;
}
__device__ __forceinline__ float wmax64(float v) {
#pragma unroll
  for (int o = 32; o > 0; o >>= 1) v = fmaxf(v, __shfl_xor(v, o, 64));
  return v;
}

// ---- prep1: bf16 B-frags (base / dc / proj), one element per thread ----
__global__ void prep_bf(const float* __restrict__ We_w,
                        const float* __restrict__ Wd_w,
                        char* __restrict__ ws8) {
  int e = blockIdx.x * 256 + threadIdx.x;
  if (e >= 40960) return;
  short* f16 = (short*)ws8;
  int region = e >> 14;                  // 0=WHS 1=WDDC 2=WDENC
  int er = e & 16383;
  int fi = er >> 9, li = (er >> 3) & 63, jq = er & 7;
  int kt = fi >> 2, nt = fi & 3;
  int k = kt * 32 + ((li >> 4) << 3) + jq, n = nt * 16 + (li & 15);
  float v;
  if (region == 0)      v = We_w[n * 257 + k];
  else if (region == 1) v = (k < 128) ? Wd_w[n * 384 + 128 + k]
                                      : Wd_w[n * 384 + 256 + (k - 128)];
  else                  v = Wd_w[n * 384 + k];
  f16[e] = f2b(v);
}

// ---- prep2: i8 quantized gates weights, one wave per column ----
__global__ void prep_q(const float* __restrict__ enc_Wih,
                       const float* __restrict__ enc_Whh,
                       const float* __restrict__ dec_Whh,
                       char* __restrict__ ws8) {
  int gw = (blockIdx.x * 256 + threadIdx.x) >> 6;
  int lane = threadIdx.x & 63;
  if (gw < 512) {                        // encoder col, K=256
    int n = gw;
    float v[4]; float m = 0.f;
#pragma unroll
    for (int q = 0; q < 4; ++q) {
      int k = lane * 4 + q;
      v[q] = (k < 128) ? enc_Wih[n * 128 + k] : enc_Whh[n * 128 + (k - 128)];
      m = fmaxf(m, fabsf(v[q]));
    }
    m = wmax64(m);
    if (lane == 0) ((float*)(ws8 + SENC_B))[n] = m * C127;
    float inv = m > 0.f ? 127.f / m : 0.f;
    char* dst = ws8 + WENC8_B;
#pragma unroll
    for (int q = 0; q < 4; ++q) {
      int k = lane * 4 + q;
      int kt = k >> 6, grp = (k >> 4) & 3, b = k & 15, l16 = (n & 15) | (grp << 4);
      dst[((kt * 32 + (n >> 4)) * 64 + l16) * 16 + b] = (char)(int)rintf(v[q] * inv);
    }
  } else if (gw < 1024) {                // decoder col, K=128
    int n = gw - 512;
    float v[2]; float m = 0.f;
#pragma unroll
    for (int q = 0; q < 2; ++q) {
      int k = lane * 2 + q;
      v[q] = dec_Whh[n * 128 + k];
      m = fmaxf(m, fabsf(v[q]));
    }
    m = wmax64(m);
    if (lane == 0) ((float*)(ws8 + SDEC_B))[n] = m * C127;
    float inv = m > 0.f ? 127.f / m : 0.f;
    char* dst = ws8 + WDEC8_B;
#pragma unroll
    for (int q = 0; q < 2; ++q) {
      int k = lane * 2 + q;
      int kt = k >> 6, grp = (k >> 4) & 3, b = k & 15, l16 = (n & 15) | (grp << 4);
      dst[((kt * 32 + (n >> 4)) * 64 + l16) * 16 + b] = (char)(int)rintf(v[q] * inv);
    }
  }
}

__global__ __launch_bounds__(512, 2)
void da_rnn(const float* __restrict__ X, const float* __restrict__ y_hist,
            const float* __restrict__ We_w, const float* __restrict__ We_b,
            const float* __restrict__ ve_w,
            const float* __restrict__ enc_bih, const float* __restrict__ enc_bhh,
            const float* __restrict__ dec_Wih,
            const float* __restrict__ dec_bih, const float* __restrict__ dec_bhh,
            const float* __restrict__ Wd_b, const float* __restrict__ vd_w,
            const float* __restrict__ fc_w, const float* __restrict__ fc_b,
            const char* __restrict__ ws8, float* __restrict__ out) {
  const short* f16  = (const short*)ws8;
  const i32x4* enc8 = (const i32x4*)(ws8 + WENC8_B);
  const i32x4* dec8 = (const i32x4*)(ws8 + WDEC8_B);
  const float* senc = (const float*)(ws8 + SENC_B);
  const float* sdec = (const float*)(ws8 + SDEC_B);

  // strides: s_A8 272B=68w (68%32=4 -> 2-way, free); s_Ahc 264sh=132w (4 mod 32)
  __shared__ __align__(16) char  s_A8[16][272];   // gates A i8
  __shared__ __align__(16) short s_Ahc[16][264];  // base/dc/proj A bf16 [h;c]
  __shared__ short s_projT[BB][64][65];           // enc_proj^T
  __shared__ short s_encht[BB][128][66];          // enc_hiddens [r][j][t] bf16
  __shared__ float s_d2[BB][128];                 // dec d2 (f32, for fc)
  __shared__ float s_base[BB][64];                // enc: base ; dec: dc
  __shared__ float s_beta[BB][64];
  __shared__ float s_xr[BB];
  __shared__ float s_yp[BB];
  __shared__ float2 s_wv[64];                     // (w_feat[k], ve_w[k])
  __shared__ float s_web[64], s_vd[64], s_wdb[64];
  __shared__ float s_se[512];                     // enc scales -> dec scales
  __shared__ float s_encb[512];                   // enc bias   -> dec bias
  __shared__ float s_dwih[512];
  __shared__ float s_fcw[320];

  const int tid  = threadIdx.x;
  const int lane = tid & 63;
  const int w    = tid >> 6;        // wave 0..7 ; waves 0-3 own row w
  const int b0   = blockIdx.x * BB;

  // ---- init ----
  if (tid < 64) {
    s_wv[tid]  = make_float2(We_w[tid * 257 + 256], ve_w[tid]);
    s_web[tid] = We_b[tid];
    s_vd[tid]  = vd_w[tid];
    s_wdb[tid] = Wd_b[tid];
  }
  if (tid < 320) s_fcw[tid] = fc_w[tid];
  s_se[tid]   = senc[tid];
  s_encb[tid] = enc_bih[tid] + enc_bhh[tid];
  s_dwih[tid] = dec_Wih[tid];
  for (int i = tid; i < (16 * 272) / 4; i += 512) ((int*)s_A8)[i] = 0;
  for (int i = tid; i < (16 * 264) / 2; i += 512) ((int*)s_Ahc)[i] = 0;
  if (tid < 64 * BB) s_base[tid >> 6][tid & 63] = We_b[tid & 63];  // base_0

  // ---- register-resident weights (loaded once, L2) ----
  i32x4 wg[4][4];                       // enc gates i8, nt = w + 8i
#pragma unroll
  for (int kt = 0; kt < 4; ++kt)
#pragma unroll
    for (int i = 0; i < 4; ++i)
      wg[kt][i] = enc8[(kt * 32 + (w + 8 * i)) * 64 + lane];
  bf16x8 wb[8], wp[4];
  if (w < 4) {
#pragma unroll
    for (int kt = 0; kt < 8; ++kt)
      wb[kt] = *(const bf16x8*)(f16 + WHS_E + ((kt * 4 + w) * 64 + lane) * 8);
  } else {
#pragma unroll
    for (int kt = 0; kt < 4; ++kt)
      wp[kt] = *(const bf16x8*)(f16 + WDENC_E + ((kt * 4 + (w - 4)) * 64 + lane) * 8);
  }

  // per-row attention state (waves 0-3): features j0=lane, j1=lane+64
  float x0 = 0.f, x1 = 0.f, xi = 0.f;
  const float* Xr = X + (size_t)(b0 + (w & (BB - 1))) * T_ * D_;
  if (w < BB) {
    x0 = Xr[lane]; x1 = Xr[64 + lane];
    xi = 6.f * cosf((2 * (lane >> 3) + 1) * 0.19634954084936207f);  // node
  }
  // per-feature LSTM c-state (all waves, lanes<16): feature f = 16w+lane
  float cst[BB] = {0.f, 0.f, 0.f, 0.f};
  __syncthreads();

  // ====================== encoder ======================
  for (int t = 0; t < T_; ++t) {
    // ---- P_A: input attention, in-wave, waves 0-3 (row = w) ----
    if (w < BB) {
      float x0n = 0.f, x1n = 0.f;
      if (t < T_ - 1) { x0n = Xr[(t + 1) * D_ + lane]; x1n = Xr[(t + 1) * D_ + 64 + lane]; }
      // node eval: lane = (ni = lane>>3, kc = lane&7); 8 k-terms each
      const int kc = lane & 7;
      float p = 0.f;
      const float4* wvp = (const float4*)&s_wv[kc * 8];
      const float4* bp  = (const float4*)&s_base[w][kc * 8];
      float4 bA = bp[0], bB = bp[1];
#pragma unroll
      for (int q = 0; q < 4; ++q) {
        float4 wv = wvp[q];                       // (w_k, ve_k, w_{k+1}, ve_{k+1})
        float bb0 = (q < 2) ? ((q & 1) ? bA.z : bA.x) : ((q & 1) ? bB.z : bB.x);
        float bb1 = (q < 2) ? ((q & 1) ? bA.w : bA.y) : ((q & 1) ? bB.w : bB.y);
        p += wv.y * tanh_acc(fmaf(xi, wv.x, bb0));
        p += wv.w * tanh_acc(fmaf(xi, wv.z, bb1));
      }
      p += __shfl_xor(p, 1, 64); p += __shfl_xor(p, 2, 64); p += __shfl_xor(p, 4, 64);
      float f0 = __shfl(p,  0, 64), f1 = __shfl(p,  8, 64);
      float f2 = __shfl(p, 16, 64), f3 = __shfl(p, 24, 64);
      float f4 = __shfl(p, 32, 64), f5 = __shfl(p, 40, 64);
      float f6 = __shfl(p, 48, 64), f7 = __shfl(p, 56, 64);
      // barycentric interpolation at u = clamp(x, +-6), Cheb-1 nodes
      float sc0, sc1;
      {
        const float xb[8] = { 5.884711682f, 4.988817674f, 3.333421398f, 1.170541932f,
                             -1.170541932f, -3.333421398f, -4.988817674f, -5.884711682f};
        const float wbar[8] = { 0.1950903220f, -0.5555702330f, 0.8314696123f, -0.9807852804f,
                                0.9807852804f, -0.8314696123f, 0.5555702330f, -0.1950903220f};
        float u0 = fminf(fmaxf(x0, -6.f), 6.f), u1 = fminf(fmaxf(x1, -6.f), 6.f);
        float n0 = 0.f, d0 = 0.f, n1 = 0.f, d1 = 0.f;
        float fv[8] = {f0, f1, f2, f3, f4, f5, f6, f7};
#pragma unroll
        for (int i = 0; i < 8; ++i) {
          float dd0 = u0 - xb[i]; dd0 = copysignf(fmaxf(fabsf(dd0), 1e-5f), dd0);
          float dd1 = u1 - xb[i]; dd1 = copysignf(fmaxf(fabsf(dd1), 1e-5f), dd1);
          float t0 = wbar[i] * frcp(dd0), t1 = wbar[i] * frcp(dd1);
          n0 = fmaf(t0, fv[i], n0); d0 += t0;
          n1 = fmaf(t1, fv[i], n1); d1 += t1;
        }
        sc0 = n0 * frcp(d0); sc1 = n1 * frcp(d1);
      }
      float e0 = fexp2(sc0 * LOG2E), e1 = fexp2(sc1 * LOG2E);  // |sc|<=sum|ve|~2.6
      float sum = wsum64(e0 + e1);
      float mx  = wmax64(fmaxf(e0 * fabsf(x0), e1 * fabsf(x1)));
      float inv = mx > 0.f ? 127.f * frcp(mx) : 0.f;
      s_A8[w][lane]      = (char)(int)rintf(x0 * e0 * inv);
      s_A8[w][64 + lane] = (char)(int)rintf(x1 * e1 * inv);
      if (lane == 0) s_xr[w] = mx * frcp(127.f * sum);
      x0 = x0n; x1 = x1n;
    }
    __syncthreads();                                            // B1
    // ---- P_GE: gates i8 GEMM + FUSED LSTM epilogue (all 8 waves) ----
    // wave w's tiles nt=w+8i are gates i,f,g,o of features 16w..16w+15
    {
      i32x4 a0 = *(const i32x4*)&s_A8[lane & 15][  0 + ((lane >> 4) << 4)];
      i32x4 a1 = *(const i32x4*)&s_A8[lane & 15][ 64 + ((lane >> 4) << 4)];
      i32x4 a2 = *(const i32x4*)&s_A8[lane & 15][128 + ((lane >> 4) << 4)];
      i32x4 a3 = *(const i32x4*)&s_A8[lane & 15][192 + ((lane >> 4) << 4)];
      i32x4 ax[4], ah[4];
#pragma unroll
      for (int i = 0; i < 4; ++i) {
        i32x4 z = {0, 0, 0, 0};
        ax[i] = MFMAI8(a1, wg[1][i], MFMAI8(a0, wg[0][i], z));
        ah[i] = MFMAI8(a3, wg[3][i], MFMAI8(a2, wg[2][i], z));
      }
      if (lane < 16) {
        const int f = (w << 4) + lane;               // feature 0..127
        float se0 = s_se[f],       se1 = s_se[128 + f];
        float se2 = s_se[256 + f], se3 = s_se[384 + f];
        float eb0 = s_encb[f],       eb1 = s_encb[128 + f];
        float eb2 = s_encb[256 + f], eb3 = s_encb[384 + f];
#pragma unroll
        for (int r = 0; r < BB; ++r) {
          float sx = s_xr[r];
          float gi = se0 * fmaf(sx, (float)ax[0][r], C127 * (float)ah[0][r]) + eb0;
          float gf = se1 * fmaf(sx, (float)ax[1][r], C127 * (float)ah[1][r]) + eb1;
          float gg = se2 * fmaf(sx, (float)ax[2][r], C127 * (float)ah[2][r]) + eb2;
          float go = se3 * fmaf(sx, (float)ax[3][r], C127 * (float)ah[3][r]) + eb3;
          cst[r] = sigm(gf) * cst[r] + sigm(gi) * tanh_acc(gg);
          float h = sigm(go) * tanh_acc(cst[r]);
          s_Ahc[r][f]          = f2b(h);
          s_Ahc[r][128 + f]    = f2b(cst[r]);
          s_A8[r][128 + f]     = (char)(int)rintf(h * 127.f);
          s_encht[r][f][t]     = f2b(h);
        }
      }
    }
    __syncthreads();                                            // B2
    // ---- P_B: base_{t+1} (waves 0-3) | proj_t (waves 4-7), B in regs ----
    if (w < 4) {
      f32x4 acc = {0.f, 0.f, 0.f, 0.f}, acc2 = {0.f, 0.f, 0.f, 0.f};
#pragma unroll
      for (int kt = 0; kt < 4; ++kt) {
        bf16x8 a = *(const bf16x8*)&s_Ahc[lane & 15][kt * 32 + ((lane >> 4) << 3)];
        acc = MFMA16(a, wb[kt], acc);
      }
#pragma unroll
      for (int kt = 4; kt < 8; ++kt) {
        bf16x8 a = *(const bf16x8*)&s_Ahc[lane & 15][kt * 32 + ((lane >> 4) << 3)];
        acc2 = MFMA16(a, wb[kt], acc2);
      }
      if (lane < 16) {
        int col = w * 16 + lane; float bias = s_web[col];
#pragma unroll
        for (int r = 0; r < BB; ++r) s_base[r][col] = acc[r] + acc2[r] + bias;
      }
    } else {
      f32x4 acc = {0.f, 0.f, 0.f, 0.f};
#pragma unroll
      for (int kt = 0; kt < 4; ++kt) {
        bf16x8 a = *(const bf16x8*)&s_Ahc[lane & 15][kt * 32 + ((lane >> 4) << 3)];
        acc = MFMA16(a, wp[kt], acc);
      }
      if (lane < 16) {
        int katt = (w - 4) * 16 + lane;
#pragma unroll
        for (int r = 0; r < BB; ++r) s_projT[r][katt][t] = f2b(acc[r]);
      }
    }
    __syncthreads();                                            // B3
  }

  // ====================== decoder ======================
  {
    int r = tid >> 7, j = tid & 127;
    s_Ahc[r][j] = 0; s_Ahc[r][128 + j] = 0; s_A8[r][j] = 0;
    // enc-only LDS constants -> decoder versions (all enc reads are behind
    // at least one barrier already; saves 4 KB of LDS vs separate arrays)
    s_se[tid]   = sdec[tid];
    s_encb[tid] = dec_bih[tid] + dec_bhh[tid];
  }
  // dec gates i8 (waves 4-7), feature-aligned: tile = 8q + 2j + s
  i32x4 wdg[2][8];                      // [kt][q*2+s]
  bf16x8 wdc[8];                        // dc bf16 (waves 0-3)
  float yp = 0.f, yhd = 0.f;
  float ccs[2][BB];                     // dec cc state (waves 4-7, lanes<16)
#pragma unroll
  for (int s = 0; s < 2; ++s)
#pragma unroll
    for (int r = 0; r < BB; ++r) ccs[s][r] = 0.f;
  if (w >= 4) {
    int j = w - 4;
#pragma unroll
    for (int kt = 0; kt < 2; ++kt)
#pragma unroll
      for (int q = 0; q < 4; ++q)
#pragma unroll
        for (int s = 0; s < 2; ++s)
          wdg[kt][q * 2 + s] = dec8[(kt * 32 + (8 * q + 2 * j + s)) * 64 + lane];
  } else {
#pragma unroll
    for (int kt = 0; kt < 8; ++kt)
      wdc[kt] = *(const bf16x8*)(f16 + WDDC_E + ((kt * 4 + w) * 64 + lane) * 8);
    yp = y_hist[(b0 + w) * T_ + (T_ - 1)];
    float pp = s_fcw[256 + lane] * y_hist[(b0 + w) * T_ + lane];
    yhd = wsum64(pp) + fc_b[0];
    if (lane == 0) s_yp[w] = yp;
  }
  __syncthreads();

  for (int hs = 0; hs < HOR_; ++hs) {
    // ---- P_d1: gates i8 + FUSED epilogue (waves 4-7) | dc bf16 (waves 0-3)
    if (w >= 4) {
      int j = w - 4;
      i32x4 a0 = *(const i32x4*)&s_A8[lane & 15][ 0 + ((lane >> 4) << 4)];
      i32x4 a1 = *(const i32x4*)&s_A8[lane & 15][64 + ((lane >> 4) << 4)];
      i32x4 acc[8];
#pragma unroll
      for (int u = 0; u < 8; ++u) {
        i32x4 z = {0, 0, 0, 0};
        acc[u] = MFMAI8(a1, wdg[1][u], MFMAI8(a0, wdg[0][u], z));
      }
      if (lane < 16) {
        float yp0 = s_yp[0], yp1 = s_yp[1], yp2 = s_yp[2], yp3 = s_yp[3];
        float ypr[BB] = {yp0, yp1, yp2, yp3};
#pragma unroll
        for (int s = 0; s < 2; ++s) {
          const int f = 32 * j + 16 * s + lane;       // feature 0..127
          float sd0 = s_se[f]       * C127, sd1 = s_se[128 + f] * C127;
          float sd2 = s_se[256 + f] * C127, sd3 = s_se[384 + f] * C127;
          float db0 = s_encb[f],       db1 = s_encb[128 + f];
          float db2 = s_encb[256 + f], db3 = s_encb[384 + f];
          float dw0 = s_dwih[f],       dw1 = s_dwih[128 + f];
          float dw2 = s_dwih[256 + f], dw3 = s_dwih[384 + f];
#pragma unroll
          for (int r = 0; r < BB; ++r) {
            float gi = sd0 * (float)acc[0 + s][r] + db0 + ypr[r] * dw0;
            float gf = sd1 * (float)acc[2 + s][r] + db1 + ypr[r] * dw1;
            float gg = sd2 * (float)acc[4 + s][r] + db2 + ypr[r] * dw2;
            float go = sd3 * (float)acc[6 + s][r] + db3 + ypr[r] * dw3;
            ccs[s][r] = sigm(gf) * ccs[s][r] + sigm(gi) * tanh_acc(gg);
            float d2 = sigm(go) * tanh_acc(ccs[s][r]);
            s_Ahc[r][f]       = f2b(d2);
            s_Ahc[r][128 + f] = f2b(ccs[s][r]);
            s_A8[r][f]        = (char)(int)rintf(d2 * 127.f);
            s_d2[r][f]        = d2;
          }
        }
      }
    } else {
      f32x4 acc = {0.f, 0.f, 0.f, 0.f}, acc2 = {0.f, 0.f, 0.f, 0.f};
#pragma unroll
      for (int kt = 0; kt < 4; ++kt) {
        bf16x8 a = *(const bf16x8*)&s_Ahc[lane & 15][kt * 32 + ((lane >> 4) << 3)];
        acc = MFMA16(a, wdc[kt], acc);
      }
#pragma unroll
      for (int kt = 4; kt < 8; ++kt) {
        bf16x8 a = *(const bf16x8*)&s_Ahc[lane & 15][kt * 32 + ((lane >> 4) << 3)];
        acc2 = MFMA16(a, wdc[kt], acc2);
      }
      if (lane < 16) {
        int col = w * 16 + lane; float bias = s_wdb[col];
#pragma unroll
        for (int r = 0; r < BB; ++r) s_base[r][col] = acc[r] + acc2[r] + bias;
      }
    }
    __syncthreads();                                            // B1
    // ---- P_d2: attention + context + fc, in-wave (waves 0-3) ----
    if (w < BB) {
      // scores: lane = t'
      float s = 0.f;
#pragma unroll 8
      for (int k = 0; k < 64; ++k)
        s += s_vd[k] * tanh_acc(b2f(s_projT[w][k][lane]) + s_base[w][k]);
      float e = fexp2(s * LOG2E);
      float ssum = wsum64(e);
      s_beta[w][lane] = e * frcp(ssum);
      // context: per lane features j0=lane, j1=lane+64 (same-wave LDS RAW ok)
      float cx0 = 0.f, cx1 = 0.f;
      const short* e0p = &s_encht[w][lane][0];
      const short* e1p = &s_encht[w][lane + 64][0];
#pragma unroll 8
      for (int tp = 0; tp < 32; ++tp) {
        float2 bta = *(const float2*)&s_beta[w][2 * tp];
        short2 h0v = *(const short2*)&e0p[2 * tp];
        short2 h1v = *(const short2*)&e1p[2 * tp];
        cx0 = fmaf(bta.x, b2f(h0v.x), cx0); cx0 = fmaf(bta.y, b2f(h0v.y), cx0);
        cx1 = fmaf(bta.x, b2f(h1v.x), cx1); cx1 = fmaf(bta.y, b2f(h1v.y), cx1);
      }
      // fc (d2 from LDS f32, exact)
      float d20 = s_d2[w][lane], d21 = s_d2[w][64 + lane];
      float pf = s_fcw[lane] * d20 + s_fcw[64 + lane] * d21
               + s_fcw[128 + lane] * cx0 + s_fcw[192 + lane] * cx1;
      pf = wsum64(pf);
      float o = pf + yhd;
      if (lane == 0) { out[(b0 + w) * HOR_ + hs] = o; s_yp[w] = o; }
    }
    __syncthreads();                                            // B2
  }
}

extern "C" void kernel_launch(void* const* d_in, const int* in_sizes, int n_in,
                              void* d_out, int out_size, void* d_ws, size_t ws_size,
                              hipStream_t stream) {
  (void)in_sizes; (void)n_in; (void)out_size; (void)ws_size;
  const float* X       = (const float*)d_in[0];
  const float* y_hist  = (const float*)d_in[1];
  const float* We_w    = (const float*)d_in[2];
  const float* We_b    = (const float*)d_in[3];
  const float* ve_w    = (const float*)d_in[4];
  // d_in[5] = ve_b : softmax-invariant, unused
  const float* enc_Wih = (const float*)d_in[6];
  const float* enc_Whh = (const float*)d_in[7];
  const float* enc_bih = (const float*)d_in[8];
  const float* enc_bhh = (const float*)d_in[9];
  const float* dec_Wih = (const float*)d_in[10];
  const float* dec_Whh = (const float*)d_in[11];
  const float* dec_bih = (const float*)d_in[12];
  const float* dec_bhh = (const float*)d_in[13];
  const float* Wd_w    = (const float*)d_in[14];
  const float* Wd_b    = (const float*)d_in[15];
  const float* vd_w    = (const float*)d_in[16];
  // d_in[17] = vd_b : softmax-invariant, unused
  const float* fc_w    = (const float*)d_in[18];
  const float* fc_b    = (const float*)d_in[19];

  char* ws8  = (char*)d_ws;
  float* out = (float*)d_out;

  prep_bf<<<160, 256, 0, stream>>>(We_w, Wd_w, ws8);
  prep_q <<<256, 256, 0, stream>>>(enc_Wih, enc_Whh, dec_Whh, ws8);
  da_rnn <<<B_ / BB, 512, 0, stream>>>(X, y_hist, We_w, We_b, ve_w,
                                       enc_bih, enc_bhh, dec_Wih, dec_bih, dec_bhh,
                                       Wd_b, vd_w, fc_w, fc_b, ws8, out);
}

// Round 4
// 330.255 us; speedup vs baseline: 2.2739x; 1.1545x over previous
//
#include <hip/hip_runtime.h>
#include <hip/hip_bf16.h>

// DA-RNN persistent kernel, round 10: R6 structure + DPP-speed reductions.
// R9 post-mortem: fused epilogue concentrated trans-issue on 2 waves/SIMD
// (4 cells x 16 lanes) -> regressed. R6's wide epilogue (1 wave/SIMD) is
// right. New theory: ~1000-1500 cy/step of the 8700-cy enc step is dependent
// __shfl latency (~120 cy DS-op each: 3-deep p-reduce + two 6-deep
// butterflies). R10 swaps butterflies for DPP quad_perm/row_mirror (VALU
// speed) + 1 ds_swizzle (xor16) + 1 shfl (xor32); trees the decoder's
// 64-deep score/context FP chains; splits 8-deep MFMA chains into 4+4.
// BB=4, 256 blocks, __launch_bounds__(512,2): proven no-spill regime.

#define B_    1024
#define T_    64
#define D_    128
#define H_    128
#define HOR_  24
#define ATT_  64
#define BB    4
#define LOG2E 1.4426950408889634f
#define C127  (1.f/127.f)

typedef float f32x4  __attribute__((ext_vector_type(4)));
typedef short bf16x8 __attribute__((ext_vector_type(8)));
typedef int   i32x4  __attribute__((ext_vector_type(4)));

#define MFMA16(a,b,c) __builtin_amdgcn_mfma_f32_16x16x32_bf16((a),(b),(c),0,0,0)
#define MFMAI8(a,b,c) __builtin_amdgcn_mfma_i32_16x16x64_i8((a),(b),(c),0,0,0)

// ---- workspace layout (same packing as R5/R6) ----
#define WHS_E    0        // base GEMM  B bf16: kt0..7, nt0..3  (16384 el)
#define WDDC_E   16384    // dc GEMM    B bf16: kt0..7, nt0..3  (16384 el)
#define WDENC_E  32768    // proj GEMM  B bf16: kt0..3, nt0..3  ( 8192 el)
#define WENC8_B  81920    // i8 enc gates B: [kt4][nt32][lane64][16] (131072 B)
#define WDEC8_B  212992   // i8 dec gates B: [kt2][nt32][lane64][16] ( 65536 B)
#define SENC_B   278528   // 512 f32 per-col scales (enc)
#define SDEC_B   280576   // 512 f32 per-col scales (dec)

__device__ __forceinline__ short f2b(float f) {        // fp32 -> bf16 RNE
  union { float f; unsigned u; } c; c.f = f;
  unsigned r = c.u + 0x7fffu + ((c.u >> 16) & 1u);
  return (short)(r >> 16);
}
__device__ __forceinline__ float b2f(short s) {
  union { unsigned u; float f; } c; c.u = ((unsigned)(unsigned short)s) << 16;
  return c.f;
}
__device__ __forceinline__ float fexp2(float x) { return __builtin_amdgcn_exp2f(x); }
__device__ __forceinline__ float frcp (float x) { return __builtin_amdgcn_rcpf(x); }
__device__ __forceinline__ float tanh_acc(float x) {   // 1 - 2/(1+e^{2x})
  float e = fexp2(x * 2.885390081777927f);
  return 1.f - 2.f * frcp(1.f + e);
}
__device__ __forceinline__ float sigm(float x) {
  return frcp(1.f + fexp2(-LOG2E * x));
}

// ---- fast cross-lane: DPP for xor1/2/4/8, ds_swizzle xor16, shfl xor32 ----
// row_half_mirror (xor7) / row_mirror (xor15) are valid xor4/xor8 stand-ins
// inside a reduction: after xor1+xor2 (xor1+2+4) the groups are uniform.
template<int CTRL>
__device__ __forceinline__ float dppmov(float v) {
  return __builtin_bit_cast(float,
      __builtin_amdgcn_mov_dpp(__builtin_bit_cast(int, v), CTRL, 0xF, 0xF, true));
}
__device__ __forceinline__ float swz16(float v) {      // lane ^= 16
  return __builtin_bit_cast(float,
      __builtin_amdgcn_ds_swizzle(__builtin_bit_cast(int, v), 0x401F));
}
__device__ __forceinline__ float wsum64(float v) {
  v += dppmov<0xB1>(v);        // xor1  (quad_perm 1,0,3,2)
  v += dppmov<0x4E>(v);        // xor2  (quad_perm 2,3,0,1)
  v += dppmov<0x141>(v);       // xor4  (row_half_mirror)
  v += dppmov<0x140>(v);       // xor8  (row_mirror)
  v += swz16(v);               // xor16
  v += __shfl_xor(v, 32, 64);  // xor32
  return v;
}
__device__ __forceinline__ float wmax64(float v) {
  v = fmaxf(v, dppmov<0xB1>(v));
  v = fmaxf(v, dppmov<0x4E>(v));
  v = fmaxf(v, dppmov<0x141>(v));
  v = fmaxf(v, dppmov<0x140>(v));
  v = fmaxf(v, swz16(v));
  v = fmaxf(v, __shfl_xor(v, 32, 64));
  return v;
}
__device__ __forceinline__ float gsum8(float v) {      // sum within group of 8
  v += dppmov<0xB1>(v);
  v += dppmov<0x4E>(v);
  v += dppmov<0x141>(v);
  return v;
}

// ---- prep1: bf16 B-frags (base / dc / proj), one element per thread ----
__global__ void prep_bf(const float* __restrict__ We_w,
                        const float* __restrict__ Wd_w,
                        char* __restrict__ ws8) {
  int e = blockIdx.x * 256 + threadIdx.x;
  if (e >= 40960) return;
  short* f16 = (short*)ws8;
  int region = e >> 14;                  // 0=WHS 1=WDDC 2=WDENC
  int er = e & 16383;
  int fi = er >> 9, li = (er >> 3) & 63, jq = er & 7;
  int kt = fi >> 2, nt = fi & 3;
  int k = kt * 32 + ((li >> 4) << 3) + jq, n = nt * 16 + (li & 15);
  float v;
  if (region == 0)      v = We_w[n * 257 + k];
  else if (region == 1) v = (k < 128) ? Wd_w[n * 384 + 128 + k]
                                      : Wd_w[n * 384 + 256 + (k - 128)];
  else                  v = Wd_w[n * 384 + k];
  f16[e] = f2b(v);
}

// ---- prep2: i8 quantized gates weights, one wave per column ----
__global__ void prep_q(const float* __restrict__ enc_Wih,
                       const float* __restrict__ enc_Whh,
                       const float* __restrict__ dec_Whh,
                       char* __restrict__ ws8) {
  int gw = (blockIdx.x * 256 + threadIdx.x) >> 6;
  int lane = threadIdx.x & 63;
  if (gw < 512) {                        // encoder col, K=256
    int n = gw;
    float v[4]; float m = 0.f;
#pragma unroll
    for (int q = 0; q < 4; ++q) {
      int k = lane * 4 + q;
      v[q] = (k < 128) ? enc_Wih[n * 128 + k] : enc_Whh[n * 128 + (k - 128)];
      m = fmaxf(m, fabsf(v[q]));
    }
    m = wmax64(m);
    if (lane == 0) ((float*)(ws8 + SENC_B))[n] = m * C127;
    float inv = m > 0.f ? 127.f / m : 0.f;
    char* dst = ws8 + WENC8_B;
#pragma unroll
    for (int q = 0; q < 4; ++q) {
      int k = lane * 4 + q;
      int kt = k >> 6, grp = (k >> 4) & 3, b = k & 15, l16 = (n & 15) | (grp << 4);
      dst[((kt * 32 + (n >> 4)) * 64 + l16) * 16 + b] = (char)(int)rintf(v[q] * inv);
    }
  } else if (gw < 1024) {                // decoder col, K=128
    int n = gw - 512;
    float v[2]; float m = 0.f;
#pragma unroll
    for (int q = 0; q < 2; ++q) {
      int k = lane * 2 + q;
      v[q] = dec_Whh[n * 128 + k];
      m = fmaxf(m, fabsf(v[q]));
    }
    m = wmax64(m);
    if (lane == 0) ((float*)(ws8 + SDEC_B))[n] = m * C127;
    float inv = m > 0.f ? 127.f / m : 0.f;
    char* dst = ws8 + WDEC8_B;
#pragma unroll
    for (int q = 0; q < 2; ++q) {
      int k = lane * 2 + q;
      int kt = k >> 6, grp = (k >> 4) & 3, b = k & 15, l16 = (n & 15) | (grp << 4);
      dst[((kt * 32 + (n >> 4)) * 64 + l16) * 16 + b] = (char)(int)rintf(v[q] * inv);
    }
  }
}

__global__ __launch_bounds__(512, 2)
void da_rnn(const float* __restrict__ X, const float* __restrict__ y_hist,
            const float* __restrict__ We_w, const float* __restrict__ We_b,
            const float* __restrict__ ve_w,
            const float* __restrict__ enc_bih, const float* __restrict__ enc_bhh,
            const float* __restrict__ dec_Wih,
            const float* __restrict__ dec_bih, const float* __restrict__ dec_bhh,
            const float* __restrict__ Wd_b, const float* __restrict__ vd_w,
            const float* __restrict__ fc_w, const float* __restrict__ fc_b,
            const char* __restrict__ ws8, float* __restrict__ out) {
  const short* f16  = (const short*)ws8;
  const i32x4* enc8 = (const i32x4*)(ws8 + WENC8_B);
  const i32x4* dec8 = (const i32x4*)(ws8 + WDEC8_B);
  const float* senc = (const float*)(ws8 + SENC_B);
  const float* sdec = (const float*)(ws8 + SDEC_B);

  // strides: s_A8 272B=68w (68%32=4 -> 2-way, free); s_Ahc 264sh=132w (4 mod 32)
  __shared__ __align__(16) char  s_A8[16][272];   // gates A i8
  __shared__ __align__(16) short s_Ahc[16][264];  // base/dc/proj A bf16 [h;c]
  __shared__ short s_projT[4][64][65];            // enc_proj^T
  __shared__ short s_encht[4][128][66];           // enc_hiddens [r][j][t] bf16
  __shared__ float s_gates[4][512];
  __shared__ float s_base[4][64];                 // enc: base ; dec: dc
  __shared__ float s_beta[4][64];
  __shared__ float s_xr[4];
  __shared__ float2 s_wv[64];                     // (w_feat[k], ve_w[k])
  __shared__ float s_web[64], s_vd[64], s_wdb[64];
  __shared__ float s_se[512], s_sd[512];
  __shared__ float s_encb[512], s_decb[512], s_dwih[512];
  __shared__ float s_fcw[320];

  const int tid  = threadIdx.x;
  const int lane = tid & 63;
  const int w    = tid >> 6;        // wave 0..7 ; waves 0-3 own row w
  const int b0   = blockIdx.x * BB;

  // ---- init ----
  if (tid < 64) {
    s_wv[tid]  = make_float2(We_w[tid * 257 + 256], ve_w[tid]);
    s_web[tid] = We_b[tid];
    s_vd[tid]  = vd_w[tid];
    s_wdb[tid] = Wd_b[tid];
  }
  if (tid < 320) s_fcw[tid] = fc_w[tid];
  s_se[tid]   = senc[tid];
  s_sd[tid]   = sdec[tid];
  s_encb[tid] = enc_bih[tid] + enc_bhh[tid];
  s_decb[tid] = dec_bih[tid] + dec_bhh[tid];
  s_dwih[tid] = dec_Wih[tid];
  for (int i = tid; i < (16 * 272) / 4; i += 512) ((int*)s_A8)[i] = 0;
  for (int i = tid; i < (16 * 264) / 2; i += 512) ((int*)s_Ahc)[i] = 0;
  if (tid < 256) s_base[tid >> 6][tid & 63] = We_b[tid & 63];  // base_0

  // ---- register-resident weights (loaded once, L2) ----
  i32x4 wg[4][4];                       // enc gates i8, nt = w + 8i
#pragma unroll
  for (int kt = 0; kt < 4; ++kt)
#pragma unroll
    for (int i = 0; i < 4; ++i)
      wg[kt][i] = enc8[(kt * 32 + (w + 8 * i)) * 64 + lane];
  bf16x8 wb[8], wp[4];
  if (w < 4) {
#pragma unroll
    for (int kt = 0; kt < 8; ++kt)
      wb[kt] = *(const bf16x8*)(f16 + WHS_E + ((kt * 4 + w) * 64 + lane) * 8);
  } else {
#pragma unroll
    for (int kt = 0; kt < 4; ++kt)
      wp[kt] = *(const bf16x8*)(f16 + WDENC_E + ((kt * 4 + (w - 4)) * 64 + lane) * 8);
  }

  // per-row state (waves 0-3): features j0=lane, j1=lane+64
  float h0 = 0.f, c0 = 0.f, h1 = 0.f, c1 = 0.f;
  float x0 = 0.f, x1 = 0.f, xi = 0.f;
  const float* Xr = X + (size_t)(b0 + (w & 3)) * T_ * D_;
  if (w < 4) {
    x0 = Xr[lane]; x1 = Xr[64 + lane];
    xi = 6.f * cosf((2 * (lane >> 3) + 1) * 0.19634954084936207f);  // node
  }
  __syncthreads();

  // ====================== encoder ======================
  for (int t = 0; t < T_; ++t) {
    // ---- P_A: input attention, in-wave, waves 0-3 (row = w) ----
    if (w < 4) {
      float x0n = 0.f, x1n = 0.f;
      if (t < T_ - 1) { x0n = Xr[(t + 1) * D_ + lane]; x1n = Xr[(t + 1) * D_ + 64 + lane]; }
      // node eval: lane = (ni = lane>>3, kc = lane&7); 8 k-terms each
      const int kc = lane & 7;
      float p = 0.f;
      const float4* wvp = (const float4*)&s_wv[kc * 8];
      const float4* bp  = (const float4*)&s_base[w][kc * 8];
      float4 bA = bp[0], bB = bp[1];
#pragma unroll
      for (int q = 0; q < 4; ++q) {
        float4 wv = wvp[q];                       // (w_k, ve_k, w_{k+1}, ve_{k+1})
        float bb0 = (q < 2) ? ((q & 1) ? bA.z : bA.x) : ((q & 1) ? bB.z : bB.x);
        float bb1 = (q < 2) ? ((q & 1) ? bA.w : bA.y) : ((q & 1) ? bB.w : bB.y);
        p += wv.y * tanh_acc(fmaf(xi, wv.x, bb0));
        p += wv.w * tanh_acc(fmaf(xi, wv.z, bb1));
      }
      p = gsum8(p);                               // sum over kc within node grp
      float f0 = __shfl(p,  0, 64), f1 = __shfl(p,  8, 64);
      float f2 = __shfl(p, 16, 64), f3 = __shfl(p, 24, 64);
      float f4 = __shfl(p, 32, 64), f5 = __shfl(p, 40, 64);
      float f6 = __shfl(p, 48, 64), f7 = __shfl(p, 56, 64);
      // barycentric interpolation at u = clamp(x, +-6), Cheb-1 nodes
      float sc0, sc1;
      {
        const float xb[8] = { 5.884711682f, 4.988817674f, 3.333421398f, 1.170541932f,
                             -1.170541932f, -3.333421398f, -4.988817674f, -5.884711682f};
        const float wbar[8] = { 0.1950903220f, -0.5555702330f, 0.8314696123f, -0.9807852804f,
                                0.9807852804f, -0.8314696123f, 0.5555702330f, -0.1950903220f};
        float u0 = fminf(fmaxf(x0, -6.f), 6.f), u1 = fminf(fmaxf(x1, -6.f), 6.f);
        float n0 = 0.f, d0 = 0.f, n1 = 0.f, d1 = 0.f;
        float fv[8] = {f0, f1, f2, f3, f4, f5, f6, f7};
#pragma unroll
        for (int i = 0; i < 8; ++i) {
          float dd0 = u0 - xb[i]; dd0 = copysignf(fmaxf(fabsf(dd0), 1e-5f), dd0);
          float dd1 = u1 - xb[i]; dd1 = copysignf(fmaxf(fabsf(dd1), 1e-5f), dd1);
          float t0 = wbar[i] * frcp(dd0), t1 = wbar[i] * frcp(dd1);
          n0 = fmaf(t0, fv[i], n0); d0 += t0;
          n1 = fmaf(t1, fv[i], n1); d1 += t1;
        }
        sc0 = n0 * frcp(d0); sc1 = n1 * frcp(d1);
      }
      float e0 = fexp2(sc0 * LOG2E), e1 = fexp2(sc1 * LOG2E);  // |sc|<=sum|ve|~2.6
      float sum = wsum64(e0 + e1);
      float mx  = wmax64(fmaxf(e0 * fabsf(x0), e1 * fabsf(x1)));
      float inv = mx > 0.f ? 127.f * frcp(mx) : 0.f;
      s_A8[w][lane]      = (char)(int)rintf(x0 * e0 * inv);
      s_A8[w][64 + lane] = (char)(int)rintf(x1 * e1 * inv);
      if (lane == 0) s_xr[w] = mx * frcp(127.f * sum);
      x0 = x0n; x1 = x1n;
    }
    __syncthreads();                                            // B1
    // ---- P_G: gates i8 GEMM, all 8 waves, weights in registers ----
    {
      i32x4 a0 = *(const i32x4*)&s_A8[lane & 15][  0 + ((lane >> 4) << 4)];
      i32x4 a1 = *(const i32x4*)&s_A8[lane & 15][ 64 + ((lane >> 4) << 4)];
      i32x4 a2 = *(const i32x4*)&s_A8[lane & 15][128 + ((lane >> 4) << 4)];
      i32x4 a3 = *(const i32x4*)&s_A8[lane & 15][192 + ((lane >> 4) << 4)];
      i32x4 ax[4], ah[4];
#pragma unroll
      for (int i = 0; i < 4; ++i) {
        i32x4 z = {0, 0, 0, 0};
        ax[i] = MFMAI8(a1, wg[1][i], MFMAI8(a0, wg[0][i], z));
        ah[i] = MFMAI8(a3, wg[3][i], MFMAI8(a2, wg[2][i], z));
      }
      if (lane < 16) {
        float sx0 = s_xr[0], sx1 = s_xr[1], sx2 = s_xr[2], sx3 = s_xr[3];
#pragma unroll
        for (int i = 0; i < 4; ++i) {
          int col = (w + 8 * i) * 16 + lane;
          float se = s_se[col];
          s_gates[0][col] = se * fmaf(sx0, (float)ax[i][0], C127 * (float)ah[i][0]);
          s_gates[1][col] = se * fmaf(sx1, (float)ax[i][1], C127 * (float)ah[i][1]);
          s_gates[2][col] = se * fmaf(sx2, (float)ax[i][2], C127 * (float)ah[i][2]);
          s_gates[3][col] = se * fmaf(sx3, (float)ax[i][3], C127 * (float)ah[i][3]);
        }
      }
    }
    __syncthreads();                                            // B2
    // ---- P_E: LSTM epilogue, in-wave, waves 0-3 (2 features/lane) ----
    if (w < 4) {
      float gi0 = s_gates[w][lane]       + s_encb[lane];
      float gf0 = s_gates[w][lane + 128] + s_encb[lane + 128];
      float gg0 = s_gates[w][lane + 256] + s_encb[lane + 256];
      float go0 = s_gates[w][lane + 384] + s_encb[lane + 384];
      float gi1 = s_gates[w][lane + 64]  + s_encb[lane + 64];
      float gf1 = s_gates[w][lane + 192] + s_encb[lane + 192];
      float gg1 = s_gates[w][lane + 320] + s_encb[lane + 320];
      float go1 = s_gates[w][lane + 448] + s_encb[lane + 448];
      c0 = sigm(gf0) * c0 + sigm(gi0) * tanh_acc(gg0);
      h0 = sigm(go0) * tanh_acc(c0);
      c1 = sigm(gf1) * c1 + sigm(gi1) * tanh_acc(gg1);
      h1 = sigm(go1) * tanh_acc(c1);
      s_Ahc[w][lane]        = f2b(h0);
      s_Ahc[w][lane + 64]   = f2b(h1);
      s_Ahc[w][lane + 128]  = f2b(c0);
      s_Ahc[w][lane + 192]  = f2b(c1);
      s_A8[w][128 + lane]      = (char)(int)rintf(h0 * 127.f);
      s_A8[w][128 + lane + 64] = (char)(int)rintf(h1 * 127.f);
      s_encht[w][lane][t]      = f2b(h0);
      s_encht[w][lane + 64][t] = f2b(h1);
    }
    __syncthreads();                                            // B3
    // ---- P_B: base_{t+1} (waves 0-3) | proj_t (waves 4-7), B in regs ----
    if (w < 4) {
      f32x4 acc = {0.f, 0.f, 0.f, 0.f}, acc2 = {0.f, 0.f, 0.f, 0.f};
#pragma unroll
      for (int kt = 0; kt < 4; ++kt) {
        bf16x8 a = *(const bf16x8*)&s_Ahc[lane & 15][kt * 32 + ((lane >> 4) << 3)];
        acc = MFMA16(a, wb[kt], acc);
      }
#pragma unroll
      for (int kt = 4; kt < 8; ++kt) {
        bf16x8 a = *(const bf16x8*)&s_Ahc[lane & 15][kt * 32 + ((lane >> 4) << 3)];
        acc2 = MFMA16(a, wb[kt], acc2);
      }
      if (lane < 16) {
        int col = w * 16 + lane; float bias = s_web[col];
#pragma unroll
        for (int r = 0; r < 4; ++r) s_base[r][col] = acc[r] + acc2[r] + bias;
      }
    } else {
      f32x4 acc = {0.f, 0.f, 0.f, 0.f};
#pragma unroll
      for (int kt = 0; kt < 4; ++kt) {
        bf16x8 a = *(const bf16x8*)&s_Ahc[lane & 15][kt * 32 + ((lane >> 4) << 3)];
        acc = MFMA16(a, wp[kt], acc);
      }
      if (lane < 16) {
        int katt = (w - 4) * 16 + lane;
#pragma unroll
        for (int r = 0; r < 4; ++r) s_projT[r][katt][t] = f2b(acc[r]);
      }
    }
    __syncthreads();                                            // B4
  }

  // ====================== decoder ======================
  {
    int r = tid >> 7, j = tid & 127;
    s_Ahc[r][j] = 0; s_Ahc[r][128 + j] = 0; s_A8[r][j] = 0;
  }
  i32x4 wdg[2][8];                      // dec gates i8 (waves 4-7), nt=(w-4)*8+i
  bf16x8 wdc[8];                        // dc bf16 (waves 0-3)
  float yp = 0.f, yhd = 0.f;
  if (w >= 4) {
#pragma unroll
    for (int kt = 0; kt < 2; ++kt)
#pragma unroll
      for (int i = 0; i < 8; ++i)
        wdg[kt][i] = dec8[(kt * 32 + ((w - 4) * 8 + i)) * 64 + lane];
  } else {
#pragma unroll
    for (int kt = 0; kt < 8; ++kt)
      wdc[kt] = *(const bf16x8*)(f16 + WDDC_E + ((kt * 4 + w) * 64 + lane) * 8);
    yp = y_hist[(b0 + w) * T_ + (T_ - 1)];
    float pp = s_fcw[256 + lane] * y_hist[(b0 + w) * T_ + lane];
    yhd = wsum64(pp) + fc_b[0];
  }
  float dd0 = 0.f, dc0 = 0.f, dd1 = 0.f, dc1 = 0.f;   // d, cc (2 feats/lane)
  __syncthreads();

  for (int hs = 0; hs < HOR_; ++hs) {
    // ---- P_dG: dec gates i8 (waves 4-7) | dc bf16 (waves 0-3) ----
    if (w >= 4) {
      i32x4 a0 = *(const i32x4*)&s_A8[lane & 15][ 0 + ((lane >> 4) << 4)];
      i32x4 a1 = *(const i32x4*)&s_A8[lane & 15][64 + ((lane >> 4) << 4)];
#pragma unroll
      for (int i = 0; i < 8; ++i) {
        i32x4 z = {0, 0, 0, 0};
        i32x4 ac = MFMAI8(a1, wdg[1][i], MFMAI8(a0, wdg[0][i], z));
        if (lane < 16) {
          int col = ((w - 4) * 8 + i) * 16 + lane;
          float sd = s_sd[col] * C127;
#pragma unroll
          for (int r = 0; r < 4; ++r) s_gates[r][col] = sd * (float)ac[r];
        }
      }
    } else {
      f32x4 acc = {0.f, 0.f, 0.f, 0.f}, acc2 = {0.f, 0.f, 0.f, 0.f};
#pragma unroll
      for (int kt = 0; kt < 4; ++kt) {
        bf16x8 a = *(const bf16x8*)&s_Ahc[lane & 15][kt * 32 + ((lane >> 4) << 3)];
        acc = MFMA16(a, wdc[kt], acc);
      }
#pragma unroll
      for (int kt = 4; kt < 8; ++kt) {
        bf16x8 a = *(const bf16x8*)&s_Ahc[lane & 15][kt * 32 + ((lane >> 4) << 3)];
        acc2 = MFMA16(a, wdc[kt], acc2);
      }
      if (lane < 16) {
        int col = w * 16 + lane; float bias = s_wdb[col];
#pragma unroll
        for (int r = 0; r < 4; ++r) s_base[r][col] = acc[r] + acc2[r] + bias;
      }
    }
    __syncthreads();                                            // B1
    // ---- P_dA: attention + context + epilogue + fc, in-wave (waves 0-3) ----
    if (w < 4) {
      // scores: lane = t' ; 4-way treed accumulation (64-deep -> 16-deep)
      float sA = 0.f, sB = 0.f, sC = 0.f, sD = 0.f;
#pragma unroll 4
      for (int k = 0; k < 64; k += 4) {
        sA += s_vd[k]     * tanh_acc(b2f(s_projT[w][k][lane])     + s_base[w][k]);
        sB += s_vd[k + 1] * tanh_acc(b2f(s_projT[w][k + 1][lane]) + s_base[w][k + 1]);
        sC += s_vd[k + 2] * tanh_acc(b2f(s_projT[w][k + 2][lane]) + s_base[w][k + 2]);
        sD += s_vd[k + 3] * tanh_acc(b2f(s_projT[w][k + 3][lane]) + s_base[w][k + 3]);
      }
      float s = (sA + sB) + (sC + sD);
      float e = fexp2(s * LOG2E);
      float ssum = wsum64(e);
      s_beta[w][lane] = e * frcp(ssum);
      // context: per lane features j0=lane, j1=lane+64 (same-wave LDS RAW ok)
      float cx0a = 0.f, cx0b = 0.f, cx1a = 0.f, cx1b = 0.f;
      const short* e0p = &s_encht[w][lane][0];
      const short* e1p = &s_encht[w][lane + 64][0];
#pragma unroll 8
      for (int tp = 0; tp < 32; ++tp) {
        float2 bta = *(const float2*)&s_beta[w][2 * tp];
        short2 h0v = *(const short2*)&e0p[2 * tp];
        short2 h1v = *(const short2*)&e1p[2 * tp];
        cx0a = fmaf(bta.x, b2f(h0v.x), cx0a); cx0b = fmaf(bta.y, b2f(h0v.y), cx0b);
        cx1a = fmaf(bta.x, b2f(h1v.x), cx1a); cx1b = fmaf(bta.y, b2f(h1v.y), cx1b);
      }
      float cx0 = cx0a + cx0b, cx1 = cx1a + cx1b;
      // LSTM epilogue (gates use OLD d via GEMM; +y_prev*dec_Wih)
      float gi0 = s_gates[w][lane]       + s_decb[lane]       + yp * s_dwih[lane];
      float gf0 = s_gates[w][lane + 128] + s_decb[lane + 128] + yp * s_dwih[lane + 128];
      float gg0 = s_gates[w][lane + 256] + s_decb[lane + 256] + yp * s_dwih[lane + 256];
      float go0 = s_gates[w][lane + 384] + s_decb[lane + 384] + yp * s_dwih[lane + 384];
      float gi1 = s_gates[w][lane + 64]  + s_decb[lane + 64]  + yp * s_dwih[lane + 64];
      float gf1 = s_gates[w][lane + 192] + s_decb[lane + 192] + yp * s_dwih[lane + 192];
      float gg1 = s_gates[w][lane + 320] + s_decb[lane + 320] + yp * s_dwih[lane + 320];
      float go1 = s_gates[w][lane + 448] + s_decb[lane + 448] + yp * s_dwih[lane + 448];
      dc0 = sigm(gf0) * dc0 + sigm(gi0) * tanh_acc(gg0);
      dd0 = sigm(go0) * tanh_acc(dc0);
      dc1 = sigm(gf1) * dc1 + sigm(gi1) * tanh_acc(gg1);
      dd1 = sigm(go1) * tanh_acc(dc1);
      // fc
      float pf = s_fcw[lane] * dd0 + s_fcw[64 + lane] * dd1
               + s_fcw[128 + lane] * cx0 + s_fcw[192 + lane] * cx1;
      pf = wsum64(pf);
      float o = pf + yhd;
      if (lane == 0) out[(b0 + w) * HOR_ + hs] = o;
      yp = o;
      // state for next P_dG
      s_Ahc[w][lane]       = f2b(dd0);
      s_Ahc[w][lane + 64]  = f2b(dd1);
      s_Ahc[w][lane + 128] = f2b(dc0);
      s_Ahc[w][lane + 192] = f2b(dc1);
      s_A8[w][lane]      = (char)(int)rintf(dd0 * 127.f);
      s_A8[w][lane + 64] = (char)(int)rintf(dd1 * 127.f);
    }
    __syncthreads();                                            // B2
  }
}

extern "C" void kernel_launch(void* const* d_in, const int* in_sizes, int n_in,
                              void* d_out, int out_size, void* d_ws, size_t ws_size,
                              hipStream_t stream) {
  (void)in_sizes; (void)n_in; (void)out_size; (void)ws_size;
  const float* X       = (const float*)d_in[0];
  const float* y_hist  = (const float*)d_in[1];
  const float* We_w    = (const float*)d_in[2];
  const float* We_b    = (const float*)d_in[3];
  const float* ve_w    = (const float*)d_in[4];
  // d_in[5] = ve_b : softmax-invariant, unused
  const float* enc_Wih = (const float*)d_in[6];
  const float* enc_Whh = (const float*)d_in[7];
  const float* enc_bih = (const float*)d_in[8];
  const float* enc_bhh = (const float*)d_in[9];
  const float* dec_Wih = (const float*)d_in[10];
  const float* dec_Whh = (const float*)d_in[11];
  const float* dec_bih = (const float*)d_in[12];
  const float* dec_bhh = (const float*)d_in[13];
  const float* Wd_w    = (const float*)d_in[14];
  const float* Wd_b    = (const float*)d_in[15];
  const float* vd_w    = (const float*)d_in[16];
  // d_in[17] = vd_b : softmax-invariant, unused
  const float* fc_w    = (const float*)d_in[18];
  const float* fc_b    = (const float*)d_in[19];

  char* ws8  = (char*)d_ws;
  float* out = (float*)d_out;

  prep_bf<<<160, 256, 0, stream>>>(We_w, Wd_w, ws8);
  prep_q <<<256, 256, 0, stream>>>(enc_Wih, enc_Whh, dec_Whh, ws8);
  da_rnn <<<B_ / BB, 512, 0, stream>>>(X, y_hist, We_w, We_b, ve_w,
                                       enc_bih, enc_bhh, dec_Wih, dec_bih, dec_bhh,
                                       Wd_b, vd_w, fc_w, fc_b, ws8, out);
}

// Round 5
// 325.208 us; speedup vs baseline: 2.3091x; 1.0155x over previous
//
#include <hip/hip_runtime.h>
#include <hip/hip_bf16.h>

// DA-RNN persistent kernel, round 11: transposed-MFMA vectorized scatters.
// R10 post-mortem: DPP reductions confirmed (-7.5%). Next unmodeled cost:
// LDS-pipe serialization of scalar scatters (P_G: 128 ds_write_b32/step;
// dec P_dG: 128/step) caused by MFMA C layout (row=batch) mismatching the
// per-gate-column redistribution. Fix: A/B frags share lane layout, so
// swapping MFMA operands (W,A) yields C^T: lane&15=batch row, regs=4
// consecutive gate cols -> ONE ds_write_b128 per tile. Scale/bias moved to
// preloaded regs. Also: h-frag (pa2/pa3) prefetch one phase early; X
// prefetch one full step early. Same math order -> absmax unchanged.
// BB=4, 256 blocks, __launch_bounds__(512,2): proven no-spill regime.

#define B_    1024
#define T_    64
#define D_    128
#define H_    128
#define HOR_  24
#define ATT_  64
#define BB    4
#define LOG2E 1.4426950408889634f
#define C127  (1.f/127.f)

typedef float f32x4  __attribute__((ext_vector_type(4)));
typedef short bf16x8 __attribute__((ext_vector_type(8)));
typedef int   i32x4  __attribute__((ext_vector_type(4)));

#define MFMA16(a,b,c) __builtin_amdgcn_mfma_f32_16x16x32_bf16((a),(b),(c),0,0,0)
#define MFMAI8(a,b,c) __builtin_amdgcn_mfma_i32_16x16x64_i8((a),(b),(c),0,0,0)

// ---- workspace layout (same packing as R5..R10) ----
#define WHS_E    0        // base GEMM  B bf16: kt0..7, nt0..3  (16384 el)
#define WDDC_E   16384    // dc GEMM    B bf16: kt0..7, nt0..3  (16384 el)
#define WDENC_E  32768    // proj GEMM  B bf16: kt0..3, nt0..3  ( 8192 el)
#define WENC8_B  81920    // i8 enc gates B: [kt4][nt32][lane64][16] (131072 B)
#define WDEC8_B  212992   // i8 dec gates B: [kt2][nt32][lane64][16] ( 65536 B)
#define SENC_B   278528   // 512 f32 per-col scales (enc)
#define SDEC_B   280576   // 512 f32 per-col scales (dec)

__device__ __forceinline__ short f2b(float f) {        // fp32 -> bf16 RNE
  union { float f; unsigned u; } c; c.f = f;
  unsigned r = c.u + 0x7fffu + ((c.u >> 16) & 1u);
  return (short)(r >> 16);
}
__device__ __forceinline__ float b2f(short s) {
  union { unsigned u; float f; } c; c.u = ((unsigned)(unsigned short)s) << 16;
  return c.f;
}
__device__ __forceinline__ float fexp2(float x) { return __builtin_amdgcn_exp2f(x); }
__device__ __forceinline__ float frcp (float x) { return __builtin_amdgcn_rcpf(x); }
__device__ __forceinline__ float tanh_acc(float x) {   // 1 - 2/(1+e^{2x})
  float e = fexp2(x * 2.885390081777927f);
  return 1.f - 2.f * frcp(1.f + e);
}
__device__ __forceinline__ float sigm(float x) {
  return frcp(1.f + fexp2(-LOG2E * x));
}

// ---- fast cross-lane: DPP for xor1/2/4/8, ds_swizzle xor16, shfl xor32 ----
template<int CTRL>
__device__ __forceinline__ float dppmov(float v) {
  return __builtin_bit_cast(float,
      __builtin_amdgcn_mov_dpp(__builtin_bit_cast(int, v), CTRL, 0xF, 0xF, true));
}
__device__ __forceinline__ float swz16(float v) {      // lane ^= 16
  return __builtin_bit_cast(float,
      __builtin_amdgcn_ds_swizzle(__builtin_bit_cast(int, v), 0x401F));
}
__device__ __forceinline__ float wsum64(float v) {
  v += dppmov<0xB1>(v);        // xor1  (quad_perm 1,0,3,2)
  v += dppmov<0x4E>(v);        // xor2  (quad_perm 2,3,0,1)
  v += dppmov<0x141>(v);       // xor4  (row_half_mirror)
  v += dppmov<0x140>(v);       // xor8  (row_mirror)
  v += swz16(v);               // xor16
  v += __shfl_xor(v, 32, 64);  // xor32
  return v;
}
__device__ __forceinline__ float wmax64(float v) {
  v = fmaxf(v, dppmov<0xB1>(v));
  v = fmaxf(v, dppmov<0x4E>(v));
  v = fmaxf(v, dppmov<0x141>(v));
  v = fmaxf(v, dppmov<0x140>(v));
  v = fmaxf(v, swz16(v));
  v = fmaxf(v, __shfl_xor(v, 32, 64));
  return v;
}
__device__ __forceinline__ float gsum8(float v) {      // sum within group of 8
  v += dppmov<0xB1>(v);
  v += dppmov<0x4E>(v);
  v += dppmov<0x141>(v);
  return v;
}

// ---- prep1: bf16 B-frags (base / dc / proj), one element per thread ----
__global__ void prep_bf(const float* __restrict__ We_w,
                        const float* __restrict__ Wd_w,
                        char* __restrict__ ws8) {
  int e = blockIdx.x * 256 + threadIdx.x;
  if (e >= 40960) return;
  short* f16 = (short*)ws8;
  int region = e >> 14;                  // 0=WHS 1=WDDC 2=WDENC
  int er = e & 16383;
  int fi = er >> 9, li = (er >> 3) & 63, jq = er & 7;
  int kt = fi >> 2, nt = fi & 3;
  int k = kt * 32 + ((li >> 4) << 3) + jq, n = nt * 16 + (li & 15);
  float v;
  if (region == 0)      v = We_w[n * 257 + k];
  else if (region == 1) v = (k < 128) ? Wd_w[n * 384 + 128 + k]
                                      : Wd_w[n * 384 + 256 + (k - 128)];
  else                  v = Wd_w[n * 384 + k];
  f16[e] = f2b(v);
}

// ---- prep2: i8 quantized gates weights, one wave per column ----
__global__ void prep_q(const float* __restrict__ enc_Wih,
                       const float* __restrict__ enc_Whh,
                       const float* __restrict__ dec_Whh,
                       char* __restrict__ ws8) {
  int gw = (blockIdx.x * 256 + threadIdx.x) >> 6;
  int lane = threadIdx.x & 63;
  if (gw < 512) {                        // encoder col, K=256
    int n = gw;
    float v[4]; float m = 0.f;
#pragma unroll
    for (int q = 0; q < 4; ++q) {
      int k = lane * 4 + q;
      v[q] = (k < 128) ? enc_Wih[n * 128 + k] : enc_Whh[n * 128 + (k - 128)];
      m = fmaxf(m, fabsf(v[q]));
    }
    m = wmax64(m);
    if (lane == 0) ((float*)(ws8 + SENC_B))[n] = m * C127;
    float inv = m > 0.f ? 127.f / m : 0.f;
    char* dst = ws8 + WENC8_B;
#pragma unroll
    for (int q = 0; q < 4; ++q) {
      int k = lane * 4 + q;
      int kt = k >> 6, grp = (k >> 4) & 3, b = k & 15, l16 = (n & 15) | (grp << 4);
      dst[((kt * 32 + (n >> 4)) * 64 + l16) * 16 + b] = (char)(int)rintf(v[q] * inv);
    }
  } else if (gw < 1024) {                // decoder col, K=128
    int n = gw - 512;
    float v[2]; float m = 0.f;
#pragma unroll
    for (int q = 0; q < 2; ++q) {
      int k = lane * 2 + q;
      v[q] = dec_Whh[n * 128 + k];
      m = fmaxf(m, fabsf(v[q]));
    }
    m = wmax64(m);
    if (lane == 0) ((float*)(ws8 + SDEC_B))[n] = m * C127;
    float inv = m > 0.f ? 127.f / m : 0.f;
    char* dst = ws8 + WDEC8_B;
#pragma unroll
    for (int q = 0; q < 2; ++q) {
      int k = lane * 2 + q;
      int kt = k >> 6, grp = (k >> 4) & 3, b = k & 15, l16 = (n & 15) | (grp << 4);
      dst[((kt * 32 + (n >> 4)) * 64 + l16) * 16 + b] = (char)(int)rintf(v[q] * inv);
    }
  }
}

__global__ __launch_bounds__(512, 2)
void da_rnn(const float* __restrict__ X, const float* __restrict__ y_hist,
            const float* __restrict__ We_w, const float* __restrict__ We_b,
            const float* __restrict__ ve_w,
            const float* __restrict__ enc_bih, const float* __restrict__ enc_bhh,
            const float* __restrict__ dec_Wih,
            const float* __restrict__ dec_bih, const float* __restrict__ dec_bhh,
            const float* __restrict__ Wd_b, const float* __restrict__ vd_w,
            const float* __restrict__ fc_w, const float* __restrict__ fc_b,
            const char* __restrict__ ws8, float* __restrict__ out) {
  const short* f16  = (const short*)ws8;
  const i32x4* enc8 = (const i32x4*)(ws8 + WENC8_B);
  const i32x4* dec8 = (const i32x4*)(ws8 + WDEC8_B);
  const float* senc = (const float*)(ws8 + SENC_B);
  const float* sdec = (const float*)(ws8 + SDEC_B);

  // strides: s_A8 272B=68w (68%32=4 -> 2-way, free); s_Ahc 264sh=132w (4 mod 32)
  __shared__ __align__(16) char  s_A8[16][272];   // gates A i8
  __shared__ __align__(16) short s_Ahc[16][264];  // base/dc/proj A bf16 [h;c]
  __shared__ short s_projT[4][64][65];            // enc_proj^T
  __shared__ short s_encht[4][128][66];           // enc_hiddens [r][j][t] bf16
  __shared__ __align__(16) float s_gates[4][512]; // raw gate pre-acts (C^T b128)
  __shared__ __align__(16) float s_base[4][64];   // enc: base ; dec: dc
  __shared__ float s_beta[4][64];
  __shared__ float s_xr[4];
  __shared__ float2 s_wv[64];                     // (w_feat[k], ve_w[k])
  __shared__ __align__(16) float s_web[64];
  __shared__ float s_vd[64];
  __shared__ __align__(16) float s_wdb[64];
  __shared__ float s_se[512], s_sd[512];
  __shared__ float s_encb[512], s_decb[512], s_dwih[512];
  __shared__ float s_fcw[320];

  const int tid  = threadIdx.x;
  const int lane = tid & 63;
  const int w    = tid >> 6;        // wave 0..7 ; waves 0-3 own row w
  const int b0   = blockIdx.x * BB;

  // ---- init ----
  if (tid < 64) {
    s_wv[tid]  = make_float2(We_w[tid * 257 + 256], ve_w[tid]);
    s_web[tid] = We_b[tid];
    s_vd[tid]  = vd_w[tid];
    s_wdb[tid] = Wd_b[tid];
  }
  if (tid < 320) s_fcw[tid] = fc_w[tid];
  s_se[tid]   = senc[tid];
  s_sd[tid]   = sdec[tid];
  s_encb[tid] = enc_bih[tid] + enc_bhh[tid];
  s_decb[tid] = dec_bih[tid] + dec_bhh[tid];
  s_dwih[tid] = dec_Wih[tid];
  for (int i = tid; i < (16 * 272) / 4; i += 512) ((int*)s_A8)[i] = 0;
  for (int i = tid; i < (16 * 264) / 2; i += 512) ((int*)s_Ahc)[i] = 0;
  if (tid < 256) s_base[tid >> 6][tid & 63] = We_b[tid & 63];  // base_0

  // ---- register-resident weights (loaded once, L2) ----
  i32x4 wg[4][4];                       // enc gates i8, nt = w + 8i
#pragma unroll
  for (int kt = 0; kt < 4; ++kt)
#pragma unroll
    for (int i = 0; i < 4; ++i)
      wg[kt][i] = enc8[(kt * 32 + (w + 8 * i)) * 64 + lane];
  bf16x8 wb[8], wp[4];
  if (w < 4) {
#pragma unroll
    for (int kt = 0; kt < 8; ++kt)
      wb[kt] = *(const bf16x8*)(f16 + WHS_E + ((kt * 4 + w) * 64 + lane) * 8);
  } else {
#pragma unroll
    for (int kt = 0; kt < 4; ++kt)
      wp[kt] = *(const bf16x8*)(f16 + WDENC_E + ((kt * 4 + (w - 4)) * 64 + lane) * 8);
  }

  // per-row state (waves 0-3): features j0=lane, j1=lane+64
  float h0 = 0.f, c0 = 0.f, h1 = 0.f, c1 = 0.f;
  float xf0 = 0.f, xf1 = 0.f, xi = 0.f;
  const float* Xr = X + (size_t)(b0 + (w & 3)) * T_ * D_;
  if (w < 4) {
    xf0 = Xr[lane]; xf1 = Xr[64 + lane];    // x(t=0), consumed top of P_A(0)
    xi = 6.f * cosf((2 * (lane >> 3) + 1) * 0.19634954084936207f);  // node
  }
  __syncthreads();

  // ---- per-wave preloads (post-barrier: LDS constants now valid) ----
  float se_p[8], eb_p[8];
  f32x4 webq = {0.f, 0.f, 0.f, 0.f};
  if (w < 4) {
#pragma unroll
    for (int j = 0; j < 8; ++j) {
      se_p[j] = s_se[lane + 64 * j];
      eb_p[j] = s_encb[lane + 64 * j];
    }
    webq = *(const f32x4*)&s_web[(w << 4) + ((lane >> 4) << 2)];
  }
  // prefetched h-side A-frags for P_G (valid: s_A8 h-part zero-initialized)
  i32x4 pa2 = *(const i32x4*)&s_A8[lane & 15][128 + ((lane >> 4) << 4)];
  i32x4 pa3 = *(const i32x4*)&s_A8[lane & 15][192 + ((lane >> 4) << 4)];

  // ====================== encoder ======================
  for (int t = 0; t < T_; ++t) {
    // ---- P_A: input attention, in-wave, waves 0-3 (row = w) ----
    float x0, x1;
    if (w < 4) {
      x0 = xf0; x1 = xf1;                 // prefetched one step ago
      // node eval: lane = (ni = lane>>3, kc = lane&7); 8 k-terms each
      const int kc = lane & 7;
      float p = 0.f;
      const float4* wvp = (const float4*)&s_wv[kc * 8];
      const float4* bp  = (const float4*)&s_base[w][kc * 8];
      float4 bA = bp[0], bB = bp[1];
#pragma unroll
      for (int q = 0; q < 4; ++q) {
        float4 wv = wvp[q];                       // (w_k, ve_k, w_{k+1}, ve_{k+1})
        float bb0 = (q < 2) ? ((q & 1) ? bA.z : bA.x) : ((q & 1) ? bB.z : bB.x);
        float bb1 = (q < 2) ? ((q & 1) ? bA.w : bA.y) : ((q & 1) ? bB.w : bB.y);
        p += wv.y * tanh_acc(fmaf(xi, wv.x, bb0));
        p += wv.w * tanh_acc(fmaf(xi, wv.z, bb1));
      }
      p = gsum8(p);                               // sum over kc within node grp
      float f0 = __shfl(p,  0, 64), f1 = __shfl(p,  8, 64);
      float f2 = __shfl(p, 16, 64), f3 = __shfl(p, 24, 64);
      float f4 = __shfl(p, 32, 64), f5 = __shfl(p, 40, 64);
      float f6 = __shfl(p, 48, 64), f7 = __shfl(p, 56, 64);
      // barycentric interpolation at u = clamp(x, +-6), Cheb-1 nodes
      float sc0, sc1;
      {
        const float xb[8] = { 5.884711682f, 4.988817674f, 3.333421398f, 1.170541932f,
                             -1.170541932f, -3.333421398f, -4.988817674f, -5.884711682f};
        const float wbar[8] = { 0.1950903220f, -0.5555702330f, 0.8314696123f, -0.9807852804f,
                                0.9807852804f, -0.8314696123f, 0.5555702330f, -0.1950903220f};
        float u0 = fminf(fmaxf(x0, -6.f), 6.f), u1 = fminf(fmaxf(x1, -6.f), 6.f);
        float n0 = 0.f, d0 = 0.f, n1 = 0.f, d1 = 0.f;
        float fv[8] = {f0, f1, f2, f3, f4, f5, f6, f7};
#pragma unroll
        for (int i = 0; i < 8; ++i) {
          float dd0 = u0 - xb[i]; dd0 = copysignf(fmaxf(fabsf(dd0), 1e-5f), dd0);
          float dd1 = u1 - xb[i]; dd1 = copysignf(fmaxf(fabsf(dd1), 1e-5f), dd1);
          float t0 = wbar[i] * frcp(dd0), t1 = wbar[i] * frcp(dd1);
          n0 = fmaf(t0, fv[i], n0); d0 += t0;
          n1 = fmaf(t1, fv[i], n1); d1 += t1;
        }
        sc0 = n0 * frcp(d0); sc1 = n1 * frcp(d1);
      }
      float e0 = fexp2(sc0 * LOG2E), e1 = fexp2(sc1 * LOG2E);  // |sc|<=sum|ve|~2.6
      float sum = wsum64(e0 + e1);
      float mx  = wmax64(fmaxf(e0 * fabsf(x0), e1 * fabsf(x1)));
      float inv = mx > 0.f ? 127.f * frcp(mx) : 0.f;
      s_A8[w][lane]      = (char)(int)rintf(x0 * e0 * inv);
      s_A8[w][64 + lane] = (char)(int)rintf(x1 * e1 * inv);
      if (lane == 0) s_xr[w] = mx * frcp(127.f * sum);
    }
    __syncthreads();                                            // B1
    // ---- P_G: gates i8 GEMM, TRANSPOSED (C^T: lane&15=brow, regs=gcols) ----
    {
      i32x4 a0 = *(const i32x4*)&s_A8[lane & 15][  0 + ((lane >> 4) << 4)];
      i32x4 a1 = *(const i32x4*)&s_A8[lane & 15][ 64 + ((lane >> 4) << 4)];
      i32x4 ax[4], ah[4];
#pragma unroll
      for (int i = 0; i < 4; ++i) {
        i32x4 z = {0, 0, 0, 0};
        ax[i] = MFMAI8(wg[1][i], a1, MFMAI8(wg[0][i], a0, z));
        ah[i] = MFMAI8(wg[3][i], pa3, MFMAI8(wg[2][i], pa2, z));
      }
      float sx = s_xr[lane & 3];
      if ((lane & 15) < 4) {
        int cb = (lane >> 4) << 2;
#pragma unroll
        for (int i = 0; i < 4; ++i) {
          f32x4 v;
#pragma unroll
          for (int r = 0; r < 4; ++r)
            v[r] = fmaf(sx, (float)ax[i][r], C127 * (float)ah[i][r]);
          *(f32x4*)&s_gates[lane & 15][(w + 8 * i) * 16 + cb] = v;
        }
      }
    }
    __syncthreads();                                            // B2
    // ---- P_E: LSTM epilogue, in-wave, waves 0-3 (scale/bias from regs) ----
    if (w < 4) {
      float gi0 = fmaf(s_gates[w][lane]      , se_p[0], eb_p[0]);
      float gi1 = fmaf(s_gates[w][lane + 64] , se_p[1], eb_p[1]);
      float gf0 = fmaf(s_gates[w][lane + 128], se_p[2], eb_p[2]);
      float gf1 = fmaf(s_gates[w][lane + 192], se_p[3], eb_p[3]);
      float gg0 = fmaf(s_gates[w][lane + 256], se_p[4], eb_p[4]);
      float gg1 = fmaf(s_gates[w][lane + 320], se_p[5], eb_p[5]);
      float go0 = fmaf(s_gates[w][lane + 384], se_p[6], eb_p[6]);
      float go1 = fmaf(s_gates[w][lane + 448], se_p[7], eb_p[7]);
      c0 = sigm(gf0) * c0 + sigm(gi0) * tanh_acc(gg0);
      h0 = sigm(go0) * tanh_acc(c0);
      c1 = sigm(gf1) * c1 + sigm(gi1) * tanh_acc(gg1);
      h1 = sigm(go1) * tanh_acc(c1);
      s_Ahc[w][lane]        = f2b(h0);
      s_Ahc[w][lane + 64]   = f2b(h1);
      s_Ahc[w][lane + 128]  = f2b(c0);
      s_Ahc[w][lane + 192]  = f2b(c1);
      s_A8[w][128 + lane]      = (char)(int)rintf(h0 * 127.f);
      s_A8[w][128 + lane + 64] = (char)(int)rintf(h1 * 127.f);
      s_encht[w][lane][t]      = f2b(h0);
      s_encht[w][lane + 64][t] = f2b(h1);
    }
    __syncthreads();                                            // B3
    // ---- P_B: base_{t+1} (w0-3, transposed) | proj_t (w4-7) ; prefetches ----
    // h-frag prefetch for next P_G (s_A8 h-part valid since P_E)
    pa2 = *(const i32x4*)&s_A8[lane & 15][128 + ((lane >> 4) << 4)];
    pa3 = *(const i32x4*)&s_A8[lane & 15][192 + ((lane >> 4) << 4)];
    if (w < 4) {
      if (t < T_ - 1) {                   // X prefetch: one full step early
        xf0 = Xr[(t + 1) * D_ + lane];
        xf1 = Xr[(t + 1) * D_ + 64 + lane];
      }
      f32x4 acc = {0.f, 0.f, 0.f, 0.f}, acc2 = {0.f, 0.f, 0.f, 0.f};
#pragma unroll
      for (int kt = 0; kt < 4; ++kt) {
        bf16x8 a = *(const bf16x8*)&s_Ahc[lane & 15][kt * 32 + ((lane >> 4) << 3)];
        acc = MFMA16(wb[kt], a, acc);
      }
#pragma unroll
      for (int kt = 4; kt < 8; ++kt) {
        bf16x8 a = *(const bf16x8*)&s_Ahc[lane & 15][kt * 32 + ((lane >> 4) << 3)];
        acc2 = MFMA16(wb[kt], a, acc2);
      }
      if ((lane & 15) < 4) {
        f32x4 v = acc + acc2 + webq;
        *(f32x4*)&s_base[lane & 15][(w << 4) + ((lane >> 4) << 2)] = v;
      }
    } else {
      f32x4 acc = {0.f, 0.f, 0.f, 0.f};
#pragma unroll
      for (int kt = 0; kt < 4; ++kt) {
        bf16x8 a = *(const bf16x8*)&s_Ahc[lane & 15][kt * 32 + ((lane >> 4) << 3)];
        acc = MFMA16(a, wp[kt], acc);    // original orientation (strided store)
      }
      if (lane < 16) {
        int katt = (w - 4) * 16 + lane;
#pragma unroll
        for (int r = 0; r < 4; ++r) s_projT[r][katt][t] = f2b(acc[r]);
      }
    }
    __syncthreads();                                            // B4
  }

  // ====================== decoder ======================
  {
    int r = tid >> 7, j = tid & 127;
    s_Ahc[r][j] = 0; s_Ahc[r][128 + j] = 0; s_A8[r][j] = 0;
  }
  i32x4 wdg[2][8];                      // dec gates i8 (waves 4-7), nt=(w-4)*8+i
  bf16x8 wdc[8];                        // dc bf16 (waves 0-3)
  float yp = 0.f, yhd = 0.f;
  float sdC_p[8];
  f32x4 wdbq = {0.f, 0.f, 0.f, 0.f};
  if (w >= 4) {
#pragma unroll
    for (int kt = 0; kt < 2; ++kt)
#pragma unroll
      for (int i = 0; i < 8; ++i)
        wdg[kt][i] = dec8[(kt * 32 + ((w - 4) * 8 + i)) * 64 + lane];
  } else {
#pragma unroll
    for (int kt = 0; kt < 8; ++kt)
      wdc[kt] = *(const bf16x8*)(f16 + WDDC_E + ((kt * 4 + w) * 64 + lane) * 8);
#pragma unroll
    for (int j = 0; j < 8; ++j) sdC_p[j] = s_sd[lane + 64 * j] * C127;
    wdbq = *(const f32x4*)&s_wdb[(w << 4) + ((lane >> 4) << 2)];
    yp = y_hist[(b0 + w) * T_ + (T_ - 1)];
    float pp = s_fcw[256 + lane] * y_hist[(b0 + w) * T_ + lane];
    yhd = wsum64(pp) + fc_b[0];
  }
  float dd0 = 0.f, dc0 = 0.f, dd1 = 0.f, dc1 = 0.f;   // d, cc (2 feats/lane)
  __syncthreads();

  for (int hs = 0; hs < HOR_; ++hs) {
    // ---- P_dG: dec gates i8 (w4-7, transposed) | dc bf16 (w0-3, transposed)
    if (w >= 4) {
      i32x4 a0 = *(const i32x4*)&s_A8[lane & 15][ 0 + ((lane >> 4) << 4)];
      i32x4 a1 = *(const i32x4*)&s_A8[lane & 15][64 + ((lane >> 4) << 4)];
#pragma unroll
      for (int i = 0; i < 8; ++i) {
        i32x4 z = {0, 0, 0, 0};
        i32x4 ac = MFMAI8(wdg[1][i], a1, MFMAI8(wdg[0][i], a0, z));
        if ((lane & 15) < 4) {
          f32x4 v = {(float)ac[0], (float)ac[1], (float)ac[2], (float)ac[3]};
          *(f32x4*)&s_gates[lane & 15][(((w - 4) * 8 + i) << 4) + ((lane >> 4) << 2)] = v;
        }
      }
    } else {
      f32x4 acc = {0.f, 0.f, 0.f, 0.f}, acc2 = {0.f, 0.f, 0.f, 0.f};
#pragma unroll
      for (int kt = 0; kt < 4; ++kt) {
        bf16x8 a = *(const bf16x8*)&s_Ahc[lane & 15][kt * 32 + ((lane >> 4) << 3)];
        acc = MFMA16(wdc[kt], a, acc);
      }
#pragma unroll
      for (int kt = 4; kt < 8; ++kt) {
        bf16x8 a = *(const bf16x8*)&s_Ahc[lane & 15][kt * 32 + ((lane >> 4) << 3)];
        acc2 = MFMA16(wdc[kt], a, acc2);
      }
      if ((lane & 15) < 4) {
        f32x4 v = acc + acc2 + wdbq;
        *(f32x4*)&s_base[lane & 15][(w << 4) + ((lane >> 4) << 2)] = v;
      }
    }
    __syncthreads();                                            // B1
    // ---- P_dA: attention + context + epilogue + fc, in-wave (waves 0-3) ----
    if (w < 4) {
      // scores: lane = t' ; 4-way treed accumulation (64-deep -> 16-deep)
      float sA = 0.f, sB = 0.f, sC = 0.f, sD = 0.f;
#pragma unroll 4
      for (int k = 0; k < 64; k += 4) {
        sA += s_vd[k]     * tanh_acc(b2f(s_projT[w][k][lane])     + s_base[w][k]);
        sB += s_vd[k + 1] * tanh_acc(b2f(s_projT[w][k + 1][lane]) + s_base[w][k + 1]);
        sC += s_vd[k + 2] * tanh_acc(b2f(s_projT[w][k + 2][lane]) + s_base[w][k + 2]);
        sD += s_vd[k + 3] * tanh_acc(b2f(s_projT[w][k + 3][lane]) + s_base[w][k + 3]);
      }
      float s = (sA + sB) + (sC + sD);
      float e = fexp2(s * LOG2E);
      float ssum = wsum64(e);
      s_beta[w][lane] = e * frcp(ssum);
      // context: per lane features j0=lane, j1=lane+64 (same-wave LDS RAW ok)
      float cx0a = 0.f, cx0b = 0.f, cx1a = 0.f, cx1b = 0.f;
      const short* e0p = &s_encht[w][lane][0];
      const short* e1p = &s_encht[w][lane + 64][0];
#pragma unroll 8
      for (int tp = 0; tp < 32; ++tp) {
        float2 bta = *(const float2*)&s_beta[w][2 * tp];
        short2 h0v = *(const short2*)&e0p[2 * tp];
        short2 h1v = *(const short2*)&e1p[2 * tp];
        cx0a = fmaf(bta.x, b2f(h0v.x), cx0a); cx0b = fmaf(bta.y, b2f(h0v.y), cx0b);
        cx1a = fmaf(bta.x, b2f(h1v.x), cx1a); cx1b = fmaf(bta.y, b2f(h1v.y), cx1b);
      }
      float cx0 = cx0a + cx0b, cx1 = cx1a + cx1b;
      // LSTM epilogue (gates use OLD d via GEMM; +y_prev*dec_Wih)
      float gi0 = s_gates[w][lane]       * sdC_p[0] + s_decb[lane]       + yp * s_dwih[lane];
      float gi1 = s_gates[w][lane + 64]  * sdC_p[1] + s_decb[lane + 64]  + yp * s_dwih[lane + 64];
      float gf0 = s_gates[w][lane + 128] * sdC_p[2] + s_decb[lane + 128] + yp * s_dwih[lane + 128];
      float gf1 = s_gates[w][lane + 192] * sdC_p[3] + s_decb[lane + 192] + yp * s_dwih[lane + 192];
      float gg0 = s_gates[w][lane + 256] * sdC_p[4] + s_decb[lane + 256] + yp * s_dwih[lane + 256];
      float gg1 = s_gates[w][lane + 320] * sdC_p[5] + s_decb[lane + 320] + yp * s_dwih[lane + 320];
      float go0 = s_gates[w][lane + 384] * sdC_p[6] + s_decb[lane + 384] + yp * s_dwih[lane + 384];
      float go1 = s_gates[w][lane + 448] * sdC_p[7] + s_decb[lane + 448] + yp * s_dwih[lane + 448];
      dc0 = sigm(gf0) * dc0 + sigm(gi0) * tanh_acc(gg0);
      dd0 = sigm(go0) * tanh_acc(dc0);
      dc1 = sigm(gf1) * dc1 + sigm(gi1) * tanh_acc(gg1);
      dd1 = sigm(go1) * tanh_acc(dc1);
      // fc
      float pf = s_fcw[lane] * dd0 + s_fcw[64 + lane] * dd1
               + s_fcw[128 + lane] * cx0 + s_fcw[192 + lane] * cx1;
      pf = wsum64(pf);
      float o = pf + yhd;
      if (lane == 0) out[(b0 + w) * HOR_ + hs] = o;
      yp = o;
      // state for next P_dG
      s_Ahc[w][lane]       = f2b(dd0);
      s_Ahc[w][lane + 64]  = f2b(dd1);
      s_Ahc[w][lane + 128] = f2b(dc0);
      s_Ahc[w][lane + 192] = f2b(dc1);
      s_A8[w][lane]      = (char)(int)rintf(dd0 * 127.f);
      s_A8[w][lane + 64] = (char)(int)rintf(dd1 * 127.f);
    }
    __syncthreads();                                            // B2
  }
}

extern "C" void kernel_launch(void* const* d_in, const int* in_sizes, int n_in,
                              void* d_out, int out_size, void* d_ws, size_t ws_size,
                              hipStream_t stream) {
  (void)in_sizes; (void)n_in; (void)out_size; (void)ws_size;
  const float* X       = (const float*)d_in[0];
  const float* y_hist  = (const float*)d_in[1];
  const float* We_w    = (const float*)d_in[2];
  const float* We_b    = (const float*)d_in[3];
  const float* ve_w    = (const float*)d_in[4];
  // d_in[5] = ve_b : softmax-invariant, unused
  const float* enc_Wih = (const float*)d_in[6];
  const float* enc_Whh = (const float*)d_in[7];
  const float* enc_bih = (const float*)d_in[8];
  const float* enc_bhh = (const float*)d_in[9];
  const float* dec_Wih = (const float*)d_in[10];
  const float* dec_Whh = (const float*)d_in[11];
  const float* dec_bih = (const float*)d_in[12];
  const float* dec_bhh = (const float*)d_in[13];
  const float* Wd_w    = (const float*)d_in[14];
  const float* Wd_b    = (const float*)d_in[15];
  const float* vd_w    = (const float*)d_in[16];
  // d_in[17] = vd_b : softmax-invariant, unused
  const float* fc_w    = (const float*)d_in[18];
  const float* fc_b    = (const float*)d_in[19];

  char* ws8  = (char*)d_ws;
  float* out = (float*)d_out;

  prep_bf<<<160, 256, 0, stream>>>(We_w, Wd_w, ws8);
  prep_q <<<256, 256, 0, stream>>>(enc_Wih, enc_Whh, dec_Whh, ws8);
  da_rnn <<<B_ / BB, 512, 0, stream>>>(X, y_hist, We_w, We_b, ve_w,
                                       enc_bih, enc_bhh, dec_Wih, dec_bih, dec_bhh,
                                       Wd_b, vd_w, fc_w, fc_b, ws8, out);
}

// Round 7
// 314.390 us; speedup vs baseline: 2.3886x; 1.0344x over previous
//
#include <hip/hip_runtime.h>
#include <hip/hip_bf16.h>

// DA-RNN persistent kernel, round 13.
// R12 post-mortem (FAILED, absmax 1.36): permlane32_swap with BOTH operands
// the same value -> compiler aliases them to one register; the hardware swap
// then destroys the original half (r0 = r1 = swapped), so r0+r1 = 2*swapped
// != cross-half sum. Every wsum64/wmax64 (softmax, prep_q quant scales, fc)
// was wrong. LESSON: permlane*_swap needs distinct registers; not worth it.
// R13 = R12 with the reduction tail reverted to __shfl_xor(v,32,64) (proven
// R10/R11 path). Kept R12's three sound changes:
//  1) padded s_gates[4][528] / s_base[4][72] (strides 16/8 mod 32: <=2-way
//     bank conflicts on f32x4 C^T stores, was 4-way at 512/64)
//  2) Lagrange FIRST-form interpolation (rcp-free; lambda_i = wbar_i/17496
//     verified; constant-fn test = 1.0002)
//  3) ah (h-side gates MFMA) precomputed in P_B (same dataflow as R11's
//     pa2/pa3 prefetch, MFMA hoisted off P_G's critical path)
// BB=4, 256 blocks, __launch_bounds__(512,2): proven no-spill regime.

#define B_    1024
#define T_    64
#define D_    128
#define H_    128
#define HOR_  24
#define ATT_  64
#define BB    4
#define LOG2E 1.4426950408889634f
#define C127  (1.f/127.f)
// LOG2E / 17496 (Lagrange first-form normalization folded into exp2 arg)
#define KLAG  8.245856315e-05f

typedef float f32x4  __attribute__((ext_vector_type(4)));
typedef short bf16x8 __attribute__((ext_vector_type(8)));
typedef int   i32x4  __attribute__((ext_vector_type(4)));

#define MFMA16(a,b,c) __builtin_amdgcn_mfma_f32_16x16x32_bf16((a),(b),(c),0,0,0)
#define MFMAI8(a,b,c) __builtin_amdgcn_mfma_i32_16x16x64_i8((a),(b),(c),0,0,0)

// ---- workspace layout (same packing as R5..R12) ----
#define WHS_E    0        // base GEMM  B bf16: kt0..7, nt0..3  (16384 el)
#define WDDC_E   16384    // dc GEMM    B bf16: kt0..7, nt0..3  (16384 el)
#define WDENC_E  32768    // proj GEMM  B bf16: kt0..3, nt0..3  ( 8192 el)
#define WENC8_B  81920    // i8 enc gates B: [kt4][nt32][lane64][16] (131072 B)
#define WDEC8_B  212992   // i8 dec gates B: [kt2][nt32][lane64][16] ( 65536 B)
#define SENC_B   278528   // 512 f32 per-col scales (enc)
#define SDEC_B   280576   // 512 f32 per-col scales (dec)

__device__ __forceinline__ short f2b(float f) {        // fp32 -> bf16 RNE
  union { float f; unsigned u; } c; c.f = f;
  unsigned r = c.u + 0x7fffu + ((c.u >> 16) & 1u);
  return (short)(r >> 16);
}
__device__ __forceinline__ float b2f(short s) {
  union { unsigned u; float f; } c; c.u = ((unsigned)(unsigned short)s) << 16;
  return c.f;
}
__device__ __forceinline__ float fexp2(float x) { return __builtin_amdgcn_exp2f(x); }
__device__ __forceinline__ float frcp (float x) { return __builtin_amdgcn_rcpf(x); }
__device__ __forceinline__ float tanh_acc(float x) {   // 1 - 2/(1+e^{2x})
  float e = fexp2(x * 2.885390081777927f);
  return 1.f - 2.f * frcp(1.f + e);
}
__device__ __forceinline__ float sigm(float x) {
  return frcp(1.f + fexp2(-LOG2E * x));
}

// ---- fast cross-lane: DPP xor1/2/4/8, ds_swizzle xor16, shfl xor32 ----
template<int CTRL>
__device__ __forceinline__ float dppmov(float v) {
  return __builtin_bit_cast(float,
      __builtin_amdgcn_mov_dpp(__builtin_bit_cast(int, v), CTRL, 0xF, 0xF, true));
}
__device__ __forceinline__ float swz16(float v) {      // lane ^= 16
  return __builtin_bit_cast(float,
      __builtin_amdgcn_ds_swizzle(__builtin_bit_cast(int, v), 0x401F));
}
__device__ __forceinline__ float wsum64(float v) {
  v += dppmov<0xB1>(v);        // xor1  (quad_perm 1,0,3,2)
  v += dppmov<0x4E>(v);        // xor2  (quad_perm 2,3,0,1)
  v += dppmov<0x141>(v);       // xor4  (row_half_mirror)
  v += dppmov<0x140>(v);       // xor8  (row_mirror)
  v += swz16(v);               // xor16
  v += __shfl_xor(v, 32, 64);  // xor32 (ds_bpermute; permlane32_swap is
                               //        UNSAFE when operands alias - R12)
  return v;
}
__device__ __forceinline__ float wmax64(float v) {
  v = fmaxf(v, dppmov<0xB1>(v));
  v = fmaxf(v, dppmov<0x4E>(v));
  v = fmaxf(v, dppmov<0x141>(v));
  v = fmaxf(v, dppmov<0x140>(v));
  v = fmaxf(v, swz16(v));
  v = fmaxf(v, __shfl_xor(v, 32, 64));
  return v;
}
__device__ __forceinline__ float gsum8(float v) {      // sum within group of 8
  v += dppmov<0xB1>(v);
  v += dppmov<0x4E>(v);
  v += dppmov<0x141>(v);
  return v;
}

// ---- prep1: bf16 B-frags (base / dc / proj), one element per thread ----
__global__ void prep_bf(const float* __restrict__ We_w,
                        const float* __restrict__ Wd_w,
                        char* __restrict__ ws8) {
  int e = blockIdx.x * 256 + threadIdx.x;
  if (e >= 40960) return;
  short* f16 = (short*)ws8;
  int region = e >> 14;                  // 0=WHS 1=WDDC 2=WDENC
  int er = e & 16383;
  int fi = er >> 9, li = (er >> 3) & 63, jq = er & 7;
  int kt = fi >> 2, nt = fi & 3;
  int k = kt * 32 + ((li >> 4) << 3) + jq, n = nt * 16 + (li & 15);
  float v;
  if (region == 0)      v = We_w[n * 257 + k];
  else if (region == 1) v = (k < 128) ? Wd_w[n * 384 + 128 + k]
                                      : Wd_w[n * 384 + 256 + (k - 128)];
  else                  v = Wd_w[n * 384 + k];
  f16[e] = f2b(v);
}

// ---- prep2: i8 quantized gates weights, one wave per column ----
__global__ void prep_q(const float* __restrict__ enc_Wih,
                       const float* __restrict__ enc_Whh,
                       const float* __restrict__ dec_Whh,
                       char* __restrict__ ws8) {
  int gw = (blockIdx.x * 256 + threadIdx.x) >> 6;
  int lane = threadIdx.x & 63;
  if (gw < 512) {                        // encoder col, K=256
    int n = gw;
    float v[4]; float m = 0.f;
#pragma unroll
    for (int q = 0; q < 4; ++q) {
      int k = lane * 4 + q;
      v[q] = (k < 128) ? enc_Wih[n * 128 + k] : enc_Whh[n * 128 + (k - 128)];
      m = fmaxf(m, fabsf(v[q]));
    }
    m = wmax64(m);
    if (lane == 0) ((float*)(ws8 + SENC_B))[n] = m * C127;
    float inv = m > 0.f ? 127.f / m : 0.f;
    char* dst = ws8 + WENC8_B;
#pragma unroll
    for (int q = 0; q < 4; ++q) {
      int k = lane * 4 + q;
      int kt = k >> 6, grp = (k >> 4) & 3, b = k & 15, l16 = (n & 15) | (grp << 4);
      dst[((kt * 32 + (n >> 4)) * 64 + l16) * 16 + b] = (char)(int)rintf(v[q] * inv);
    }
  } else if (gw < 1024) {                // decoder col, K=128
    int n = gw - 512;
    float v[2]; float m = 0.f;
#pragma unroll
    for (int q = 0; q < 2; ++q) {
      int k = lane * 2 + q;
      v[q] = dec_Whh[n * 128 + k];
      m = fmaxf(m, fabsf(v[q]));
    }
    m = wmax64(m);
    if (lane == 0) ((float*)(ws8 + SDEC_B))[n] = m * C127;
    float inv = m > 0.f ? 127.f / m : 0.f;
    char* dst = ws8 + WDEC8_B;
#pragma unroll
    for (int q = 0; q < 2; ++q) {
      int k = lane * 2 + q;
      int kt = k >> 6, grp = (k >> 4) & 3, b = k & 15, l16 = (n & 15) | (grp << 4);
      dst[((kt * 32 + (n >> 4)) * 64 + l16) * 16 + b] = (char)(int)rintf(v[q] * inv);
    }
  }
}

__global__ __launch_bounds__(512, 2)
void da_rnn(const float* __restrict__ X, const float* __restrict__ y_hist,
            const float* __restrict__ We_w, const float* __restrict__ We_b,
            const float* __restrict__ ve_w,
            const float* __restrict__ enc_bih, const float* __restrict__ enc_bhh,
            const float* __restrict__ dec_Wih,
            const float* __restrict__ dec_bih, const float* __restrict__ dec_bhh,
            const float* __restrict__ Wd_b, const float* __restrict__ vd_w,
            const float* __restrict__ fc_w, const float* __restrict__ fc_b,
            const char* __restrict__ ws8, float* __restrict__ out) {
  const short* f16  = (const short*)ws8;
  const i32x4* enc8 = (const i32x4*)(ws8 + WENC8_B);
  const i32x4* dec8 = (const i32x4*)(ws8 + WDEC8_B);
  const float* senc = (const float*)(ws8 + SENC_B);
  const float* sdec = (const float*)(ws8 + SDEC_B);

  // strides mod 32 words: s_A8 68=4, s_Ahc 132=4, s_gates 528=16, s_base 72=8
  __shared__ __align__(16) char  s_A8[16][272];   // gates A i8
  __shared__ __align__(16) short s_Ahc[16][264];  // base/dc/proj A bf16 [h;c]
  __shared__ short s_projT[4][64][65];            // enc_proj^T
  __shared__ short s_encht[4][128][66];           // enc_hiddens [r][j][t] bf16
  __shared__ __align__(16) float s_gates[4][528]; // raw gate pre-acts (C^T b128)
  __shared__ __align__(16) float s_base[4][72];   // enc: base ; dec: dc
  __shared__ float s_beta[4][64];
  __shared__ float s_xr[4];
  __shared__ float2 s_wv[64];                     // (w_feat[k], ve_w[k])
  __shared__ __align__(16) float s_web[64];
  __shared__ float s_vd[64];
  __shared__ __align__(16) float s_wdb[64];
  __shared__ float s_se[512], s_sd[512];
  __shared__ float s_encb[512], s_decb[512], s_dwih[512];
  __shared__ float s_fcw[320];

  const int tid  = threadIdx.x;
  const int lane = tid & 63;
  const int w    = tid >> 6;        // wave 0..7 ; waves 0-3 own row w
  const int b0   = blockIdx.x * BB;

  // ---- init ----
  if (tid < 64) {
    s_wv[tid]  = make_float2(We_w[tid * 257 + 256], ve_w[tid]);
    s_web[tid] = We_b[tid];
    s_vd[tid]  = vd_w[tid];
    s_wdb[tid] = Wd_b[tid];
  }
  if (tid < 320) s_fcw[tid] = fc_w[tid];
  s_se[tid]   = senc[tid];
  s_sd[tid]   = sdec[tid];
  s_encb[tid] = enc_bih[tid] + enc_bhh[tid];
  s_decb[tid] = dec_bih[tid] + dec_bhh[tid];
  s_dwih[tid] = dec_Wih[tid];
  for (int i = tid; i < (16 * 272) / 4; i += 512) ((int*)s_A8)[i] = 0;
  for (int i = tid; i < (16 * 264) / 2; i += 512) ((int*)s_Ahc)[i] = 0;
  if (tid < 256) s_base[tid >> 6][tid & 63] = We_b[tid & 63];  // base_0

  // ---- register-resident weights (loaded once, L2) ----
  i32x4 wg[4][4];                       // enc gates i8, nt = w + 8i
#pragma unroll
  for (int kt = 0; kt < 4; ++kt)
#pragma unroll
    for (int i = 0; i < 4; ++i)
      wg[kt][i] = enc8[(kt * 32 + (w + 8 * i)) * 64 + lane];
  bf16x8 wb[8], wp[4];
  if (w < 4) {
#pragma unroll
    for (int kt = 0; kt < 8; ++kt)
      wb[kt] = *(const bf16x8*)(f16 + WHS_E + ((kt * 4 + w) * 64 + lane) * 8);
  } else {
#pragma unroll
    for (int kt = 0; kt < 4; ++kt)
      wp[kt] = *(const bf16x8*)(f16 + WDENC_E + ((kt * 4 + (w - 4)) * 64 + lane) * 8);
  }

  // per-row state (waves 0-3): features j0=lane, j1=lane+64
  float h0 = 0.f, c0 = 0.f, h1 = 0.f, c1 = 0.f;
  float xf0 = 0.f, xf1 = 0.f, xi = 0.f;
  const float* Xr = X + (size_t)(b0 + (w & 3)) * T_ * D_;
  if (w < 4) {
    xf0 = Xr[lane]; xf1 = Xr[64 + lane];    // x(t=0), consumed top of P_A(0)
    xi = 6.f * cosf((2 * (lane >> 3) + 1) * 0.19634954084936207f);  // node
  }
  // h-side gates contribution (precomputed each P_B; h_0 = 0 -> zero)
  i32x4 ahp[4];
#pragma unroll
  for (int i = 0; i < 4; ++i) ahp[i] = (i32x4){0, 0, 0, 0};
  __syncthreads();

  // ---- per-wave preloads (post-barrier: LDS constants now valid) ----
  float se_p[8], eb_p[8];
  f32x4 webq = {0.f, 0.f, 0.f, 0.f};
  if (w < 4) {
#pragma unroll
    for (int j = 0; j < 8; ++j) {
      se_p[j] = s_se[lane + 64 * j];
      eb_p[j] = s_encb[lane + 64 * j];
    }
    webq = *(const f32x4*)&s_web[(w << 4) + ((lane >> 4) << 2)];
  }

  // ====================== encoder ======================
  for (int t = 0; t < T_; ++t) {
    // ---- P_A: input attention, in-wave, waves 0-3 (row = w) ----
    float x0, x1;
    if (w < 4) {
      x0 = xf0; x1 = xf1;                 // prefetched one step ago
      // node eval: lane = (ni = lane>>3, kc = lane&7); 8 k-terms each
      const int kc = lane & 7;
      float p = 0.f;
      const float4* wvp = (const float4*)&s_wv[kc * 8];
      const float4* bp  = (const float4*)&s_base[w][kc * 8];
      float4 bA = bp[0], bB = bp[1];
#pragma unroll
      for (int q = 0; q < 4; ++q) {
        float4 wv = wvp[q];                       // (w_k, ve_k, w_{k+1}, ve_{k+1})
        float bb0 = (q < 2) ? ((q & 1) ? bA.z : bA.x) : ((q & 1) ? bB.z : bB.x);
        float bb1 = (q < 2) ? ((q & 1) ? bA.w : bA.y) : ((q & 1) ? bB.w : bB.y);
        p += wv.y * tanh_acc(fmaf(xi, wv.x, bb0));
        p += wv.w * tanh_acc(fmaf(xi, wv.z, bb1));
      }
      p = gsum8(p);                               // sum over kc within node grp
      float f0 = __shfl(p,  0, 64), f1 = __shfl(p,  8, 64);
      float f2 = __shfl(p, 16, 64), f3 = __shfl(p, 24, 64);
      float f4 = __shfl(p, 32, 64), f5 = __shfl(p, 40, 64);
      float f6 = __shfl(p, 48, 64), f7 = __shfl(p, 56, 64);
      // Lagrange FIRST form at u = clamp(x, +-6): rcp-free.
      // p(u) = (1/17496) * sum_i f_i * wbar_i * prod_{j!=i}(u - x_j)
      float e0, e1;
      {
        const float xb[8] = { 5.884711682f, 4.988817674f, 3.333421398f, 1.170541932f,
                             -1.170541932f, -3.333421398f, -4.988817674f, -5.884711682f};
        const float wbar[8] = { 0.1950903220f, -0.5555702330f, 0.8314696123f, -0.9807852804f,
                                0.9807852804f, -0.8314696123f, 0.5555702330f, -0.1950903220f};
        float fw[8] = {f0 * wbar[0], f1 * wbar[1], f2 * wbar[2], f3 * wbar[3],
                       f4 * wbar[4], f5 * wbar[5], f6 * wbar[6], f7 * wbar[7]};
        float u0 = fminf(fmaxf(x0, -6.f), 6.f), u1 = fminf(fmaxf(x1, -6.f), 6.f);
        float d0[8], d1[8], P0[8], P1[8];
        float pre0 = 1.f, pre1 = 1.f;
#pragma unroll
        for (int i = 0; i < 8; ++i) {
          d0[i] = u0 - xb[i]; d1[i] = u1 - xb[i];
          P0[i] = pre0;       P1[i] = pre1;
          pre0 *= d0[i];      pre1 *= d1[i];
        }
        float suf0 = 1.f, suf1 = 1.f, acc0 = 0.f, acc1 = 0.f;
#pragma unroll
        for (int i = 7; i >= 0; --i) {
          acc0 = fmaf(fw[i] * P0[i], suf0, acc0);
          acc1 = fmaf(fw[i] * P1[i], suf1, acc1);
          suf0 *= d0[i];
          suf1 *= d1[i];
        }
        e0 = fexp2(acc0 * KLAG);                  // exp(sc), sc=acc/17496
        e1 = fexp2(acc1 * KLAG);
      }
      float sum = wsum64(e0 + e1);
      float mx  = wmax64(fmaxf(e0 * fabsf(x0), e1 * fabsf(x1)));
      float inv = mx > 0.f ? 127.f * frcp(mx) : 0.f;
      s_A8[w][lane]      = (char)(int)rintf(x0 * e0 * inv);
      s_A8[w][64 + lane] = (char)(int)rintf(x1 * e1 * inv);
      if (lane == 0) s_xr[w] = mx * frcp(127.f * sum);
    }
    __syncthreads();                                            // B1
    // ---- P_G: gates i8 GEMM, TRANSPOSED (C^T: lane&15=brow, regs=gcols) ----
    // h-side contribution (ahp) precomputed last P_B; only x-side here.
    {
      i32x4 a0 = *(const i32x4*)&s_A8[lane & 15][  0 + ((lane >> 4) << 4)];
      i32x4 a1 = *(const i32x4*)&s_A8[lane & 15][ 64 + ((lane >> 4) << 4)];
      i32x4 ax[4];
#pragma unroll
      for (int i = 0; i < 4; ++i) {
        i32x4 z = {0, 0, 0, 0};
        ax[i] = MFMAI8(wg[1][i], a1, MFMAI8(wg[0][i], a0, z));
      }
      float sx = s_xr[lane & 3];
      if ((lane & 15) < 4) {
        int cb = (lane >> 4) << 2;
#pragma unroll
        for (int i = 0; i < 4; ++i) {
          f32x4 v;
#pragma unroll
          for (int r = 0; r < 4; ++r)
            v[r] = fmaf(sx, (float)ax[i][r], C127 * (float)ahp[i][r]);
          *(f32x4*)&s_gates[lane & 15][(w + 8 * i) * 16 + cb] = v;
        }
      }
    }
    __syncthreads();                                            // B2
    // ---- P_E: LSTM epilogue, in-wave, waves 0-3 (scale/bias from regs) ----
    if (w < 4) {
      float gi0 = fmaf(s_gates[w][lane]      , se_p[0], eb_p[0]);
      float gi1 = fmaf(s_gates[w][lane + 64] , se_p[1], eb_p[1]);
      float gf0 = fmaf(s_gates[w][lane + 128], se_p[2], eb_p[2]);
      float gf1 = fmaf(s_gates[w][lane + 192], se_p[3], eb_p[3]);
      float gg0 = fmaf(s_gates[w][lane + 256], se_p[4], eb_p[4]);
      float gg1 = fmaf(s_gates[w][lane + 320], se_p[5], eb_p[5]);
      float go0 = fmaf(s_gates[w][lane + 384], se_p[6], eb_p[6]);
      float go1 = fmaf(s_gates[w][lane + 448], se_p[7], eb_p[7]);
      c0 = sigm(gf0) * c0 + sigm(gi0) * tanh_acc(gg0);
      h0 = sigm(go0) * tanh_acc(c0);
      c1 = sigm(gf1) * c1 + sigm(gi1) * tanh_acc(gg1);
      h1 = sigm(go1) * tanh_acc(c1);
      s_Ahc[w][lane]        = f2b(h0);
      s_Ahc[w][lane + 64]   = f2b(h1);
      s_Ahc[w][lane + 128]  = f2b(c0);
      s_Ahc[w][lane + 192]  = f2b(c1);
      s_A8[w][128 + lane]      = (char)(int)rintf(h0 * 127.f);
      s_A8[w][128 + lane + 64] = (char)(int)rintf(h1 * 127.f);
      s_encht[w][lane][t]      = f2b(h0);
      s_encht[w][lane + 64][t] = f2b(h1);
    }
    __syncthreads();                                            // B3
    // ---- P_B: base_{t+1} (w0-3, transposed) | proj_t (w4-7) ; ah-precompute
    {
      i32x4 pa2 = *(const i32x4*)&s_A8[lane & 15][128 + ((lane >> 4) << 4)];
      i32x4 pa3 = *(const i32x4*)&s_A8[lane & 15][192 + ((lane >> 4) << 4)];
#pragma unroll
      for (int i = 0; i < 4; ++i) {
        i32x4 z = {0, 0, 0, 0};
        ahp[i] = MFMAI8(wg[3][i], pa3, MFMAI8(wg[2][i], pa2, z));
      }
    }
    if (w < 4) {
      if (t < T_ - 1) {                   // X prefetch: one full step early
        xf0 = Xr[(t + 1) * D_ + lane];
        xf1 = Xr[(t + 1) * D_ + 64 + lane];
      }
      f32x4 acc = {0.f, 0.f, 0.f, 0.f}, acc2 = {0.f, 0.f, 0.f, 0.f};
#pragma unroll
      for (int kt = 0; kt < 4; ++kt) {
        bf16x8 a = *(const bf16x8*)&s_Ahc[lane & 15][kt * 32 + ((lane >> 4) << 3)];
        acc = MFMA16(wb[kt], a, acc);
      }
#pragma unroll
      for (int kt = 4; kt < 8; ++kt) {
        bf16x8 a = *(const bf16x8*)&s_Ahc[lane & 15][kt * 32 + ((lane >> 4) << 3)];
        acc2 = MFMA16(wb[kt], a, acc2);
      }
      if ((lane & 15) < 4) {
        f32x4 v = acc + acc2 + webq;
        *(f32x4*)&s_base[lane & 15][(w << 4) + ((lane >> 4) << 2)] = v;
      }
    } else {
      f32x4 acc = {0.f, 0.f, 0.f, 0.f};
#pragma unroll
      for (int kt = 0; kt < 4; ++kt) {
        bf16x8 a = *(const bf16x8*)&s_Ahc[lane & 15][kt * 32 + ((lane >> 4) << 3)];
        acc = MFMA16(a, wp[kt], acc);    // original orientation (strided store)
      }
      if (lane < 16) {
        int katt = (w - 4) * 16 + lane;
#pragma unroll
        for (int r = 0; r < 4; ++r) s_projT[r][katt][t] = f2b(acc[r]);
      }
    }
    __syncthreads();                                            // B4
  }

  // ====================== decoder ======================
  {
    int r = tid >> 7, j = tid & 127;
    s_Ahc[r][j] = 0; s_Ahc[r][128 + j] = 0; s_A8[r][j] = 0;
  }
  i32x4 wdg[2][8];                      // dec gates i8 (waves 4-7), nt=(w-4)*8+i
  bf16x8 wdc[8];                        // dc bf16 (waves 0-3)
  float yp = 0.f, yhd = 0.f;
  float sdC_p[8];
  f32x4 wdbq = {0.f, 0.f, 0.f, 0.f};
  if (w >= 4) {
#pragma unroll
    for (int kt = 0; kt < 2; ++kt)
#pragma unroll
      for (int i = 0; i < 8; ++i)
        wdg[kt][i] = dec8[(kt * 32 + ((w - 4) * 8 + i)) * 64 + lane];
  } else {
#pragma unroll
    for (int kt = 0; kt < 8; ++kt)
      wdc[kt] = *(const bf16x8*)(f16 + WDDC_E + ((kt * 4 + w) * 64 + lane) * 8);
#pragma unroll
    for (int j = 0; j < 8; ++j) sdC_p[j] = s_sd[lane + 64 * j] * C127;
    wdbq = *(const f32x4*)&s_wdb[(w << 4) + ((lane >> 4) << 2)];
    yp = y_hist[(b0 + w) * T_ + (T_ - 1)];
    float pp = s_fcw[256 + lane] * y_hist[(b0 + w) * T_ + lane];
    yhd = wsum64(pp) + fc_b[0];
  }
  float dd0 = 0.f, dc0 = 0.f, dd1 = 0.f, dc1 = 0.f;   // d, cc (2 feats/lane)
  __syncthreads();

  for (int hs = 0; hs < HOR_; ++hs) {
    // ---- P_dG: dec gates i8 (w4-7, transposed) | dc bf16 (w0-3, transposed)
    if (w >= 4) {
      i32x4 a0 = *(const i32x4*)&s_A8[lane & 15][ 0 + ((lane >> 4) << 4)];
      i32x4 a1 = *(const i32x4*)&s_A8[lane & 15][64 + ((lane >> 4) << 4)];
#pragma unroll
      for (int i = 0; i < 8; ++i) {
        i32x4 z = {0, 0, 0, 0};
        i32x4 ac = MFMAI8(wdg[1][i], a1, MFMAI8(wdg[0][i], a0, z));
        if ((lane & 15) < 4) {
          f32x4 v = {(float)ac[0], (float)ac[1], (float)ac[2], (float)ac[3]};
          *(f32x4*)&s_gates[lane & 15][(((w - 4) * 8 + i) << 4) + ((lane >> 4) << 2)] = v;
        }
      }
    } else {
      f32x4 acc = {0.f, 0.f, 0.f, 0.f}, acc2 = {0.f, 0.f, 0.f, 0.f};
#pragma unroll
      for (int kt = 0; kt < 4; ++kt) {
        bf16x8 a = *(const bf16x8*)&s_Ahc[lane & 15][kt * 32 + ((lane >> 4) << 3)];
        acc = MFMA16(wdc[kt], a, acc);
      }
#pragma unroll
      for (int kt = 4; kt < 8; ++kt) {
        bf16x8 a = *(const bf16x8*)&s_Ahc[lane & 15][kt * 32 + ((lane >> 4) << 3)];
        acc2 = MFMA16(wdc[kt], a, acc2);
      }
      if ((lane & 15) < 4) {
        f32x4 v = acc + acc2 + wdbq;
        *(f32x4*)&s_base[lane & 15][(w << 4) + ((lane >> 4) << 2)] = v;
      }
    }
    __syncthreads();                                            // B1
    // ---- P_dA: attention + context + epilogue + fc, in-wave (waves 0-3) ----
    if (w < 4) {
      // scores: lane = t' ; 4-way treed accumulation (64-deep -> 16-deep)
      float sA = 0.f, sB = 0.f, sC = 0.f, sD = 0.f;
#pragma unroll 4
      for (int k = 0; k < 64; k += 4) {
        sA += s_vd[k]     * tanh_acc(b2f(s_projT[w][k][lane])     + s_base[w][k]);
        sB += s_vd[k + 1] * tanh_acc(b2f(s_projT[w][k + 1][lane]) + s_base[w][k + 1]);
        sC += s_vd[k + 2] * tanh_acc(b2f(s_projT[w][k + 2][lane]) + s_base[w][k + 2]);
        sD += s_vd[k + 3] * tanh_acc(b2f(s_projT[w][k + 3][lane]) + s_base[w][k + 3]);
      }
      float s = (sA + sB) + (sC + sD);
      float e = fexp2(s * LOG2E);
      float ssum = wsum64(e);
      s_beta[w][lane] = e * frcp(ssum);
      // context: per lane features j0=lane, j1=lane+64 (same-wave LDS RAW ok)
      float cx0a = 0.f, cx0b = 0.f, cx1a = 0.f, cx1b = 0.f;
      const short* e0p = &s_encht[w][lane][0];
      const short* e1p = &s_encht[w][lane + 64][0];
#pragma unroll 8
      for (int tp = 0; tp < 32; ++tp) {
        float2 bta = *(const float2*)&s_beta[w][2 * tp];
        short2 h0v = *(const short2*)&e0p[2 * tp];
        short2 h1v = *(const short2*)&e1p[2 * tp];
        cx0a = fmaf(bta.x, b2f(h0v.x), cx0a); cx0b = fmaf(bta.y, b2f(h0v.y), cx0b);
        cx1a = fmaf(bta.x, b2f(h1v.x), cx1a); cx1b = fmaf(bta.y, b2f(h1v.y), cx1b);
      }
      float cx0 = cx0a + cx0b, cx1 = cx1a + cx1b;
      // LSTM epilogue (gates use OLD d via GEMM; +y_prev*dec_Wih)
      float gi0 = s_gates[w][lane]       * sdC_p[0] + s_decb[lane]       + yp * s_dwih[lane];
      float gi1 = s_gates[w][lane + 64]  * sdC_p[1] + s_decb[lane + 64]  + yp * s_dwih[lane + 64];
      float gf0 = s_gates[w][lane + 128] * sdC_p[2] + s_decb[lane + 128] + yp * s_dwih[lane + 128];
      float gf1 = s_gates[w][lane + 192] * sdC_p[3] + s_decb[lane + 192] + yp * s_dwih[lane + 192];
      float gg0 = s_gates[w][lane + 256] * sdC_p[4] + s_decb[lane + 256] + yp * s_dwih[lane + 256];
      float gg1 = s_gates[w][lane + 320] * sdC_p[5] + s_decb[lane + 320] + yp * s_dwih[lane + 320];
      float go0 = s_gates[w][lane + 384] * sdC_p[6] + s_decb[lane + 384] + yp * s_dwih[lane + 384];
      float go1 = s_gates[w][lane + 448] * sdC_p[7] + s_decb[lane + 448] + yp * s_dwih[lane + 448];
      dc0 = sigm(gf0) * dc0 + sigm(gi0) * tanh_acc(gg0);
      dd0 = sigm(go0) * tanh_acc(dc0);
      dc1 = sigm(gf1) * dc1 + sigm(gi1) * tanh_acc(gg1);
      dd1 = sigm(go1) * tanh_acc(dc1);
      // fc
      float pf = s_fcw[lane] * dd0 + s_fcw[64 + lane] * dd1
               + s_fcw[128 + lane] * cx0 + s_fcw[192 + lane] * cx1;
      pf = wsum64(pf);
      float o = pf + yhd;
      if (lane == 0) out[(b0 + w) * HOR_ + hs] = o;
      yp = o;
      // state for next P_dG
      s_Ahc[w][lane]       = f2b(dd0);
      s_Ahc[w][lane + 64]  = f2b(dd1);
      s_Ahc[w][lane + 128] = f2b(dc0);
      s_Ahc[w][lane + 192] = f2b(dc1);
      s_A8[w][lane]      = (char)(int)rintf(dd0 * 127.f);
      s_A8[w][lane + 64] = (char)(int)rintf(dd1 * 127.f);
    }
    __syncthreads();                                            // B2
  }
}

extern "C" void kernel_launch(void* const* d_in, const int* in_sizes, int n_in,
                              void* d_out, int out_size, void* d_ws, size_t ws_size,
                              hipStream_t stream) {
  (void)in_sizes; (void)n_in; (void)out_size; (void)ws_size;
  const float* X       = (const float*)d_in[0];
  const float* y_hist  = (const float*)d_in[1];
  const float* We_w    = (const float*)d_in[2];
  const float* We_b    = (const float*)d_in[3];
  const float* ve_w    = (const float*)d_in[4];
  // d_in[5] = ve_b : softmax-invariant, unused
  const float* enc_Wih = (const float*)d_in[6];
  const float* enc_Whh = (const float*)d_in[7];
  const float* enc_bih = (const float*)d_in[8];
  const float* enc_bhh = (const float*)d_in[9];
  const float* dec_Wih = (const float*)d_in[10];
  const float* dec_Whh = (const float*)d_in[11];
  const float* dec_bih = (const float*)d_in[12];
  const float* dec_bhh = (const float*)d_in[13];
  const float* Wd_w    = (const float*)d_in[14];
  const float* Wd_b    = (const float*)d_in[15];
  const float* vd_w    = (const float*)d_in[16];
  // d_in[17] = vd_b : softmax-invariant, unused
  const float* fc_w    = (const float*)d_in[18];
  const float* fc_b    = (const float*)d_in[19];

  char* ws8  = (char*)d_ws;
  float* out = (float*)d_out;

  prep_bf<<<160, 256, 0, stream>>>(We_w, Wd_w, ws8);
  prep_q <<<256, 256, 0, stream>>>(enc_Wih, enc_Whh, dec_Whh, ws8);
  da_rnn <<<B_ / BB, 512, 0, stream>>>(X, y_hist, We_w, We_b, ve_w,
                                       enc_bih, enc_bhh, dec_Wih, dec_bih, dec_bhh,
                                       Wd_b, vd_w, fc_w, fc_b, ws8, out);
}

// Round 8
// 300.151 us; speedup vs baseline: 2.5019x; 1.0474x over previous
//
#include <hip/hip_runtime.h>
#include <hip/hip_bf16.h>

// DA-RNN persistent kernel, round 14: idle-wave elimination.
// R13 confirmed (225us, -18% cumulative). Remaining: two phases leave half
// the waves idle on serial chains.
//  1) Encoder P_E split over 8 waves: wave w -> row w&3, feature
//     (w>>2)*64+lane. 1 cell/lane (5 trans, was 10). Trans issue/SIMD
//     unchanged (R9 lesson: wide lanes, few trans/lane); chain halves and
//     2 waves/SIMD interleave.
//  2) Decoder 2-phase overlap: Phase A = {w0-3: context+fc+out(hs-1) then
//     dc GEMM | w4-7: gates GEMM}; Phase B = {w0-3: LSTM epilogue | w4-7:
//     scores+softmax -> s_beta}. The 64-tanh score chain runs concurrently
//     with the epilogue; context+fc overlaps the GEMMs. Same 2 barriers.
//     Final output in post-loop tail. All LDS producer/consumer pairs cross
//     exactly one barrier (audited).
// Ops identical to R13 -> absmax unchanged.
// BB=4, 256 blocks, __launch_bounds__(512,2): proven no-spill regime.

#define B_    1024
#define T_    64
#define D_    128
#define H_    128
#define HOR_  24
#define ATT_  64
#define BB    4
#define LOG2E 1.4426950408889634f
#define C127  (1.f/127.f)
// LOG2E / 17496 (Lagrange first-form normalization folded into exp2 arg)
#define KLAG  8.245856315e-05f

typedef float f32x4  __attribute__((ext_vector_type(4)));
typedef short bf16x8 __attribute__((ext_vector_type(8)));
typedef int   i32x4  __attribute__((ext_vector_type(4)));

#define MFMA16(a,b,c) __builtin_amdgcn_mfma_f32_16x16x32_bf16((a),(b),(c),0,0,0)
#define MFMAI8(a,b,c) __builtin_amdgcn_mfma_i32_16x16x64_i8((a),(b),(c),0,0,0)

// ---- workspace layout (same packing as R5..R13) ----
#define WHS_E    0        // base GEMM  B bf16: kt0..7, nt0..3  (16384 el)
#define WDDC_E   16384    // dc GEMM    B bf16: kt0..7, nt0..3  (16384 el)
#define WDENC_E  32768    // proj GEMM  B bf16: kt0..3, nt0..3  ( 8192 el)
#define WENC8_B  81920    // i8 enc gates B: [kt4][nt32][lane64][16] (131072 B)
#define WDEC8_B  212992   // i8 dec gates B: [kt2][nt32][lane64][16] ( 65536 B)
#define SENC_B   278528   // 512 f32 per-col scales (enc)
#define SDEC_B   280576   // 512 f32 per-col scales (dec)

__device__ __forceinline__ short f2b(float f) {        // fp32 -> bf16 RNE
  union { float f; unsigned u; } c; c.f = f;
  unsigned r = c.u + 0x7fffu + ((c.u >> 16) & 1u);
  return (short)(r >> 16);
}
__device__ __forceinline__ float b2f(short s) {
  union { unsigned u; float f; } c; c.u = ((unsigned)(unsigned short)s) << 16;
  return c.f;
}
__device__ __forceinline__ float fexp2(float x) { return __builtin_amdgcn_exp2f(x); }
__device__ __forceinline__ float frcp (float x) { return __builtin_amdgcn_rcpf(x); }
__device__ __forceinline__ float tanh_acc(float x) {   // 1 - 2/(1+e^{2x})
  float e = fexp2(x * 2.885390081777927f);
  return 1.f - 2.f * frcp(1.f + e);
}
__device__ __forceinline__ float sigm(float x) {
  return frcp(1.f + fexp2(-LOG2E * x));
}

// ---- fast cross-lane: DPP xor1/2/4/8, ds_swizzle xor16, shfl xor32 ----
template<int CTRL>
__device__ __forceinline__ float dppmov(float v) {
  return __builtin_bit_cast(float,
      __builtin_amdgcn_mov_dpp(__builtin_bit_cast(int, v), CTRL, 0xF, 0xF, true));
}
__device__ __forceinline__ float swz16(float v) {      // lane ^= 16
  return __builtin_bit_cast(float,
      __builtin_amdgcn_ds_swizzle(__builtin_bit_cast(int, v), 0x401F));
}
__device__ __forceinline__ float wsum64(float v) {
  v += dppmov<0xB1>(v);        // xor1  (quad_perm 1,0,3,2)
  v += dppmov<0x4E>(v);        // xor2  (quad_perm 2,3,0,1)
  v += dppmov<0x141>(v);       // xor4  (row_half_mirror)
  v += dppmov<0x140>(v);       // xor8  (row_mirror)
  v += swz16(v);               // xor16
  v += __shfl_xor(v, 32, 64);  // xor32 (permlane32_swap UNSAFE when aliased - R12)
  return v;
}
__device__ __forceinline__ float wmax64(float v) {
  v = fmaxf(v, dppmov<0xB1>(v));
  v = fmaxf(v, dppmov<0x4E>(v));
  v = fmaxf(v, dppmov<0x141>(v));
  v = fmaxf(v, dppmov<0x140>(v));
  v = fmaxf(v, swz16(v));
  v = fmaxf(v, __shfl_xor(v, 32, 64));
  return v;
}
__device__ __forceinline__ float gsum8(float v) {      // sum within group of 8
  v += dppmov<0xB1>(v);
  v += dppmov<0x4E>(v);
  v += dppmov<0x141>(v);
  return v;
}

// ---- prep1: bf16 B-frags (base / dc / proj), one element per thread ----
__global__ void prep_bf(const float* __restrict__ We_w,
                        const float* __restrict__ Wd_w,
                        char* __restrict__ ws8) {
  int e = blockIdx.x * 256 + threadIdx.x;
  if (e >= 40960) return;
  short* f16 = (short*)ws8;
  int region = e >> 14;                  // 0=WHS 1=WDDC 2=WDENC
  int er = e & 16383;
  int fi = er >> 9, li = (er >> 3) & 63, jq = er & 7;
  int kt = fi >> 2, nt = fi & 3;
  int k = kt * 32 + ((li >> 4) << 3) + jq, n = nt * 16 + (li & 15);
  float v;
  if (region == 0)      v = We_w[n * 257 + k];
  else if (region == 1) v = (k < 128) ? Wd_w[n * 384 + 128 + k]
                                      : Wd_w[n * 384 + 256 + (k - 128)];
  else                  v = Wd_w[n * 384 + k];
  f16[e] = f2b(v);
}

// ---- prep2: i8 quantized gates weights, one wave per column ----
__global__ void prep_q(const float* __restrict__ enc_Wih,
                       const float* __restrict__ enc_Whh,
                       const float* __restrict__ dec_Whh,
                       char* __restrict__ ws8) {
  int gw = (blockIdx.x * 256 + threadIdx.x) >> 6;
  int lane = threadIdx.x & 63;
  if (gw < 512) {                        // encoder col, K=256
    int n = gw;
    float v[4]; float m = 0.f;
#pragma unroll
    for (int q = 0; q < 4; ++q) {
      int k = lane * 4 + q;
      v[q] = (k < 128) ? enc_Wih[n * 128 + k] : enc_Whh[n * 128 + (k - 128)];
      m = fmaxf(m, fabsf(v[q]));
    }
    m = wmax64(m);
    if (lane == 0) ((float*)(ws8 + SENC_B))[n] = m * C127;
    float inv = m > 0.f ? 127.f / m : 0.f;
    char* dst = ws8 + WENC8_B;
#pragma unroll
    for (int q = 0; q < 4; ++q) {
      int k = lane * 4 + q;
      int kt = k >> 6, grp = (k >> 4) & 3, b = k & 15, l16 = (n & 15) | (grp << 4);
      dst[((kt * 32 + (n >> 4)) * 64 + l16) * 16 + b] = (char)(int)rintf(v[q] * inv);
    }
  } else if (gw < 1024) {                // decoder col, K=128
    int n = gw - 512;
    float v[2]; float m = 0.f;
#pragma unroll
    for (int q = 0; q < 2; ++q) {
      int k = lane * 2 + q;
      v[q] = dec_Whh[n * 128 + k];
      m = fmaxf(m, fabsf(v[q]));
    }
    m = wmax64(m);
    if (lane == 0) ((float*)(ws8 + SDEC_B))[n] = m * C127;
    float inv = m > 0.f ? 127.f / m : 0.f;
    char* dst = ws8 + WDEC8_B;
#pragma unroll
    for (int q = 0; q < 2; ++q) {
      int k = lane * 2 + q;
      int kt = k >> 6, grp = (k >> 4) & 3, b = k & 15, l16 = (n & 15) | (grp << 4);
      dst[((kt * 32 + (n >> 4)) * 64 + l16) * 16 + b] = (char)(int)rintf(v[q] * inv);
    }
  }
}

__global__ __launch_bounds__(512, 2)
void da_rnn(const float* __restrict__ X, const float* __restrict__ y_hist,
            const float* __restrict__ We_w, const float* __restrict__ We_b,
            const float* __restrict__ ve_w,
            const float* __restrict__ enc_bih, const float* __restrict__ enc_bhh,
            const float* __restrict__ dec_Wih,
            const float* __restrict__ dec_bih, const float* __restrict__ dec_bhh,
            const float* __restrict__ Wd_b, const float* __restrict__ vd_w,
            const float* __restrict__ fc_w, const float* __restrict__ fc_b,
            const char* __restrict__ ws8, float* __restrict__ out) {
  const short* f16  = (const short*)ws8;
  const i32x4* enc8 = (const i32x4*)(ws8 + WENC8_B);
  const i32x4* dec8 = (const i32x4*)(ws8 + WDEC8_B);
  const float* senc = (const float*)(ws8 + SENC_B);
  const float* sdec = (const float*)(ws8 + SDEC_B);

  // strides mod 32 words: s_A8 68=4, s_Ahc 132=4, s_gates 528=16, s_base 72=8
  __shared__ __align__(16) char  s_A8[16][272];   // gates A i8
  __shared__ __align__(16) short s_Ahc[16][264];  // base/dc/proj A bf16 [h;c]
  __shared__ short s_projT[4][64][65];            // enc_proj^T
  __shared__ short s_encht[4][128][66];           // enc_hiddens [r][j][t] bf16
  __shared__ __align__(16) float s_gates[4][528]; // raw gate pre-acts (C^T b128)
  __shared__ __align__(16) float s_base[4][72];   // enc: base ; dec: dc
  __shared__ float s_beta[4][64];
  __shared__ float s_xr[4];
  __shared__ float2 s_wv[64];                     // (w_feat[k], ve_w[k])
  __shared__ __align__(16) float s_web[64];
  __shared__ float s_vd[64];
  __shared__ __align__(16) float s_wdb[64];
  __shared__ float s_se[512], s_sd[512];
  __shared__ float s_encb[512], s_decb[512], s_dwih[512];
  __shared__ float s_fcw[320];

  const int tid  = threadIdx.x;
  const int lane = tid & 63;
  const int w    = tid >> 6;        // wave 0..7 ; waves 0-3 own row w
  const int b0   = blockIdx.x * BB;

  // ---- init ----
  if (tid < 64) {
    s_wv[tid]  = make_float2(We_w[tid * 257 + 256], ve_w[tid]);
    s_web[tid] = We_b[tid];
    s_vd[tid]  = vd_w[tid];
    s_wdb[tid] = Wd_b[tid];
  }
  if (tid < 320) s_fcw[tid] = fc_w[tid];
  s_se[tid]   = senc[tid];
  s_sd[tid]   = sdec[tid];
  s_encb[tid] = enc_bih[tid] + enc_bhh[tid];
  s_decb[tid] = dec_bih[tid] + dec_bhh[tid];
  s_dwih[tid] = dec_Wih[tid];
  for (int i = tid; i < (16 * 272) / 4; i += 512) ((int*)s_A8)[i] = 0;
  for (int i = tid; i < (16 * 264) / 2; i += 512) ((int*)s_Ahc)[i] = 0;
  if (tid < 256) s_base[tid >> 6][tid & 63] = We_b[tid & 63];  // base_0

  // ---- register-resident weights (loaded once, L2) ----
  i32x4 wg[4][4];                       // enc gates i8, nt = w + 8i
#pragma unroll
  for (int kt = 0; kt < 4; ++kt)
#pragma unroll
    for (int i = 0; i < 4; ++i)
      wg[kt][i] = enc8[(kt * 32 + (w + 8 * i)) * 64 + lane];
  bf16x8 wb[8], wp[4];
  if (w < 4) {
#pragma unroll
    for (int kt = 0; kt < 8; ++kt)
      wb[kt] = *(const bf16x8*)(f16 + WHS_E + ((kt * 4 + w) * 64 + lane) * 8);
  } else {
#pragma unroll
    for (int kt = 0; kt < 4; ++kt)
      wp[kt] = *(const bf16x8*)(f16 + WDENC_E + ((kt * 4 + (w - 4)) * 64 + lane) * 8);
  }

  // per-row attention state (waves 0-3): features j0=lane, j1=lane+64
  float xf0 = 0.f, xf1 = 0.f, xi = 0.f;
  const float* Xr = X + (size_t)(b0 + (w & 3)) * T_ * D_;
  if (w < 4) {
    xf0 = Xr[lane]; xf1 = Xr[64 + lane];    // x(t=0), consumed top of P_A(0)
    xi = 6.f * cosf((2 * (lane >> 3) + 1) * 0.19634954084936207f);  // node
  }
  // 8-wave epilogue state: wave w -> row w&3, feature fE = 64*(w>>2)+lane
  float cstE = 0.f;
  const int rE = w & 3;
  const int fE = ((w >> 2) << 6) + lane;
  // h-side gates contribution (precomputed each P_B; h_0 = 0 -> zero)
  i32x4 ahp[4];
#pragma unroll
  for (int i = 0; i < 4; ++i) ahp[i] = (i32x4){0, 0, 0, 0};
  __syncthreads();

  // ---- per-wave preloads (post-barrier: LDS constants now valid) ----
  float seE[4], ebE[4];
#pragma unroll
  for (int g = 0; g < 4; ++g) {
    seE[g] = s_se[fE + 128 * g];
    ebE[g] = s_encb[fE + 128 * g];
  }
  f32x4 webq = {0.f, 0.f, 0.f, 0.f};
  if (w < 4) webq = *(const f32x4*)&s_web[(w << 4) + ((lane >> 4) << 2)];

  // ====================== encoder ======================
  for (int t = 0; t < T_; ++t) {
    // ---- P_A: input attention, in-wave, waves 0-3 (row = w) ----
    float x0, x1;
    if (w < 4) {
      x0 = xf0; x1 = xf1;                 // prefetched one step ago
      // node eval: lane = (ni = lane>>3, kc = lane&7); 8 k-terms each
      const int kc = lane & 7;
      float p = 0.f;
      const float4* wvp = (const float4*)&s_wv[kc * 8];
      const float4* bp  = (const float4*)&s_base[w][kc * 8];
      float4 bA = bp[0], bB = bp[1];
#pragma unroll
      for (int q = 0; q < 4; ++q) {
        float4 wv = wvp[q];                       // (w_k, ve_k, w_{k+1}, ve_{k+1})
        float bb0 = (q < 2) ? ((q & 1) ? bA.z : bA.x) : ((q & 1) ? bB.z : bB.x);
        float bb1 = (q < 2) ? ((q & 1) ? bA.w : bA.y) : ((q & 1) ? bB.w : bB.y);
        p += wv.y * tanh_acc(fmaf(xi, wv.x, bb0));
        p += wv.w * tanh_acc(fmaf(xi, wv.z, bb1));
      }
      p = gsum8(p);                               // sum over kc within node grp
      float f0 = __shfl(p,  0, 64), f1 = __shfl(p,  8, 64);
      float f2 = __shfl(p, 16, 64), f3 = __shfl(p, 24, 64);
      float f4 = __shfl(p, 32, 64), f5 = __shfl(p, 40, 64);
      float f6 = __shfl(p, 48, 64), f7 = __shfl(p, 56, 64);
      // Lagrange FIRST form at u = clamp(x, +-6): rcp-free.
      float e0, e1;
      {
        const float xb[8] = { 5.884711682f, 4.988817674f, 3.333421398f, 1.170541932f,
                             -1.170541932f, -3.333421398f, -4.988817674f, -5.884711682f};
        const float wbar[8] = { 0.1950903220f, -0.5555702330f, 0.8314696123f, -0.9807852804f,
                                0.9807852804f, -0.8314696123f, 0.5555702330f, -0.1950903220f};
        float fw[8] = {f0 * wbar[0], f1 * wbar[1], f2 * wbar[2], f3 * wbar[3],
                       f4 * wbar[4], f5 * wbar[5], f6 * wbar[6], f7 * wbar[7]};
        float u0 = fminf(fmaxf(x0, -6.f), 6.f), u1 = fminf(fmaxf(x1, -6.f), 6.f);
        float d0[8], d1[8], P0[8], P1[8];
        float pre0 = 1.f, pre1 = 1.f;
#pragma unroll
        for (int i = 0; i < 8; ++i) {
          d0[i] = u0 - xb[i]; d1[i] = u1 - xb[i];
          P0[i] = pre0;       P1[i] = pre1;
          pre0 *= d0[i];      pre1 *= d1[i];
        }
        float suf0 = 1.f, suf1 = 1.f, acc0 = 0.f, acc1 = 0.f;
#pragma unroll
        for (int i = 7; i >= 0; --i) {
          acc0 = fmaf(fw[i] * P0[i], suf0, acc0);
          acc1 = fmaf(fw[i] * P1[i], suf1, acc1);
          suf0 *= d0[i];
          suf1 *= d1[i];
        }
        e0 = fexp2(acc0 * KLAG);                  // exp(sc), sc=acc/17496
        e1 = fexp2(acc1 * KLAG);
      }
      float sum = wsum64(e0 + e1);
      float mx  = wmax64(fmaxf(e0 * fabsf(x0), e1 * fabsf(x1)));
      float inv = mx > 0.f ? 127.f * frcp(mx) : 0.f;
      s_A8[w][lane]      = (char)(int)rintf(x0 * e0 * inv);
      s_A8[w][64 + lane] = (char)(int)rintf(x1 * e1 * inv);
      if (lane == 0) s_xr[w] = mx * frcp(127.f * sum);
    }
    __syncthreads();                                            // B1
    // ---- P_G: gates i8 GEMM, TRANSPOSED (C^T: lane&15=brow, regs=gcols) ----
    {
      i32x4 a0 = *(const i32x4*)&s_A8[lane & 15][  0 + ((lane >> 4) << 4)];
      i32x4 a1 = *(const i32x4*)&s_A8[lane & 15][ 64 + ((lane >> 4) << 4)];
      i32x4 ax[4];
#pragma unroll
      for (int i = 0; i < 4; ++i) {
        i32x4 z = {0, 0, 0, 0};
        ax[i] = MFMAI8(wg[1][i], a1, MFMAI8(wg[0][i], a0, z));
      }
      float sx = s_xr[lane & 3];
      if ((lane & 15) < 4) {
        int cb = (lane >> 4) << 2;
#pragma unroll
        for (int i = 0; i < 4; ++i) {
          f32x4 v;
#pragma unroll
          for (int r = 0; r < 4; ++r)
            v[r] = fmaf(sx, (float)ax[i][r], C127 * (float)ahp[i][r]);
          *(f32x4*)&s_gates[lane & 15][(w + 8 * i) * 16 + cb] = v;
        }
      }
    }
    __syncthreads();                                            // B2
    // ---- P_E: LSTM epilogue, 8-WAVE SPLIT: 1 cell/lane (5 trans) ----
    {
      float g_i = fmaf(s_gates[rE][fE]      , seE[0], ebE[0]);
      float g_f = fmaf(s_gates[rE][fE + 128], seE[1], ebE[1]);
      float g_g = fmaf(s_gates[rE][fE + 256], seE[2], ebE[2]);
      float g_o = fmaf(s_gates[rE][fE + 384], seE[3], ebE[3]);
      cstE = sigm(g_f) * cstE + sigm(g_i) * tanh_acc(g_g);
      float h = sigm(g_o) * tanh_acc(cstE);
      s_Ahc[rE][fE]        = f2b(h);
      s_Ahc[rE][128 + fE]  = f2b(cstE);
      s_A8[rE][128 + fE]   = (char)(int)rintf(h * 127.f);
      s_encht[rE][fE][t]   = f2b(h);
    }
    __syncthreads();                                            // B3
    // ---- P_B: base_{t+1} (w0-3, transposed) | proj_t (w4-7) ; ah-precompute
    {
      i32x4 pa2 = *(const i32x4*)&s_A8[lane & 15][128 + ((lane >> 4) << 4)];
      i32x4 pa3 = *(const i32x4*)&s_A8[lane & 15][192 + ((lane >> 4) << 4)];
#pragma unroll
      for (int i = 0; i < 4; ++i) {
        i32x4 z = {0, 0, 0, 0};
        ahp[i] = MFMAI8(wg[3][i], pa3, MFMAI8(wg[2][i], pa2, z));
      }
    }
    if (w < 4) {
      if (t < T_ - 1) {                   // X prefetch: one full step early
        xf0 = Xr[(t + 1) * D_ + lane];
        xf1 = Xr[(t + 1) * D_ + 64 + lane];
      }
      f32x4 acc = {0.f, 0.f, 0.f, 0.f}, acc2 = {0.f, 0.f, 0.f, 0.f};
#pragma unroll
      for (int kt = 0; kt < 4; ++kt) {
        bf16x8 a = *(const bf16x8*)&s_Ahc[lane & 15][kt * 32 + ((lane >> 4) << 3)];
        acc = MFMA16(wb[kt], a, acc);
      }
#pragma unroll
      for (int kt = 4; kt < 8; ++kt) {
        bf16x8 a = *(const bf16x8*)&s_Ahc[lane & 15][kt * 32 + ((lane >> 4) << 3)];
        acc2 = MFMA16(wb[kt], a, acc2);
      }
      if ((lane & 15) < 4) {
        f32x4 v = acc + acc2 + webq;
        *(f32x4*)&s_base[lane & 15][(w << 4) + ((lane >> 4) << 2)] = v;
      }
    } else {
      f32x4 acc = {0.f, 0.f, 0.f, 0.f};
#pragma unroll
      for (int kt = 0; kt < 4; ++kt) {
        bf16x8 a = *(const bf16x8*)&s_Ahc[lane & 15][kt * 32 + ((lane >> 4) << 3)];
        acc = MFMA16(a, wp[kt], acc);    // original orientation (strided store)
      }
      if (lane < 16) {
        int katt = (w - 4) * 16 + lane;
#pragma unroll
        for (int r = 0; r < 4; ++r) s_projT[r][katt][t] = f2b(acc[r]);
      }
    }
    __syncthreads();                                            // B4
  }

  // ====================== decoder ======================
  {
    int r = tid >> 7, j = tid & 127;
    s_Ahc[r][j] = 0; s_Ahc[r][128 + j] = 0; s_A8[r][j] = 0;
  }
  i32x4 wdg[2][8];                      // dec gates i8 (waves 4-7), nt=(w-4)*8+i
  bf16x8 wdc[8];                        // dc bf16 (waves 0-3)
  float yp = 0.f, yhd = 0.f;
  float sdC_p[8], db_p[8], dw_p[8];
  f32x4 wdbq = {0.f, 0.f, 0.f, 0.f};
  if (w >= 4) {
#pragma unroll
    for (int kt = 0; kt < 2; ++kt)
#pragma unroll
      for (int i = 0; i < 8; ++i)
        wdg[kt][i] = dec8[(kt * 32 + ((w - 4) * 8 + i)) * 64 + lane];
  } else {
#pragma unroll
    for (int kt = 0; kt < 8; ++kt)
      wdc[kt] = *(const bf16x8*)(f16 + WDDC_E + ((kt * 4 + w) * 64 + lane) * 8);
#pragma unroll
    for (int j = 0; j < 8; ++j) {
      sdC_p[j] = s_sd[lane + 64 * j] * C127;
      db_p[j]  = s_decb[lane + 64 * j];
      dw_p[j]  = s_dwih[lane + 64 * j];
    }
    wdbq = *(const f32x4*)&s_wdb[(w << 4) + ((lane >> 4) << 2)];
    yp = y_hist[(b0 + w) * T_ + (T_ - 1)];
    float pp = s_fcw[256 + lane] * y_hist[(b0 + w) * T_ + lane];
    yhd = wsum64(pp) + fc_b[0];
  }
  float dd0 = 0.f, dc0 = 0.f, dd1 = 0.f, dc1 = 0.f;   // d, cc (2 feats/lane)
  __syncthreads();

  for (int hs = 0; hs < HOR_; ++hs) {
    // ---- Phase A: w0-3 {context+fc+out(hs-1), dc GEMM} | w4-7 {gates GEMM}
    if (w >= 4) {
      i32x4 a0 = *(const i32x4*)&s_A8[lane & 15][ 0 + ((lane >> 4) << 4)];
      i32x4 a1 = *(const i32x4*)&s_A8[lane & 15][64 + ((lane >> 4) << 4)];
#pragma unroll
      for (int i = 0; i < 8; ++i) {
        i32x4 z = {0, 0, 0, 0};
        i32x4 ac = MFMAI8(wdg[1][i], a1, MFMAI8(wdg[0][i], a0, z));
        if ((lane & 15) < 4) {
          f32x4 v = {(float)ac[0], (float)ac[1], (float)ac[2], (float)ac[3]};
          *(f32x4*)&s_gates[lane & 15][(((w - 4) * 8 + i) << 4) + ((lane >> 4) << 2)] = v;
        }
      }
    } else {
      if (hs > 0) {
        // context for step hs-1 (beta from last Phase B) + fc + out
        float cx0a = 0.f, cx0b = 0.f, cx1a = 0.f, cx1b = 0.f;
        const short* e0p = &s_encht[w][lane][0];
        const short* e1p = &s_encht[w][lane + 64][0];
#pragma unroll 8
        for (int tp = 0; tp < 32; ++tp) {
          float2 bta = *(const float2*)&s_beta[w][2 * tp];
          short2 h0v = *(const short2*)&e0p[2 * tp];
          short2 h1v = *(const short2*)&e1p[2 * tp];
          cx0a = fmaf(bta.x, b2f(h0v.x), cx0a); cx0b = fmaf(bta.y, b2f(h0v.y), cx0b);
          cx1a = fmaf(bta.x, b2f(h1v.x), cx1a); cx1b = fmaf(bta.y, b2f(h1v.y), cx1b);
        }
        float cx0 = cx0a + cx0b, cx1 = cx1a + cx1b;
        float pf = s_fcw[lane] * dd0 + s_fcw[64 + lane] * dd1
                 + s_fcw[128 + lane] * cx0 + s_fcw[192 + lane] * cx1;
        pf = wsum64(pf);
        float o = pf + yhd;
        if (lane == 0) out[(b0 + w) * HOR_ + (hs - 1)] = o;
        yp = o;
      }
      // dc GEMM (reads s_Ahc = d_hs written last Phase B)
      f32x4 acc = {0.f, 0.f, 0.f, 0.f}, acc2 = {0.f, 0.f, 0.f, 0.f};
#pragma unroll
      for (int kt = 0; kt < 4; ++kt) {
        bf16x8 a = *(const bf16x8*)&s_Ahc[lane & 15][kt * 32 + ((lane >> 4) << 3)];
        acc = MFMA16(wdc[kt], a, acc);
      }
#pragma unroll
      for (int kt = 4; kt < 8; ++kt) {
        bf16x8 a = *(const bf16x8*)&s_Ahc[lane & 15][kt * 32 + ((lane >> 4) << 3)];
        acc2 = MFMA16(wdc[kt], a, acc2);
      }
      if ((lane & 15) < 4) {
        f32x4 v = acc + acc2 + wdbq;
        *(f32x4*)&s_base[lane & 15][(w << 4) + ((lane >> 4) << 2)] = v;
      }
    }
    __syncthreads();                                            // B1
    // ---- Phase B: w0-3 {LSTM epilogue} | w4-7 {scores+softmax -> s_beta}
    if (w < 4) {
      float gi0 = s_gates[w][lane]       * sdC_p[0] + db_p[0] + yp * dw_p[0];
      float gi1 = s_gates[w][lane + 64]  * sdC_p[1] + db_p[1] + yp * dw_p[1];
      float gf0 = s_gates[w][lane + 128] * sdC_p[2] + db_p[2] + yp * dw_p[2];
      float gf1 = s_gates[w][lane + 192] * sdC_p[3] + db_p[3] + yp * dw_p[3];
      float gg0 = s_gates[w][lane + 256] * sdC_p[4] + db_p[4] + yp * dw_p[4];
      float gg1 = s_gates[w][lane + 320] * sdC_p[5] + db_p[5] + yp * dw_p[5];
      float go0 = s_gates[w][lane + 384] * sdC_p[6] + db_p[6] + yp * dw_p[6];
      float go1 = s_gates[w][lane + 448] * sdC_p[7] + db_p[7] + yp * dw_p[7];
      dc0 = sigm(gf0) * dc0 + sigm(gi0) * tanh_acc(gg0);
      dd0 = sigm(go0) * tanh_acc(dc0);
      dc1 = sigm(gf1) * dc1 + sigm(gi1) * tanh_acc(gg1);
      dd1 = sigm(go1) * tanh_acc(dc1);
      // state for next Phase A GEMMs
      s_Ahc[w][lane]       = f2b(dd0);
      s_Ahc[w][lane + 64]  = f2b(dd1);
      s_Ahc[w][lane + 128] = f2b(dc0);
      s_Ahc[w][lane + 192] = f2b(dc1);
      s_A8[w][lane]      = (char)(int)rintf(dd0 * 127.f);
      s_A8[w][lane + 64] = (char)(int)rintf(dd1 * 127.f);
    } else {
      const int r = w - 4;
      float sA = 0.f, sB = 0.f, sC = 0.f, sD = 0.f;
#pragma unroll 4
      for (int k = 0; k < 64; k += 4) {
        sA += s_vd[k]     * tanh_acc(b2f(s_projT[r][k][lane])     + s_base[r][k]);
        sB += s_vd[k + 1] * tanh_acc(b2f(s_projT[r][k + 1][lane]) + s_base[r][k + 1]);
        sC += s_vd[k + 2] * tanh_acc(b2f(s_projT[r][k + 2][lane]) + s_base[r][k + 2]);
        sD += s_vd[k + 3] * tanh_acc(b2f(s_projT[r][k + 3][lane]) + s_base[r][k + 3]);
      }
      float s = (sA + sB) + (sC + sD);
      float e = fexp2(s * LOG2E);
      float ssum = wsum64(e);
      s_beta[r][lane] = e * frcp(ssum);
    }
    __syncthreads();                                            // B2
  }
  // ---- tail: final context+fc+out for hs = HOR_-1 (w0-3) ----
  if (w < 4) {
    float cx0a = 0.f, cx0b = 0.f, cx1a = 0.f, cx1b = 0.f;
    const short* e0p = &s_encht[w][lane][0];
    const short* e1p = &s_encht[w][lane + 64][0];
#pragma unroll 8
    for (int tp = 0; tp < 32; ++tp) {
      float2 bta = *(const float2*)&s_beta[w][2 * tp];
      short2 h0v = *(const short2*)&e0p[2 * tp];
      short2 h1v = *(const short2*)&e1p[2 * tp];
      cx0a = fmaf(bta.x, b2f(h0v.x), cx0a); cx0b = fmaf(bta.y, b2f(h0v.y), cx0b);
      cx1a = fmaf(bta.x, b2f(h1v.x), cx1a); cx1b = fmaf(bta.y, b2f(h1v.y), cx1b);
    }
    float cx0 = cx0a + cx0b, cx1 = cx1a + cx1b;
    float pf = s_fcw[lane] * dd0 + s_fcw[64 + lane] * dd1
             + s_fcw[128 + lane] * cx0 + s_fcw[192 + lane] * cx1;
    pf = wsum64(pf);
    float o = pf + yhd;
    if (lane == 0) out[(b0 + w) * HOR_ + (HOR_ - 1)] = o;
  }
}

extern "C" void kernel_launch(void* const* d_in, const int* in_sizes, int n_in,
                              void* d_out, int out_size, void* d_ws, size_t ws_size,
                              hipStream_t stream) {
  (void)in_sizes; (void)n_in; (void)out_size; (void)ws_size;
  const float* X       = (const float*)d_in[0];
  const float* y_hist  = (const float*)d_in[1];
  const float* We_w    = (const float*)d_in[2];
  const float* We_b    = (const float*)d_in[3];
  const float* ve_w    = (const float*)d_in[4];
  // d_in[5] = ve_b : softmax-invariant, unused
  const float* enc_Wih = (const float*)d_in[6];
  const float* enc_Whh = (const float*)d_in[7];
  const float* enc_bih = (const float*)d_in[8];
  const float* enc_bhh = (const float*)d_in[9];
  const float* dec_Wih = (const float*)d_in[10];
  const float* dec_Whh = (const float*)d_in[11];
  const float* dec_bih = (const float*)d_in[12];
  const float* dec_bhh = (const float*)d_in[13];
  const float* Wd_w    = (const float*)d_in[14];
  const float* Wd_b    = (const float*)d_in[15];
  const float* vd_w    = (const float*)d_in[16];
  // d_in[17] = vd_b : softmax-invariant, unused
  const float* fc_w    = (const float*)d_in[18];
  const float* fc_b    = (const float*)d_in[19];

  char* ws8  = (char*)d_ws;
  float* out = (float*)d_out;

  prep_bf<<<160, 256, 0, stream>>>(We_w, Wd_w, ws8);
  prep_q <<<256, 256, 0, stream>>>(enc_Wih, enc_Whh, dec_Whh, ws8);
  da_rnn <<<B_ / BB, 512, 0, stream>>>(X, y_hist, We_w, We_b, ve_w,
                                       enc_bih, enc_bhh, dec_Wih, dec_bih, dec_bhh,
                                       Wd_b, vd_w, fc_w, fc_b, ws8, out);
}